// Round 10
// baseline (258.080 us; speedup 1.0000x reference)
//
#include <hip/hip_runtime.h>
#include <hip/hip_bf16.h>
#include <math.h>

#define BB   8
#define NN   2048
#define BN   (BB * NN)
#define CINC 128
#define COU  256
#define KNNK 16
#define REVCAP 64
#define SEG   8
#define SEGC  (NN / SEG)   // 256 candidates per segment

typedef __bf16 bf16x8 __attribute__((ext_vector_type(8)));
typedef float  f32x4  __attribute__((ext_vector_type(4)));

// Single-instruction sorted-insert step: for ascending t_{j-1} <= t_j,
// new t_j = median(t_{j-1}, t_j, key). v_med3_u32 = 1 VOP3 op (2 cyc).
#define UMED3(dst, a, bb_, c) asm("v_med3_u32 %0, %1, %2, %3" : "=v"(dst) : "v"(a), "v"(bb_), "v"(c))

#define TOP_DECL \
    unsigned int t0=~0u,t1=~0u,t2=~0u,t3=~0u,t4=~0u,t5=~0u,t6=~0u,t7=~0u, \
                 t8=~0u,t9=~0u,t10=~0u,t11=~0u,t12=~0u,t13=~0u,t14=~0u,t15=~0u;

// Insert u into sorted multiset {t0..t15}, dropping the max. Descending order
// uses old t_{j-1} before it is overwritten. 15 med3 + 1 min, no branch.
#define TOP_INSERT(u) {                     \
    UMED3(t15, t14, t15, (u));              \
    UMED3(t14, t13, t14, (u));              \
    UMED3(t13, t12, t13, (u));              \
    UMED3(t12, t11, t12, (u));              \
    UMED3(t11, t10, t11, (u));              \
    UMED3(t10, t9,  t10, (u));              \
    UMED3(t9,  t8,  t9,  (u));              \
    UMED3(t8,  t7,  t8,  (u));              \
    UMED3(t7,  t6,  t7,  (u));              \
    UMED3(t6,  t5,  t6,  (u));              \
    UMED3(t5,  t4,  t5,  (u));              \
    UMED3(t4,  t3,  t4,  (u));              \
    UMED3(t3,  t2,  t3,  (u));              \
    UMED3(t2,  t1,  t2,  (u));              \
    UMED3(t1,  t0,  t1,  (u));              \
    t0 = ((u) < t0) ? (u) : t0;             \
}

// dist arithmetic: bit-identical to the verified R1-R8 formula.
#define DIST_DU(c_)                                                              \
    float dot = fmaf(qz, (c_).z, fmaf(qy, (c_).y, __fmul_rn(qx, (c_).x)));       \
    float d = __fsub_rn(__fadd_rn(qsq, (c_).w), __fmul_rn(2.0f, dot));           \
    unsigned int du = __float_as_uint(d);                                        \
    du ^= (unsigned int)((int)du >> 31) | 0x80000000u;

// ---------------- transpose features (B,C,N) -> fT (B,N,C) ----------------
__global__ __launch_bounds__(256) void transpose_kernel(const float* __restrict__ feat,
                                                        float* __restrict__ fT) {
    __shared__ float t[32][33];
    int b  = blockIdx.z;
    int n0 = blockIdx.x * 32, c0 = blockIdx.y * 32;
    int tx = threadIdx.x, ty = threadIdx.y;  // (32,8)
#pragma unroll
    for (int i = 0; i < 4; i++)
        t[ty + i * 8][tx] = feat[((size_t)b * CINC + c0 + ty + i * 8) * NN + n0 + tx];
    __syncthreads();
#pragma unroll
    for (int i = 0; i < 4; i++)
        fT[((size_t)b * NN + n0 + ty + i * 8) * CINC + c0 + tx] = t[tx][ty + i * 8];
}

// ---------------- prep: cast weights to bf16, concat W2 & bias ----------------
__global__ __launch_bounds__(256) void prep_kernel(const float* __restrict__ Wspec,
                                                   const float* __restrict__ Wlow,
                                                   const float* __restrict__ Whigh,
                                                   const float* __restrict__ blow,
                                                   const float* __restrict__ bhigh,
                                                   __bf16* __restrict__ WspecB,
                                                   __bf16* __restrict__ WcB,
                                                   float* __restrict__ bc) {
    int i = blockIdx.x * 256 + threadIdx.x;
    if (i < COU * CINC) WspecB[i] = (__bf16)Wspec[i];
    if (i < 128 * COU) {
        WcB[i] = (__bf16)Wlow[i];
        WcB[128 * COU + i] = (__bf16)Whigh[i];
    }
    if (i < 128) { bc[i] = blow[i]; bc[128 + i] = bhigh[i]; }
}

// ---------------- KNN part: med3-u32 top-16 + exact (dist,idx) recovery ----------------
// Phase A: top-16 of ordered-u32 dists via med3 network -> T = 16th smallest (multiset).
// Phase B: emit all du<T (provably <=15), buffer first 4 ties du==T (arrival order
// = ascending idx = lax.top_k tie-break), fill slots; fallback scan for >4 ties.
// Emits exactly 16 (du,idx) pairs per (query,segment), layout [slot][bq] (coalesced merge).
__global__ __launch_bounds__(256) void knn_part_kernel(const float* __restrict__ xyz,
                                                       unsigned int* __restrict__ pdu,
                                                       unsigned int* __restrict__ pidx) {
    __shared__ float4 cand[4][SEGC];
    int b = blockIdx.z;
    int lane = threadIdx.x & 63;
    int w = threadIdx.x >> 6;
    int q = blockIdx.x * 64 + lane;
    int s = blockIdx.y * 4 + w;

    const float* xb = xyz + (size_t)b * 3 * NN;

    int base = blockIdx.y * (4 * SEGC);
    for (int t = threadIdx.x; t < 4 * SEGC; t += 256) {
        int m = base + t;
        float x = xb[m], y = xb[NN + m], z = xb[2 * NN + m];
        float sq = __fadd_rn(__fadd_rn(__fmul_rn(x, x), __fmul_rn(y, y)), __fmul_rn(z, z));
        cand[t >> 8][t & (SEGC - 1)] = make_float4(x, y, z, sq);
    }
    __syncthreads();

    float qx = xb[q], qy = xb[NN + q], qz = xb[2 * NN + q];
    float qsq = __fadd_rn(__fadd_rn(__fmul_rn(qx, qx), __fmul_rn(qy, qy)), __fmul_rn(qz, qz));

    TOP_DECL
    for (int i = 0; i < SEGC; i++) {
        float4 c = cand[w][i];
        DIST_DU(c)
        TOP_INSERT(du)
    }
    unsigned int T = t15;

    int segbase = s * SEGC;
    size_t pb = (size_t)(s * KNNK) * BN + ((size_t)b * NN + q);
    unsigned int fp = 0, tc = 0;
    int tb0 = 0, tb1 = 0, tb2 = 0, tb3 = 0;
    for (int i = 0; i < SEGC; i++) {
        float4 c = cand[w][i];
        DIST_DU(c)
        if (du < T) {
            pdu[pb + (size_t)fp * BN]  = du;
            pidx[pb + (size_t)fp * BN] = (unsigned int)(segbase + i);
            fp++;
        } else if (du == T) {
            if (tc == 0) tb0 = i; else if (tc == 1) tb1 = i;
            else if (tc == 2) tb2 = i; else if (tc == 3) tb3 = i;
            tc++;
        }
    }
#define PEMIT(ti_) { pdu[pb + (size_t)fp * BN] = T; \
                     pidx[pb + (size_t)fp * BN] = (unsigned int)(segbase + (ti_)); fp++; }
    if (fp < KNNK && tc > 0) PEMIT(tb0)
    if (fp < KNNK && tc > 1) PEMIT(tb1)
    if (fp < KNNK && tc > 2) PEMIT(tb2)
    if (fp < KNNK && tc > 3) PEMIT(tb3)
    if (fp < KNNK) {               // >4 ties needed: practically never
        unsigned int ord = 0;
        for (int i = 0; i < SEGC; i++) {
            float4 c = cand[w][i];
            DIST_DU(c)
            if (du == T) { ord++; if (ord > 4 && fp < KNNK) PEMIT(i) }
        }
    }
#undef PEMIT
}

// ---------------- KNN merge: fold 8 exact 16-lists -> final top-16 + scatter ----------------
// Tie entries (du==T) arrive in globally ascending idx order (segments are disjoint
// ascending ranges; within a segment the du==T subset is idx-ascending), so the
// first-4 buffer + ordinal fallback reproduces the exact lowest-idx tie-break.
__global__ __launch_bounds__(64) void knn_merge_kernel(const unsigned int* __restrict__ pdu,
                                                       const unsigned int* __restrict__ pidx,
                                                       int* __restrict__ knn_idx,
                                                       int* __restrict__ revcnt,
                                                       int* __restrict__ rev) {
    int bq = blockIdx.x * 64 + threadIdx.x;
    int b = bq >> 11;
    int n = bq & (NN - 1);

    TOP_DECL
    for (int j = 0; j < SEG * KNNK; j++) {
        unsigned int u = pdu[(size_t)j * BN + bq];
        TOP_INSERT(u)
    }
    unsigned int T = t15;

    unsigned int fp = 0, tc = 0;
    int tb0 = 0, tb1 = 0, tb2 = 0, tb3 = 0;
#define MEMIT(x_) { int xv = (x_); knn_idx[(size_t)bq * KNNK + fp] = xv;       \
                    int pos = atomicAdd(&revcnt[b * NN + xv], 1);              \
                    if (pos < REVCAP) rev[((size_t)(b * NN + xv)) * REVCAP + pos] = n; fp++; }
    for (int j = 0; j < SEG * KNNK; j++) {
        unsigned int u = pdu[(size_t)j * BN + bq];
        int x = (int)pidx[(size_t)j * BN + bq];
        if (u < T) {
            MEMIT(x)
        } else if (u == T) {
            if (tc == 0) tb0 = x; else if (tc == 1) tb1 = x;
            else if (tc == 2) tb2 = x; else if (tc == 3) tb3 = x;
            tc++;
        }
    }
    if (fp < KNNK && tc > 0) MEMIT(tb0)
    if (fp < KNNK && tc > 1) MEMIT(tb1)
    if (fp < KNNK && tc > 2) MEMIT(tb2)
    if (fp < KNNK && tc > 3) MEMIT(tb3)
    if (fp < KNNK) {               // >4 ties needed: practically never
        unsigned int ord = 0;
        for (int j = 0; j < SEG * KNNK; j++) {
            unsigned int u = pdu[(size_t)j * BN + bq];
            if (u == T) {
                ord++;
                if (ord > 4 && fp < KNNK) { int x = (int)pidx[(size_t)j * BN + bq]; MEMIT(x) }
            }
        }
    }
#undef MEMIT
}

// ---------------- dinv = rsqrt(D + 1e-6), D = 0.5*(K + indeg) ----------------
__global__ __launch_bounds__(256) void dinv_kernel(const int* __restrict__ revcnt,
                                                   float* __restrict__ dinv) {
    int i = blockIdx.x * 256 + threadIdx.x;
    if (i < BB * NN) {
        float D = 0.5f * (float)(KNNK + revcnt[i]);
        dinv[i] = 1.0f / sqrtf(D + 1e-6f);
    }
}

// ---------------- spec: f32 compute, bf16 output ----------------
__global__ __launch_bounds__(128) void spec_kernel(const float* __restrict__ fT,
                                                   const int* __restrict__ knn_idx,
                                                   const int* __restrict__ revcnt,
                                                   const int* __restrict__ rev,
                                                   const float* __restrict__ dinv,
                                                   __bf16* __restrict__ specB) {
    __shared__ int ml[KNNK + REVCAP];
    __shared__ float wl[KNNK + REVCAP];
    __shared__ int s_cnt;

    int bn = blockIdx.x;           // b*NN + n
    int b = bn >> 11;
    int tid = threadIdx.x;

    if (tid == 0) {
        int c = revcnt[bn];
        s_cnt = c < REVCAP ? c : REVCAP;
    }
    __syncthreads();
    int cnt = s_cnt;
    if (tid < KNNK) ml[tid] = knn_idx[(size_t)bn * KNNK + tid];
    if (tid < cnt) ml[KNNK + tid] = rev[(size_t)bn * REVCAP + tid];
    __syncthreads();
    int total = KNNK + cnt;
    if (tid < total) wl[tid] = 0.5f * dinv[b * NN + ml[tid]];
    __syncthreads();

    float dn = dinv[bn];
    float acc = 0.0f;
    for (int j = 0; j < total; j++)
        acc = fmaf(wl[j], fT[((size_t)b * NN + ml[j]) * CINC + tid], acc);
    float f0 = fT[(size_t)bn * CINC + tid];
    specB[(size_t)bn * CINC + tid] = (__bf16)(f0 - dn * acc);
}

// ---------------- GEMM1 (MFMA): g1 = gelu(bn(spec @ Wspec^T + b)) ----------------
__global__ __launch_bounds__(256) void gemm1_mfma(const __bf16* __restrict__ specB,
                                                  const __bf16* __restrict__ WspecB,
                                                  const float* __restrict__ bspec,
                                                  const float* __restrict__ gamma,
                                                  const float* __restrict__ beta,
                                                  const float* __restrict__ mean,
                                                  const float* __restrict__ var,
                                                  __bf16* __restrict__ g1B) {
    int b  = blockIdx.y;
    int n0 = blockIdx.x * 64;
    int w = threadIdx.x >> 6, lane = threadIdx.x & 63;
    int o0 = w * 64;                       // 4 waves tile o = 0..255
    int lr = lane & 15, lk = (lane >> 4) * 8;

    f32x4 acc[4][4] = {};
    const __bf16* As = specB + ((size_t)b * NN + n0 + lr) * CINC + lk;
    const __bf16* Bs = WspecB + (size_t)(o0 + lr) * CINC + lk;
#pragma unroll
    for (int kk = 0; kk < CINC; kk += 32) {
        bf16x8 a[4], bb[4];
#pragma unroll
        for (int m = 0; m < 4; m++)
            a[m] = *(const bf16x8*)(As + (size_t)(m * 16) * CINC + kk);
#pragma unroll
        for (int n = 0; n < 4; n++)
            bb[n] = *(const bf16x8*)(Bs + (size_t)(n * 16) * CINC + kk);
#pragma unroll
        for (int m = 0; m < 4; m++)
#pragma unroll
            for (int n = 0; n < 4; n++)
                acc[m][n] = __builtin_amdgcn_mfma_f32_16x16x32_bf16(a[m], bb[n], acc[m][n], 0, 0, 0);
    }

    int rb = (lane >> 4) * 4;
#pragma unroll
    for (int n = 0; n < 4; n++) {
        int o = o0 + n * 16 + lr;
        float sc = 1.0f / sqrtf(var[o] + 1e-5f);
        float ga = gamma[o], be = beta[o], mu = mean[o], bs = bspec[o];
#pragma unroll
        for (int m = 0; m < 4; m++) {
#pragma unroll
            for (int j = 0; j < 4; j++) {
                int nrow = n0 + m * 16 + rb + j;
                float y = acc[m][n][j] + bs;
                y = (y - mu) * sc;
                y = y * ga + be;
                float g = 0.5f * y * (1.0f + erff(y * 0.70710678118654752440f));
                g1B[((size_t)b * NN + nrow) * COU + o] = (__bf16)g;
            }
        }
    }
}

// ---------------- GEMM2 (MFMA): out[b,o,n] = Wc[o,:] @ g1[b,n,:] + bc[o] ----------------
__global__ __launch_bounds__(256) void gemm2_mfma(const __bf16* __restrict__ g1B,
                                                  const __bf16* __restrict__ WcB,
                                                  const float* __restrict__ bc,
                                                  float* __restrict__ out) {
    int b  = blockIdx.z;
    int n0 = blockIdx.x * 256;
    int o0 = blockIdx.y * 64;
    int w = threadIdx.x >> 6, lane = threadIdx.x & 63;
    int n0w = n0 + w * 64;                 // 4 waves tile n
    int lr = lane & 15, lk = (lane >> 4) * 8;

    f32x4 acc[4][4] = {};
    const __bf16* As = WcB + (size_t)(o0 + lr) * COU + lk;
    const __bf16* Bs = g1B + ((size_t)b * NN + n0w + lr) * COU + lk;
#pragma unroll
    for (int kk = 0; kk < COU; kk += 32) {
        bf16x8 a[4], bb[4];
#pragma unroll
        for (int m = 0; m < 4; m++)
            a[m] = *(const bf16x8*)(As + (size_t)(m * 16) * COU + kk);
#pragma unroll
        for (int n = 0; n < 4; n++)
            bb[n] = *(const bf16x8*)(Bs + (size_t)(n * 16) * COU + kk);
#pragma unroll
        for (int m = 0; m < 4; m++)
#pragma unroll
            for (int n = 0; n < 4; n++)
                acc[m][n] = __builtin_amdgcn_mfma_f32_16x16x32_bf16(a[m], bb[n], acc[m][n], 0, 0, 0);
    }

    int rb = (lane >> 4) * 4;
#pragma unroll
    for (int m = 0; m < 4; m++) {
#pragma unroll
        for (int j = 0; j < 4; j++) {
            int o = o0 + m * 16 + rb + j;
            float bias = bc[o];
#pragma unroll
            for (int n = 0; n < 4; n++) {
                int ncol = n0w + n * 16 + lr;
                out[((size_t)b * COU + o) * NN + ncol] = acc[m][n][j] + bias;
            }
        }
    }
}

extern "C" void kernel_launch(void* const* d_in, const int* in_sizes, int n_in,
                              void* d_out, int out_size, void* d_ws, size_t ws_size,
                              hipStream_t stream) {
    const float* xyz      = (const float*)d_in[0];
    const float* features = (const float*)d_in[1];
    const float* W_spec   = (const float*)d_in[2];
    const float* b_spec   = (const float*)d_in[3];
    const float* bn_gamma = (const float*)d_in[4];
    const float* bn_beta  = (const float*)d_in[5];
    const float* bn_mean  = (const float*)d_in[6];
    const float* bn_var   = (const float*)d_in[7];
    const float* W_low    = (const float*)d_in[8];
    const float* b_low    = (const float*)d_in[9];
    const float* W_high   = (const float*)d_in[10];
    const float* b_high   = (const float*)d_in[11];
    float* out = (float*)d_out;

    char* ws = (char*)d_ws;
    size_t off = 0;
    float*  fT    = (float*)(ws + off);  off += (size_t)BB * NN * CINC * 4;      // 8 MB
    __bf16* specB = (__bf16*)(ws + off); off += (size_t)BB * NN * CINC * 2;      // 4 MB
    __bf16* g1B   = (__bf16*)(ws + off); off += (size_t)BB * NN * COU  * 2;      // 8 MB
    int*    idx   = (int*)(ws + off);    off += (size_t)BB * NN * KNNK * 4;      // 1 MB
    int*    rcnt  = (int*)(ws + off);    off += (size_t)BB * NN * 4;             // 64 KB
    int*    rev   = (int*)(ws + off);    off += (size_t)BB * NN * REVCAP * 4;    // 4 MB
    float*  dinv  = (float*)(ws + off);  off += (size_t)BB * NN * 4;             // 64 KB
    unsigned int* pdu  = (unsigned int*)(ws + off); off += (size_t)SEG * KNNK * BN * 4; // 8 MB
    unsigned int* pidx = (unsigned int*)(ws + off); off += (size_t)SEG * KNNK * BN * 4; // 8 MB
    __bf16* WspecB= (__bf16*)(ws + off); off += (size_t)COU * CINC * 2;          // 64 KB
    __bf16* WcB   = (__bf16*)(ws + off); off += (size_t)COU * COU * 2;           // 128 KB
    float*  bc    = (float*)(ws + off);  off += (size_t)COU * 4;                 // 1 KB

    hipMemsetAsync(rcnt, 0, (size_t)BB * NN * sizeof(int), stream);

    prep_kernel<<<dim3((COU * CINC + 255) / 256), dim3(256), 0, stream>>>(
        W_spec, W_low, W_high, b_low, b_high, WspecB, WcB, bc);
    transpose_kernel<<<dim3(NN / 32, CINC / 32, BB), dim3(32, 8), 0, stream>>>(features, fT);
    knn_part_kernel<<<dim3(NN / 64, SEG / 4, BB), dim3(256), 0, stream>>>(xyz, pdu, pidx);
    knn_merge_kernel<<<dim3(BN / 64), dim3(64), 0, stream>>>(pdu, pidx, idx, rcnt, rev);
    dinv_kernel<<<dim3(BB * NN / 256), dim3(256), 0, stream>>>(rcnt, dinv);
    spec_kernel<<<dim3(BB * NN), dim3(128), 0, stream>>>(fT, idx, rcnt, rev, dinv, specB);
    gemm1_mfma<<<dim3(NN / 64, BB), dim3(256), 0, stream>>>(
        specB, WspecB, b_spec, bn_gamma, bn_beta, bn_mean, bn_var, g1B);
    gemm2_mfma<<<dim3(NN / 256, COU / 64, BB), dim3(256), 0, stream>>>(g1B, WcB, bc, out);
}

// Round 11
// 228.646 us; speedup vs baseline: 1.1287x; 1.1287x over previous
//
#include <hip/hip_runtime.h>
#include <hip/hip_bf16.h>
#include <math.h>

#define BB   8
#define NN   2048
#define BN   (BB * NN)
#define CINC 128
#define COU  256
#define KNNK 16
#define REVCAP 64
#define SEG   8
#define SEGC  (NN / SEG)   // 256 candidates per segment

typedef __bf16 bf16x8 __attribute__((ext_vector_type(8)));
typedef float  f32x4  __attribute__((ext_vector_type(4)));

// Single-instruction sorted-insert step: for ascending t_{j-1} <= t_j,
// new t_j = median(t_{j-1}, t_j, key). v_med3_u32 = 1 VOP3 op. Single-inst
// source reads make dst/src aliasing safe.
#define UMED3(dst, a, bb_, c) asm("v_med3_u32 %0, %1, %2, %3" : "=v"(dst) : "v"(a), "v"(bb_), "v"(c))

#define TOP_DECL \
    unsigned int t0=~0u,t1=~0u,t2=~0u,t3=~0u,t4=~0u,t5=~0u,t6=~0u,t7=~0u, \
                 t8=~0u,t9=~0u,t10=~0u,t11=~0u,t12=~0u,t13=~0u,t14=~0u,t15=~0u;

// Insert u into sorted multiset {t0..t15}, dropping the max. 15 med3 + 1 min.
#define TOP_INSERT(u) {                     \
    UMED3(t15, t14, t15, (u));              \
    UMED3(t14, t13, t14, (u));              \
    UMED3(t13, t12, t13, (u));              \
    UMED3(t12, t11, t12, (u));              \
    UMED3(t11, t10, t11, (u));              \
    UMED3(t10, t9,  t10, (u));              \
    UMED3(t9,  t8,  t9,  (u));              \
    UMED3(t8,  t7,  t8,  (u));              \
    UMED3(t7,  t6,  t7,  (u));              \
    UMED3(t6,  t5,  t6,  (u));              \
    UMED3(t5,  t4,  t5,  (u));              \
    UMED3(t4,  t3,  t4,  (u));              \
    UMED3(t3,  t2,  t3,  (u));              \
    UMED3(t2,  t1,  t2,  (u));              \
    UMED3(t1,  t0,  t1,  (u));              \
    t0 = ((u) < t0) ? (u) : t0;             \
}

// dist arithmetic: bit-identical to the verified R1-R10 formula.
#define DIST_DU(c_)                                                              \
    float dot = fmaf(qz, (c_).z, fmaf(qy, (c_).y, __fmul_rn(qx, (c_).x)));       \
    float d = __fsub_rn(__fadd_rn(qsq, (c_).w), __fmul_rn(2.0f, dot));           \
    unsigned int du = __float_as_uint(d);                                        \
    du ^= (unsigned int)((int)du >> 31) | 0x80000000u;

// ---------------- transpose features (B,C,N) -> fT (B,N,C) ----------------
__global__ __launch_bounds__(256) void transpose_kernel(const float* __restrict__ feat,
                                                        float* __restrict__ fT) {
    __shared__ float t[32][33];
    int b  = blockIdx.z;
    int n0 = blockIdx.x * 32, c0 = blockIdx.y * 32;
    int tx = threadIdx.x, ty = threadIdx.y;  // (32,8)
#pragma unroll
    for (int i = 0; i < 4; i++)
        t[ty + i * 8][tx] = feat[((size_t)b * CINC + c0 + ty + i * 8) * NN + n0 + tx];
    __syncthreads();
#pragma unroll
    for (int i = 0; i < 4; i++)
        fT[((size_t)b * NN + n0 + ty + i * 8) * CINC + c0 + tx] = t[tx][ty + i * 8];
}

// ---------------- prep: cast weights to bf16, concat W2 & bias ----------------
__global__ __launch_bounds__(256) void prep_kernel(const float* __restrict__ Wspec,
                                                   const float* __restrict__ Wlow,
                                                   const float* __restrict__ Whigh,
                                                   const float* __restrict__ blow,
                                                   const float* __restrict__ bhigh,
                                                   __bf16* __restrict__ WspecB,
                                                   __bf16* __restrict__ WcB,
                                                   float* __restrict__ bc) {
    int i = blockIdx.x * 256 + threadIdx.x;
    if (i < COU * CINC) WspecB[i] = (__bf16)Wspec[i];
    if (i < 128 * COU) {
        WcB[i] = (__bf16)Wlow[i];
        WcB[128 * COU + i] = (__bf16)Whigh[i];
    }
    if (i < 128) { bc[i] = blow[i]; bc[128 + i] = bhigh[i]; }
}

// ---------------- KNN part: med3-u32 top-16 + exact (dist,idx) recovery ----------------
// Output: pk[bq][128] uint2 (du, idx), per-query contiguous row (streams in merge).
__global__ __launch_bounds__(256) void knn_part_kernel(const float* __restrict__ xyz,
                                                       uint2* __restrict__ pk) {
    __shared__ float4 cand[4][SEGC];
    int b = blockIdx.z;
    int lane = threadIdx.x & 63;
    int w = threadIdx.x >> 6;
    int q = blockIdx.x * 64 + lane;
    int s = blockIdx.y * 4 + w;

    const float* xb = xyz + (size_t)b * 3 * NN;

    int base = blockIdx.y * (4 * SEGC);
    for (int t = threadIdx.x; t < 4 * SEGC; t += 256) {
        int m = base + t;
        float x = xb[m], y = xb[NN + m], z = xb[2 * NN + m];
        float sq = __fadd_rn(__fadd_rn(__fmul_rn(x, x), __fmul_rn(y, y)), __fmul_rn(z, z));
        cand[t >> 8][t & (SEGC - 1)] = make_float4(x, y, z, sq);
    }
    __syncthreads();

    float qx = xb[q], qy = xb[NN + q], qz = xb[2 * NN + q];
    float qsq = __fadd_rn(__fadd_rn(__fmul_rn(qx, qx), __fmul_rn(qy, qy)), __fmul_rn(qz, qz));

    TOP_DECL
    for (int i = 0; i < SEGC; i++) {
        float4 c = cand[w][i];
        DIST_DU(c)
        TOP_INSERT(du)
    }
    unsigned int T = t15;

    int segbase = s * SEGC;
    uint2* pkb = pk + (size_t)((size_t)b * NN + q) * (SEG * KNNK) + s * KNNK;
    unsigned int fp = 0, tc = 0;
    int tb0 = 0, tb1 = 0, tb2 = 0, tb3 = 0;
    for (int i = 0; i < SEGC; i++) {
        float4 c = cand[w][i];
        DIST_DU(c)
        if (du < T) {
            pkb[fp] = make_uint2(du, (unsigned int)(segbase + i));
            fp++;
        } else if (du == T) {
            if (tc == 0) tb0 = i; else if (tc == 1) tb1 = i;
            else if (tc == 2) tb2 = i; else if (tc == 3) tb3 = i;
            tc++;
        }
    }
#define PEMIT(ti_) { pkb[fp] = make_uint2(T, (unsigned int)(segbase + (ti_))); fp++; }
    if (fp < KNNK && tc > 0) PEMIT(tb0)
    if (fp < KNNK && tc > 1) PEMIT(tb1)
    if (fp < KNNK && tc > 2) PEMIT(tb2)
    if (fp < KNNK && tc > 3) PEMIT(tb3)
    if (fp < KNNK) {               // >4 ties needed: practically never
        unsigned int ord = 0;
        for (int i = 0; i < SEGC; i++) {
            float4 c = cand[w][i];
            DIST_DU(c)
            if (du == T) { ord++; if (ord > 4 && fp < KNNK) PEMIT(i) }
        }
    }
#undef PEMIT
}

// ---------------- KNN merge: fold 8 exact 16-lists -> final top-16 + scatter ----------------
// Per-thread streaming reads of its own 1KB row; tie entries arrive in globally
// ascending idx order, so first-4 buffer + ordinal fallback = exact lowest-idx tie-break.
__global__ __launch_bounds__(128) void knn_merge_kernel(const uint2* __restrict__ pk,
                                                        int* __restrict__ knn_idx,
                                                        int* __restrict__ revcnt,
                                                        int* __restrict__ rev) {
    int bq = blockIdx.x * 128 + threadIdx.x;
    int b = bq >> 11;
    int n = bq & (NN - 1);

    const uint2* row = pk + (size_t)bq * (SEG * KNNK);

    TOP_DECL
    for (int j = 0; j < SEG * KNNK; j++) {
        unsigned int u = row[j].x;
        TOP_INSERT(u)
    }
    unsigned int T = t15;

    unsigned int fp = 0, tc = 0;
    int tb0 = 0, tb1 = 0, tb2 = 0, tb3 = 0;
#define MEMIT(x_) { int xv = (x_); knn_idx[(size_t)bq * KNNK + fp] = xv;       \
                    int pos = atomicAdd(&revcnt[b * NN + xv], 1);              \
                    if (pos < REVCAP) rev[((size_t)(b * NN + xv)) * REVCAP + pos] = n; fp++; }
    for (int j = 0; j < SEG * KNNK; j++) {
        uint2 e = row[j];
        if (e.x < T) {
            MEMIT((int)e.y)
        } else if (e.x == T) {
            if (tc == 0) tb0 = (int)e.y; else if (tc == 1) tb1 = (int)e.y;
            else if (tc == 2) tb2 = (int)e.y; else if (tc == 3) tb3 = (int)e.y;
            tc++;
        }
    }
    if (fp < KNNK && tc > 0) MEMIT(tb0)
    if (fp < KNNK && tc > 1) MEMIT(tb1)
    if (fp < KNNK && tc > 2) MEMIT(tb2)
    if (fp < KNNK && tc > 3) MEMIT(tb3)
    if (fp < KNNK) {               // >4 ties needed: practically never
        unsigned int ord = 0;
        for (int j = 0; j < SEG * KNNK; j++) {
            uint2 e = row[j];
            if (e.x == T) {
                ord++;
                if (ord > 4 && fp < KNNK) MEMIT((int)e.y)
            }
        }
    }
#undef MEMIT
}

// ---------------- dinv = rsqrt(D + 1e-6), D = 0.5*(K + indeg) ----------------
__global__ __launch_bounds__(256) void dinv_kernel(const int* __restrict__ revcnt,
                                                   float* __restrict__ dinv) {
    int i = blockIdx.x * 256 + threadIdx.x;
    if (i < BB * NN) {
        float D = 0.5f * (float)(KNNK + revcnt[i]);
        dinv[i] = 1.0f / sqrtf(D + 1e-6f);
    }
}

// ---------------- spec: f32 compute, bf16 output ----------------
__global__ __launch_bounds__(128) void spec_kernel(const float* __restrict__ fT,
                                                   const int* __restrict__ knn_idx,
                                                   const int* __restrict__ revcnt,
                                                   const int* __restrict__ rev,
                                                   const float* __restrict__ dinv,
                                                   __bf16* __restrict__ specB) {
    __shared__ int ml[KNNK + REVCAP];
    __shared__ float wl[KNNK + REVCAP];
    __shared__ int s_cnt;

    int bn = blockIdx.x;           // b*NN + n
    int b = bn >> 11;
    int tid = threadIdx.x;

    if (tid == 0) {
        int c = revcnt[bn];
        s_cnt = c < REVCAP ? c : REVCAP;
    }
    __syncthreads();
    int cnt = s_cnt;
    if (tid < KNNK) ml[tid] = knn_idx[(size_t)bn * KNNK + tid];
    if (tid < cnt) ml[KNNK + tid] = rev[(size_t)bn * REVCAP + tid];
    __syncthreads();
    int total = KNNK + cnt;
    if (tid < total) wl[tid] = 0.5f * dinv[b * NN + ml[tid]];
    __syncthreads();

    float dn = dinv[bn];
    float acc = 0.0f;
    for (int j = 0; j < total; j++)
        acc = fmaf(wl[j], fT[((size_t)b * NN + ml[j]) * CINC + tid], acc);
    float f0 = fT[(size_t)bn * CINC + tid];
    specB[(size_t)bn * CINC + tid] = (__bf16)(f0 - dn * acc);
}

// ---------------- GEMM1 (MFMA): g1 = gelu(bn(spec @ Wspec^T + b)) ----------------
__global__ __launch_bounds__(256) void gemm1_mfma(const __bf16* __restrict__ specB,
                                                  const __bf16* __restrict__ WspecB,
                                                  const float* __restrict__ bspec,
                                                  const float* __restrict__ gamma,
                                                  const float* __restrict__ beta,
                                                  const float* __restrict__ mean,
                                                  const float* __restrict__ var,
                                                  __bf16* __restrict__ g1B) {
    int b  = blockIdx.y;
    int n0 = blockIdx.x * 64;
    int w = threadIdx.x >> 6, lane = threadIdx.x & 63;
    int o0 = w * 64;                       // 4 waves tile o = 0..255
    int lr = lane & 15, lk = (lane >> 4) * 8;

    f32x4 acc[4][4] = {};
    const __bf16* As = specB + ((size_t)b * NN + n0 + lr) * CINC + lk;
    const __bf16* Bs = WspecB + (size_t)(o0 + lr) * CINC + lk;
#pragma unroll
    for (int kk = 0; kk < CINC; kk += 32) {
        bf16x8 a[4], bb[4];
#pragma unroll
        for (int m = 0; m < 4; m++)
            a[m] = *(const bf16x8*)(As + (size_t)(m * 16) * CINC + kk);
#pragma unroll
        for (int n = 0; n < 4; n++)
            bb[n] = *(const bf16x8*)(Bs + (size_t)(n * 16) * CINC + kk);
#pragma unroll
        for (int m = 0; m < 4; m++)
#pragma unroll
            for (int n = 0; n < 4; n++)
                acc[m][n] = __builtin_amdgcn_mfma_f32_16x16x32_bf16(a[m], bb[n], acc[m][n], 0, 0, 0);
    }

    int rb = (lane >> 4) * 4;
#pragma unroll
    for (int n = 0; n < 4; n++) {
        int o = o0 + n * 16 + lr;
        float sc = 1.0f / sqrtf(var[o] + 1e-5f);
        float ga = gamma[o], be = beta[o], mu = mean[o], bs = bspec[o];
#pragma unroll
        for (int m = 0; m < 4; m++) {
#pragma unroll
            for (int j = 0; j < 4; j++) {
                int nrow = n0 + m * 16 + rb + j;
                float y = acc[m][n][j] + bs;
                y = (y - mu) * sc;
                y = y * ga + be;
                float g = 0.5f * y * (1.0f + erff(y * 0.70710678118654752440f));
                g1B[((size_t)b * NN + nrow) * COU + o] = (__bf16)g;
            }
        }
    }
}

// ---------------- GEMM2 (MFMA): out[b,o,n] = Wc[o,:] @ g1[b,n,:] + bc[o] ----------------
__global__ __launch_bounds__(256) void gemm2_mfma(const __bf16* __restrict__ g1B,
                                                  const __bf16* __restrict__ WcB,
                                                  const float* __restrict__ bc,
                                                  float* __restrict__ out) {
    int b  = blockIdx.z;
    int n0 = blockIdx.x * 256;
    int o0 = blockIdx.y * 64;
    int w = threadIdx.x >> 6, lane = threadIdx.x & 63;
    int n0w = n0 + w * 64;                 // 4 waves tile n
    int lr = lane & 15, lk = (lane >> 4) * 8;

    f32x4 acc[4][4] = {};
    const __bf16* As = WcB + (size_t)(o0 + lr) * COU + lk;
    const __bf16* Bs = g1B + ((size_t)b * NN + n0w + lr) * COU + lk;
#pragma unroll
    for (int kk = 0; kk < COU; kk += 32) {
        bf16x8 a[4], bb[4];
#pragma unroll
        for (int m = 0; m < 4; m++)
            a[m] = *(const bf16x8*)(As + (size_t)(m * 16) * COU + kk);
#pragma unroll
        for (int n = 0; n < 4; n++)
            bb[n] = *(const bf16x8*)(Bs + (size_t)(n * 16) * COU + kk);
#pragma unroll
        for (int m = 0; m < 4; m++)
#pragma unroll
            for (int n = 0; n < 4; n++)
                acc[m][n] = __builtin_amdgcn_mfma_f32_16x16x32_bf16(a[m], bb[n], acc[m][n], 0, 0, 0);
    }

    int rb = (lane >> 4) * 4;
#pragma unroll
    for (int m = 0; m < 4; m++) {
#pragma unroll
        for (int j = 0; j < 4; j++) {
            int o = o0 + m * 16 + rb + j;
            float bias = bc[o];
#pragma unroll
            for (int n = 0; n < 4; n++) {
                int ncol = n0w + n * 16 + lr;
                out[((size_t)b * COU + o) * NN + ncol] = acc[m][n][j] + bias;
            }
        }
    }
}

extern "C" void kernel_launch(void* const* d_in, const int* in_sizes, int n_in,
                              void* d_out, int out_size, void* d_ws, size_t ws_size,
                              hipStream_t stream) {
    const float* xyz      = (const float*)d_in[0];
    const float* features = (const float*)d_in[1];
    const float* W_spec   = (const float*)d_in[2];
    const float* b_spec   = (const float*)d_in[3];
    const float* bn_gamma = (const float*)d_in[4];
    const float* bn_beta  = (const float*)d_in[5];
    const float* bn_mean  = (const float*)d_in[6];
    const float* bn_var   = (const float*)d_in[7];
    const float* W_low    = (const float*)d_in[8];
    const float* b_low    = (const float*)d_in[9];
    const float* W_high   = (const float*)d_in[10];
    const float* b_high   = (const float*)d_in[11];
    float* out = (float*)d_out;

    char* ws = (char*)d_ws;
    size_t off = 0;
    float*  fT    = (float*)(ws + off);  off += (size_t)BB * NN * CINC * 4;      // 8 MB
    __bf16* specB = (__bf16*)(ws + off); off += (size_t)BB * NN * CINC * 2;      // 4 MB
    __bf16* g1B   = (__bf16*)(ws + off); off += (size_t)BB * NN * COU  * 2;      // 8 MB
    int*    idx   = (int*)(ws + off);    off += (size_t)BB * NN * KNNK * 4;      // 1 MB
    int*    rcnt  = (int*)(ws + off);    off += (size_t)BB * NN * 4;             // 64 KB
    int*    rev   = (int*)(ws + off);    off += (size_t)BB * NN * REVCAP * 4;    // 4 MB
    float*  dinv  = (float*)(ws + off);  off += (size_t)BB * NN * 4;             // 64 KB
    uint2*  pk    = (uint2*)(ws + off);  off += (size_t)BN * SEG * KNNK * 8;     // 16 MB
    __bf16* WspecB= (__bf16*)(ws + off); off += (size_t)COU * CINC * 2;          // 64 KB
    __bf16* WcB   = (__bf16*)(ws + off); off += (size_t)COU * COU * 2;           // 128 KB
    float*  bc    = (float*)(ws + off);  off += (size_t)COU * 4;                 // 1 KB

    hipMemsetAsync(rcnt, 0, (size_t)BB * NN * sizeof(int), stream);

    prep_kernel<<<dim3((COU * CINC + 255) / 256), dim3(256), 0, stream>>>(
        W_spec, W_low, W_high, b_low, b_high, WspecB, WcB, bc);
    transpose_kernel<<<dim3(NN / 32, CINC / 32, BB), dim3(32, 8), 0, stream>>>(features, fT);
    knn_part_kernel<<<dim3(NN / 64, SEG / 4, BB), dim3(256), 0, stream>>>(xyz, pk);
    knn_merge_kernel<<<dim3(BN / 128), dim3(128), 0, stream>>>(pk, idx, rcnt, rev);
    dinv_kernel<<<dim3(BB * NN / 256), dim3(256), 0, stream>>>(rcnt, dinv);
    spec_kernel<<<dim3(BB * NN), dim3(128), 0, stream>>>(fT, idx, rcnt, rev, dinv, specB);
    gemm1_mfma<<<dim3(NN / 64, BB), dim3(256), 0, stream>>>(
        specB, WspecB, b_spec, bn_gamma, bn_beta, bn_mean, bn_var, g1B);
    gemm2_mfma<<<dim3(NN / 256, COU / 64, BB), dim3(256), 0, stream>>>(g1B, WcB, bc, out);
}

// Round 12
// 209.716 us; speedup vs baseline: 1.2306x; 1.0903x over previous
//
#include <hip/hip_runtime.h>
#include <hip/hip_bf16.h>
#include <math.h>

#define BB   8
#define NN   2048
#define BN   (BB * NN)
#define CINC 128
#define COU  256
#define KNNK 16
#define REVCAP 64
#define SEG   8
#define SEGC  (NN / SEG)   // 256 candidates per segment

typedef __bf16 bf16x8 __attribute__((ext_vector_type(8)));
typedef float  f32x4  __attribute__((ext_vector_type(4)));

// Single-instruction sorted-insert step: for ascending t_{j-1} <= t_j,
// new t_j = median(t_{j-1}, t_j, key). v_med3_u32 = 1 VOP3 op.
#define UMED3(dst, a, bb_, c) asm("v_med3_u32 %0, %1, %2, %3" : "=v"(dst) : "v"(a), "v"(bb_), "v"(c))

#define TOP_DECL \
    unsigned int t0=~0u,t1=~0u,t2=~0u,t3=~0u,t4=~0u,t5=~0u,t6=~0u,t7=~0u, \
                 t8=~0u,t9=~0u,t10=~0u,t11=~0u,t12=~0u,t13=~0u,t14=~0u,t15=~0u;

// Insert u into sorted multiset {t0..t15}, dropping the max. 15 med3 + 1 min.
#define TOP_INSERT(u) {                     \
    UMED3(t15, t14, t15, (u));              \
    UMED3(t14, t13, t14, (u));              \
    UMED3(t13, t12, t13, (u));              \
    UMED3(t12, t11, t12, (u));              \
    UMED3(t11, t10, t11, (u));              \
    UMED3(t10, t9,  t10, (u));              \
    UMED3(t9,  t8,  t9,  (u));              \
    UMED3(t8,  t7,  t8,  (u));              \
    UMED3(t7,  t6,  t7,  (u));              \
    UMED3(t6,  t5,  t6,  (u));              \
    UMED3(t5,  t4,  t5,  (u));              \
    UMED3(t4,  t3,  t4,  (u));              \
    UMED3(t3,  t2,  t3,  (u));              \
    UMED3(t2,  t1,  t2,  (u));              \
    UMED3(t1,  t0,  t1,  (u));              \
    t0 = ((u) < t0) ? (u) : t0;             \
}

// dist arithmetic: bit-identical to the verified R1-R11 formula.
#define DIST_DU(c_)                                                              \
    float dot = fmaf(qz, (c_).z, fmaf(qy, (c_).y, __fmul_rn(qx, (c_).x)));       \
    float d = __fsub_rn(__fadd_rn(qsq, (c_).w), __fmul_rn(2.0f, dot));           \
    unsigned int du = __float_as_uint(d);                                        \
    du ^= (unsigned int)((int)du >> 31) | 0x80000000u;

// ---------------- transpose features (B,C,N) -> fT (B,N,C) ----------------
__global__ __launch_bounds__(256) void transpose_kernel(const float* __restrict__ feat,
                                                        float* __restrict__ fT) {
    __shared__ float t[32][33];
    int b  = blockIdx.z;
    int n0 = blockIdx.x * 32, c0 = blockIdx.y * 32;
    int tx = threadIdx.x, ty = threadIdx.y;  // (32,8)
#pragma unroll
    for (int i = 0; i < 4; i++)
        t[ty + i * 8][tx] = feat[((size_t)b * CINC + c0 + ty + i * 8) * NN + n0 + tx];
    __syncthreads();
#pragma unroll
    for (int i = 0; i < 4; i++)
        fT[((size_t)b * NN + n0 + ty + i * 8) * CINC + c0 + tx] = t[tx][ty + i * 8];
}

// ---------------- prep: cast weights to bf16, concat W2 & bias ----------------
__global__ __launch_bounds__(256) void prep_kernel(const float* __restrict__ Wspec,
                                                   const float* __restrict__ Wlow,
                                                   const float* __restrict__ Whigh,
                                                   const float* __restrict__ blow,
                                                   const float* __restrict__ bhigh,
                                                   __bf16* __restrict__ WspecB,
                                                   __bf16* __restrict__ WcB,
                                                   float* __restrict__ bc) {
    int i = blockIdx.x * 256 + threadIdx.x;
    if (i < COU * CINC) WspecB[i] = (__bf16)Wspec[i];
    if (i < 128 * COU) {
        WcB[i] = (__bf16)Wlow[i];
        WcB[128 * COU + i] = (__bf16)Whigh[i];
    }
    if (i < 128) { bc[i] = blow[i]; bc[128 + i] = bhigh[i]; }
}

// ---------------- KNN fused: per-wave segment top-16 + in-LDS merge ----------------
// Block = 512 threads = 8 waves; one block per 64-query group. Wave w scans
// segment w (256 cands staged in LDS): phase A med3-u32 top-16 -> T_w; phase B
// emits exactly 16 (du,idx) per (query,segment) into LDS part[k][w][lane] with
// the verified first-4-ties + ordinal-fallback recovery. After barrier, wave 0
// merges each query's 8x16 LDS lists (w-outer scan preserves ascending-idx tie
// order) and scatters knn_idx + reverse edges. Selection semantics identical to
// the HW-verified R10/R11 two-kernel path; global merge round-trip eliminated.
__global__ __launch_bounds__(512) void knn_fused_kernel(const float* __restrict__ xyz,
                                                        int* __restrict__ knn_idx,
                                                        int* __restrict__ revcnt,
                                                        int* __restrict__ rev) {
    __shared__ float4 cand[NN];             // 32 KB
    __shared__ uint2 part[KNNK][SEG][64];   // 64 KB
    int b = blockIdx.y;
    int lane = threadIdx.x & 63;
    int w = threadIdx.x >> 6;               // wave id = segment
    int q = blockIdx.x * 64 + lane;

    const float* xb = xyz + (size_t)b * 3 * NN;
    for (int t = threadIdx.x; t < NN; t += 512) {
        float x = xb[t], y = xb[NN + t], z = xb[2 * NN + t];
        float sq = __fadd_rn(__fadd_rn(__fmul_rn(x, x), __fmul_rn(y, y)), __fmul_rn(z, z));
        cand[t] = make_float4(x, y, z, sq);
    }
    __syncthreads();

    {   // ---- per-wave phase A + B over segment w ----
        float qx = xb[q], qy = xb[NN + q], qz = xb[2 * NN + q];
        float qsq = __fadd_rn(__fadd_rn(__fmul_rn(qx, qx), __fmul_rn(qy, qy)), __fmul_rn(qz, qz));
        int segbase = w * SEGC;

        TOP_DECL
        for (int i = 0; i < SEGC; i++) {
            float4 c = cand[segbase + i];
            DIST_DU(c)
            TOP_INSERT(du)
        }
        unsigned int T = t15;

        unsigned int fp = 0, tc = 0;
        int tb0 = 0, tb1 = 0, tb2 = 0, tb3 = 0;
        for (int i = 0; i < SEGC; i++) {
            float4 c = cand[segbase + i];
            DIST_DU(c)
            if (du < T) {
                part[fp][w][lane] = make_uint2(du, (unsigned int)(segbase + i));
                fp++;
            } else if (du == T) {
                if (tc == 0) tb0 = i; else if (tc == 1) tb1 = i;
                else if (tc == 2) tb2 = i; else if (tc == 3) tb3 = i;
                tc++;
            }
        }
#define PEMIT(ti_) { part[fp][w][lane] = make_uint2(T, (unsigned int)(segbase + (ti_))); fp++; }
        if (fp < KNNK && tc > 0) PEMIT(tb0)
        if (fp < KNNK && tc > 1) PEMIT(tb1)
        if (fp < KNNK && tc > 2) PEMIT(tb2)
        if (fp < KNNK && tc > 3) PEMIT(tb3)
        if (fp < KNNK) {               // >4 ties needed: practically never
            unsigned int ord = 0;
            for (int i = 0; i < SEGC; i++) {
                float4 c = cand[segbase + i];
                DIST_DU(c)
                if (du == T) { ord++; if (ord > 4 && fp < KNNK) PEMIT(i) }
            }
        }
#undef PEMIT
    }
    __syncthreads();

    // ---- merge: wave 0, lane = query ----
    if (threadIdx.x < 64) {
        int bq = b * NN + q;

        TOP_DECL
        for (int w2 = 0; w2 < SEG; w2++)
            for (int k = 0; k < KNNK; k++) {
                unsigned int u = part[k][w2][lane].x;
                TOP_INSERT(u)
            }
        unsigned int T = t15;

        unsigned int fp = 0, tc = 0;
        int tb0 = 0, tb1 = 0, tb2 = 0, tb3 = 0;
#define MEMIT(x_) { int xv = (x_); knn_idx[(size_t)bq * KNNK + fp] = xv;       \
                    int pos = atomicAdd(&revcnt[b * NN + xv], 1);              \
                    if (pos < REVCAP) rev[((size_t)(b * NN + xv)) * REVCAP + pos] = q; fp++; }
        for (int w2 = 0; w2 < SEG; w2++)
            for (int k = 0; k < KNNK; k++) {
                uint2 e = part[k][w2][lane];
                if (e.x < T) {
                    MEMIT((int)e.y)
                } else if (e.x == T) {
                    if (tc == 0) tb0 = (int)e.y; else if (tc == 1) tb1 = (int)e.y;
                    else if (tc == 2) tb2 = (int)e.y; else if (tc == 3) tb3 = (int)e.y;
                    tc++;
                }
            }
        if (fp < KNNK && tc > 0) MEMIT(tb0)
        if (fp < KNNK && tc > 1) MEMIT(tb1)
        if (fp < KNNK && tc > 2) MEMIT(tb2)
        if (fp < KNNK && tc > 3) MEMIT(tb3)
        if (fp < KNNK) {               // >4 ties needed: practically never
            unsigned int ord = 0;
            for (int w2 = 0; w2 < SEG; w2++)
                for (int k = 0; k < KNNK; k++) {
                    uint2 e = part[k][w2][lane];
                    if (e.x == T) {
                        ord++;
                        if (ord > 4 && fp < KNNK) MEMIT((int)e.y)
                    }
                }
        }
#undef MEMIT
    }
}

// ---------------- dinv = rsqrt(D + 1e-6), D = 0.5*(K + indeg) ----------------
__global__ __launch_bounds__(256) void dinv_kernel(const int* __restrict__ revcnt,
                                                   float* __restrict__ dinv) {
    int i = blockIdx.x * 256 + threadIdx.x;
    if (i < BB * NN) {
        float D = 0.5f * (float)(KNNK + revcnt[i]);
        dinv[i] = 1.0f / sqrtf(D + 1e-6f);
    }
}

// ---------------- spec: f32 compute, bf16 output ----------------
__global__ __launch_bounds__(128) void spec_kernel(const float* __restrict__ fT,
                                                   const int* __restrict__ knn_idx,
                                                   const int* __restrict__ revcnt,
                                                   const int* __restrict__ rev,
                                                   const float* __restrict__ dinv,
                                                   __bf16* __restrict__ specB) {
    __shared__ int ml[KNNK + REVCAP];
    __shared__ float wl[KNNK + REVCAP];
    __shared__ int s_cnt;

    int bn = blockIdx.x;           // b*NN + n
    int b = bn >> 11;
    int tid = threadIdx.x;

    if (tid == 0) {
        int c = revcnt[bn];
        s_cnt = c < REVCAP ? c : REVCAP;
    }
    __syncthreads();
    int cnt = s_cnt;
    if (tid < KNNK) ml[tid] = knn_idx[(size_t)bn * KNNK + tid];
    if (tid < cnt) ml[KNNK + tid] = rev[(size_t)bn * REVCAP + tid];
    __syncthreads();
    int total = KNNK + cnt;
    if (tid < total) wl[tid] = 0.5f * dinv[b * NN + ml[tid]];
    __syncthreads();

    float dn = dinv[bn];
    float acc = 0.0f;
    for (int j = 0; j < total; j++)
        acc = fmaf(wl[j], fT[((size_t)b * NN + ml[j]) * CINC + tid], acc);
    float f0 = fT[(size_t)bn * CINC + tid];
    specB[(size_t)bn * CINC + tid] = (__bf16)(f0 - dn * acc);
}

// ---------------- GEMM1 (MFMA): g1 = gelu(bn(spec @ Wspec^T + b)) ----------------
__global__ __launch_bounds__(256) void gemm1_mfma(const __bf16* __restrict__ specB,
                                                  const __bf16* __restrict__ WspecB,
                                                  const float* __restrict__ bspec,
                                                  const float* __restrict__ gamma,
                                                  const float* __restrict__ beta,
                                                  const float* __restrict__ mean,
                                                  const float* __restrict__ var,
                                                  __bf16* __restrict__ g1B) {
    int b  = blockIdx.y;
    int n0 = blockIdx.x * 64;
    int w = threadIdx.x >> 6, lane = threadIdx.x & 63;
    int o0 = w * 64;                       // 4 waves tile o = 0..255
    int lr = lane & 15, lk = (lane >> 4) * 8;

    f32x4 acc[4][4] = {};
    const __bf16* As = specB + ((size_t)b * NN + n0 + lr) * CINC + lk;
    const __bf16* Bs = WspecB + (size_t)(o0 + lr) * CINC + lk;
#pragma unroll
    for (int kk = 0; kk < CINC; kk += 32) {
        bf16x8 a[4], bb[4];
#pragma unroll
        for (int m = 0; m < 4; m++)
            a[m] = *(const bf16x8*)(As + (size_t)(m * 16) * CINC + kk);
#pragma unroll
        for (int n = 0; n < 4; n++)
            bb[n] = *(const bf16x8*)(Bs + (size_t)(n * 16) * CINC + kk);
#pragma unroll
        for (int m = 0; m < 4; m++)
#pragma unroll
            for (int n = 0; n < 4; n++)
                acc[m][n] = __builtin_amdgcn_mfma_f32_16x16x32_bf16(a[m], bb[n], acc[m][n], 0, 0, 0);
    }

    int rb = (lane >> 4) * 4;
#pragma unroll
    for (int n = 0; n < 4; n++) {
        int o = o0 + n * 16 + lr;
        float sc = 1.0f / sqrtf(var[o] + 1e-5f);
        float ga = gamma[o], be = beta[o], mu = mean[o], bs = bspec[o];
#pragma unroll
        for (int m = 0; m < 4; m++) {
#pragma unroll
            for (int j = 0; j < 4; j++) {
                int nrow = n0 + m * 16 + rb + j;
                float y = acc[m][n][j] + bs;
                y = (y - mu) * sc;
                y = y * ga + be;
                float g = 0.5f * y * (1.0f + erff(y * 0.70710678118654752440f));
                g1B[((size_t)b * NN + nrow) * COU + o] = (__bf16)g;
            }
        }
    }
}

// ---------------- GEMM2 (MFMA): out[b,o,n] = Wc[o,:] @ g1[b,n,:] + bc[o] ----------------
__global__ __launch_bounds__(256) void gemm2_mfma(const __bf16* __restrict__ g1B,
                                                  const __bf16* __restrict__ WcB,
                                                  const float* __restrict__ bc,
                                                  float* __restrict__ out) {
    int b  = blockIdx.z;
    int n0 = blockIdx.x * 256;
    int o0 = blockIdx.y * 64;
    int w = threadIdx.x >> 6, lane = threadIdx.x & 63;
    int n0w = n0 + w * 64;                 // 4 waves tile n
    int lr = lane & 15, lk = (lane >> 4) * 8;

    f32x4 acc[4][4] = {};
    const __bf16* As = WcB + (size_t)(o0 + lr) * COU + lk;
    const __bf16* Bs = g1B + ((size_t)b * NN + n0w + lr) * COU + lk;
#pragma unroll
    for (int kk = 0; kk < COU; kk += 32) {
        bf16x8 a[4], bb[4];
#pragma unroll
        for (int m = 0; m < 4; m++)
            a[m] = *(const bf16x8*)(As + (size_t)(m * 16) * COU + kk);
#pragma unroll
        for (int n = 0; n < 4; n++)
            bb[n] = *(const bf16x8*)(Bs + (size_t)(n * 16) * COU + kk);
#pragma unroll
        for (int m = 0; m < 4; m++)
#pragma unroll
            for (int n = 0; n < 4; n++)
                acc[m][n] = __builtin_amdgcn_mfma_f32_16x16x32_bf16(a[m], bb[n], acc[m][n], 0, 0, 0);
    }

    int rb = (lane >> 4) * 4;
#pragma unroll
    for (int m = 0; m < 4; m++) {
#pragma unroll
        for (int j = 0; j < 4; j++) {
            int o = o0 + m * 16 + rb + j;
            float bias = bc[o];
#pragma unroll
            for (int n = 0; n < 4; n++) {
                int ncol = n0w + n * 16 + lr;
                out[((size_t)b * COU + o) * NN + ncol] = acc[m][n][j] + bias;
            }
        }
    }
}

extern "C" void kernel_launch(void* const* d_in, const int* in_sizes, int n_in,
                              void* d_out, int out_size, void* d_ws, size_t ws_size,
                              hipStream_t stream) {
    const float* xyz      = (const float*)d_in[0];
    const float* features = (const float*)d_in[1];
    const float* W_spec   = (const float*)d_in[2];
    const float* b_spec   = (const float*)d_in[3];
    const float* bn_gamma = (const float*)d_in[4];
    const float* bn_beta  = (const float*)d_in[5];
    const float* bn_mean  = (const float*)d_in[6];
    const float* bn_var   = (const float*)d_in[7];
    const float* W_low    = (const float*)d_in[8];
    const float* b_low    = (const float*)d_in[9];
    const float* W_high   = (const float*)d_in[10];
    const float* b_high   = (const float*)d_in[11];
    float* out = (float*)d_out;

    char* ws = (char*)d_ws;
    size_t off = 0;
    float*  fT    = (float*)(ws + off);  off += (size_t)BB * NN * CINC * 4;      // 8 MB
    __bf16* specB = (__bf16*)(ws + off); off += (size_t)BB * NN * CINC * 2;      // 4 MB
    __bf16* g1B   = (__bf16*)(ws + off); off += (size_t)BB * NN * COU  * 2;      // 8 MB
    int*    idx   = (int*)(ws + off);    off += (size_t)BB * NN * KNNK * 4;      // 1 MB
    int*    rcnt  = (int*)(ws + off);    off += (size_t)BB * NN * 4;             // 64 KB
    int*    rev   = (int*)(ws + off);    off += (size_t)BB * NN * REVCAP * 4;    // 4 MB
    float*  dinv  = (float*)(ws + off);  off += (size_t)BB * NN * 4;             // 64 KB
    __bf16* WspecB= (__bf16*)(ws + off); off += (size_t)COU * CINC * 2;          // 64 KB
    __bf16* WcB   = (__bf16*)(ws + off); off += (size_t)COU * COU * 2;           // 128 KB
    float*  bc    = (float*)(ws + off);  off += (size_t)COU * 4;                 // 1 KB

    hipMemsetAsync(rcnt, 0, (size_t)BB * NN * sizeof(int), stream);

    prep_kernel<<<dim3((COU * CINC + 255) / 256), dim3(256), 0, stream>>>(
        W_spec, W_low, W_high, b_low, b_high, WspecB, WcB, bc);
    transpose_kernel<<<dim3(NN / 32, CINC / 32, BB), dim3(32, 8), 0, stream>>>(features, fT);
    knn_fused_kernel<<<dim3(NN / 64, BB), dim3(512), 0, stream>>>(xyz, idx, rcnt, rev);
    dinv_kernel<<<dim3(BB * NN / 256), dim3(256), 0, stream>>>(rcnt, dinv);
    spec_kernel<<<dim3(BB * NN), dim3(128), 0, stream>>>(fT, idx, rcnt, rev, dinv, specB);
    gemm1_mfma<<<dim3(NN / 64, BB), dim3(256), 0, stream>>>(
        specB, WspecB, b_spec, bn_gamma, bn_beta, bn_mean, bn_var, g1B);
    gemm2_mfma<<<dim3(NN / 256, COU / 64, BB), dim3(256), 0, stream>>>(g1B, WcB, bc, out);
}

// Round 13
// 198.191 us; speedup vs baseline: 1.3022x; 1.0581x over previous
//
#include <hip/hip_runtime.h>
#include <hip/hip_bf16.h>
#include <math.h>

#define BB   8
#define NN   2048
#define BN   (BB * NN)
#define CINC 128
#define COU  256
#define KNNK 16
#define REVCAP 64
#define SEG   8
#define SEGC  (NN / SEG)   // 256 candidates per segment

typedef __bf16 bf16x8 __attribute__((ext_vector_type(8)));
typedef float  f32x4  __attribute__((ext_vector_type(4)));

// Single-instruction sorted-insert step: for ascending t_{j-1} <= t_j,
// new t_j = median(t_{j-1}, t_j, key). v_med3_u32 = 1 VOP3 op.
#define UMED3(dst, a, bb_, c) asm("v_med3_u32 %0, %1, %2, %3" : "=v"(dst) : "v"(a), "v"(bb_), "v"(c))

#define TOP_DECL \
    unsigned int t0=~0u,t1=~0u,t2=~0u,t3=~0u,t4=~0u,t5=~0u,t6=~0u,t7=~0u, \
                 t8=~0u,t9=~0u,t10=~0u,t11=~0u,t12=~0u,t13=~0u,t14=~0u,t15=~0u;

// Insert u into sorted multiset {t0..t15}, dropping the max. 15 med3 + 1 min.
#define TOP_INSERT(u) {                     \
    UMED3(t15, t14, t15, (u));              \
    UMED3(t14, t13, t14, (u));              \
    UMED3(t13, t12, t13, (u));              \
    UMED3(t12, t11, t12, (u));              \
    UMED3(t11, t10, t11, (u));              \
    UMED3(t10, t9,  t10, (u));              \
    UMED3(t9,  t8,  t9,  (u));              \
    UMED3(t8,  t7,  t8,  (u));              \
    UMED3(t7,  t6,  t7,  (u));              \
    UMED3(t6,  t5,  t6,  (u));              \
    UMED3(t5,  t4,  t5,  (u));              \
    UMED3(t4,  t3,  t4,  (u));              \
    UMED3(t3,  t2,  t3,  (u));              \
    UMED3(t2,  t1,  t2,  (u));              \
    UMED3(t1,  t0,  t1,  (u));              \
    t0 = ((u) < t0) ? (u) : t0;             \
}

// dist arithmetic: bit-identical to the verified R1-R12 formula.
static __device__ __forceinline__ unsigned int dist_du(float qx, float qy, float qz,
                                                       float qsq, float4 c) {
    float dot = fmaf(qz, c.z, fmaf(qy, c.y, __fmul_rn(qx, c.x)));
    float d = __fsub_rn(__fadd_rn(qsq, c.w), __fmul_rn(2.0f, dot));
    unsigned int du = __float_as_uint(d);
    du ^= (unsigned int)((int)du >> 31) | 0x80000000u;
    return du;
}

// ---------------- transpose features (B,C,N) -> fT (B,N,C) ----------------
__global__ __launch_bounds__(256) void transpose_kernel(const float* __restrict__ feat,
                                                        float* __restrict__ fT) {
    __shared__ float t[32][33];
    int b  = blockIdx.z;
    int n0 = blockIdx.x * 32, c0 = blockIdx.y * 32;
    int tx = threadIdx.x, ty = threadIdx.y;  // (32,8)
#pragma unroll
    for (int i = 0; i < 4; i++)
        t[ty + i * 8][tx] = feat[((size_t)b * CINC + c0 + ty + i * 8) * NN + n0 + tx];
    __syncthreads();
#pragma unroll
    for (int i = 0; i < 4; i++)
        fT[((size_t)b * NN + n0 + ty + i * 8) * CINC + c0 + tx] = t[tx][ty + i * 8];
}

// ---------------- prep: cast weights to bf16, concat W2 & bias ----------------
__global__ __launch_bounds__(256) void prep_kernel(const float* __restrict__ Wspec,
                                                   const float* __restrict__ Wlow,
                                                   const float* __restrict__ Whigh,
                                                   const float* __restrict__ blow,
                                                   const float* __restrict__ bhigh,
                                                   __bf16* __restrict__ WspecB,
                                                   __bf16* __restrict__ WcB,
                                                   float* __restrict__ bc) {
    int i = blockIdx.x * 256 + threadIdx.x;
    if (i < COU * CINC) WspecB[i] = (__bf16)Wspec[i];
    if (i < 128 * COU) {
        WcB[i] = (__bf16)Wlow[i];
        WcB[128 * COU + i] = (__bf16)Whigh[i];
    }
    if (i < 128) { bc[i] = blow[i]; bc[128 + i] = bhigh[i]; }
}

// ---------------- KNN fused: per-wave segment top-16 + in-LDS merge ----------------
// Same verified structure as R12, with two latency fixes:
//  (1) scans manually batched 4x: 4 ds_read_b128 issued together, then 4 bodies
//      -> LDS latency amortized 4x instead of serialized per iteration.
//  (2) partials split into u32 du (32KB) + u16 local idx (16KB): LDS 98->80KB
//      -> 2 blocks/CU (4 waves/SIMD), merge tail overlapped by second block.
// Selection semantics byte-identical (emission order & tie handling unchanged).
__global__ __launch_bounds__(512, 4) void knn_fused_kernel(const float* __restrict__ xyz,
                                                           int* __restrict__ knn_idx,
                                                           int* __restrict__ revcnt,
                                                           int* __restrict__ rev) {
    __shared__ float4 cand[NN];                        // 32 KB
    __shared__ unsigned int   pduL[KNNK][SEG][64];     // 32 KB
    __shared__ unsigned short pidxL[KNNK][SEG][64];    // 16 KB
    int b = blockIdx.y;
    int lane = threadIdx.x & 63;
    int w = threadIdx.x >> 6;               // wave id = segment
    int q = blockIdx.x * 64 + lane;

    const float* xb = xyz + (size_t)b * 3 * NN;
    for (int t = threadIdx.x; t < NN; t += 512) {
        float x = xb[t], y = xb[NN + t], z = xb[2 * NN + t];
        float sq = __fadd_rn(__fadd_rn(__fmul_rn(x, x), __fmul_rn(y, y)), __fmul_rn(z, z));
        cand[t] = make_float4(x, y, z, sq);
    }
    __syncthreads();

    {   // ---- per-wave phase A + B over segment w ----
        float qx = xb[q], qy = xb[NN + q], qz = xb[2 * NN + q];
        float qsq = __fadd_rn(__fadd_rn(__fmul_rn(qx, qx), __fmul_rn(qy, qy)), __fmul_rn(qz, qz));
        int segbase = w * SEGC;

        TOP_DECL
        for (int i = 0; i < SEGC; i += 4) {
            float4 c0 = cand[segbase + i + 0];
            float4 c1 = cand[segbase + i + 1];
            float4 c2 = cand[segbase + i + 2];
            float4 c3 = cand[segbase + i + 3];
            unsigned int d0 = dist_du(qx, qy, qz, qsq, c0);
            unsigned int d1 = dist_du(qx, qy, qz, qsq, c1);
            unsigned int d2 = dist_du(qx, qy, qz, qsq, c2);
            unsigned int d3 = dist_du(qx, qy, qz, qsq, c3);
            TOP_INSERT(d0)
            TOP_INSERT(d1)
            TOP_INSERT(d2)
            TOP_INSERT(d3)
        }
        unsigned int T = t15;

        unsigned int fp = 0, tc = 0;
        int tb0 = 0, tb1 = 0, tb2 = 0, tb3 = 0;
#define PBODY(dj_, ii_) \
        if ((dj_) < T) { \
            pduL[fp][w][lane] = (dj_); pidxL[fp][w][lane] = (unsigned short)(ii_); fp++; \
        } else if ((dj_) == T) { \
            if (tc == 0) tb0 = (ii_); else if (tc == 1) tb1 = (ii_); \
            else if (tc == 2) tb2 = (ii_); else if (tc == 3) tb3 = (ii_); \
            tc++; \
        }
        for (int i = 0; i < SEGC; i += 4) {
            float4 c0 = cand[segbase + i + 0];
            float4 c1 = cand[segbase + i + 1];
            float4 c2 = cand[segbase + i + 2];
            float4 c3 = cand[segbase + i + 3];
            unsigned int d0 = dist_du(qx, qy, qz, qsq, c0);
            unsigned int d1 = dist_du(qx, qy, qz, qsq, c1);
            unsigned int d2 = dist_du(qx, qy, qz, qsq, c2);
            unsigned int d3 = dist_du(qx, qy, qz, qsq, c3);
            PBODY(d0, i + 0)
            PBODY(d1, i + 1)
            PBODY(d2, i + 2)
            PBODY(d3, i + 3)
        }
#undef PBODY
#define PEMIT(ti_) { pduL[fp][w][lane] = T; pidxL[fp][w][lane] = (unsigned short)(ti_); fp++; }
        if (fp < KNNK && tc > 0) PEMIT(tb0)
        if (fp < KNNK && tc > 1) PEMIT(tb1)
        if (fp < KNNK && tc > 2) PEMIT(tb2)
        if (fp < KNNK && tc > 3) PEMIT(tb3)
        if (fp < KNNK) {               // >4 ties needed: practically never
            unsigned int ord = 0;
            for (int i = 0; i < SEGC; i++) {
                unsigned int du = dist_du(qx, qy, qz, qsq, cand[segbase + i]);
                if (du == T) { ord++; if (ord > 4 && fp < KNNK) PEMIT(i) }
            }
        }
#undef PEMIT
    }
    __syncthreads();

    // ---- merge: wave 0, lane = query ----
    if (threadIdx.x < 64) {
        int bq = b * NN + q;

        TOP_DECL
        for (int w2 = 0; w2 < SEG; w2++) {
#pragma unroll
            for (int k = 0; k < KNNK; k++) {
                unsigned int u = pduL[k][w2][lane];
                TOP_INSERT(u)
            }
        }
        unsigned int T = t15;

        unsigned int fp = 0, tc = 0;
        int tb0 = 0, tb1 = 0, tb2 = 0, tb3 = 0;
#define MEMIT(x_) { int xv = (x_); knn_idx[(size_t)bq * KNNK + fp] = xv;       \
                    int pos = atomicAdd(&revcnt[b * NN + xv], 1);              \
                    if (pos < REVCAP) rev[((size_t)(b * NN + xv)) * REVCAP + pos] = q; fp++; }
        for (int w2 = 0; w2 < SEG; w2++) {
#pragma unroll
            for (int k = 0; k < KNNK; k++) {
                unsigned int u = pduL[k][w2][lane];
                int gx = w2 * SEGC + (int)pidxL[k][w2][lane];
                if (u < T) {
                    MEMIT(gx)
                } else if (u == T) {
                    if (tc == 0) tb0 = gx; else if (tc == 1) tb1 = gx;
                    else if (tc == 2) tb2 = gx; else if (tc == 3) tb3 = gx;
                    tc++;
                }
            }
        }
        if (fp < KNNK && tc > 0) MEMIT(tb0)
        if (fp < KNNK && tc > 1) MEMIT(tb1)
        if (fp < KNNK && tc > 2) MEMIT(tb2)
        if (fp < KNNK && tc > 3) MEMIT(tb3)
        if (fp < KNNK) {               // >4 ties needed: practically never
            unsigned int ord = 0;
            for (int w2 = 0; w2 < SEG; w2++) {
                for (int k = 0; k < KNNK; k++) {
                    unsigned int u = pduL[k][w2][lane];
                    if (u == T) {
                        ord++;
                        if (ord > 4 && fp < KNNK) {
                            int gx = w2 * SEGC + (int)pidxL[k][w2][lane];
                            MEMIT(gx)
                        }
                    }
                }
            }
        }
#undef MEMIT
    }
}

// ---------------- dinv = rsqrt(D + 1e-6), D = 0.5*(K + indeg) ----------------
__global__ __launch_bounds__(256) void dinv_kernel(const int* __restrict__ revcnt,
                                                   float* __restrict__ dinv) {
    int i = blockIdx.x * 256 + threadIdx.x;
    if (i < BB * NN) {
        float D = 0.5f * (float)(KNNK + revcnt[i]);
        dinv[i] = 1.0f / sqrtf(D + 1e-6f);
    }
}

// ---------------- spec: f32 compute, bf16 output ----------------
__global__ __launch_bounds__(128) void spec_kernel(const float* __restrict__ fT,
                                                   const int* __restrict__ knn_idx,
                                                   const int* __restrict__ revcnt,
                                                   const int* __restrict__ rev,
                                                   const float* __restrict__ dinv,
                                                   __bf16* __restrict__ specB) {
    __shared__ int ml[KNNK + REVCAP];
    __shared__ float wl[KNNK + REVCAP];
    __shared__ int s_cnt;

    int bn = blockIdx.x;           // b*NN + n
    int b = bn >> 11;
    int tid = threadIdx.x;

    if (tid == 0) {
        int c = revcnt[bn];
        s_cnt = c < REVCAP ? c : REVCAP;
    }
    __syncthreads();
    int cnt = s_cnt;
    if (tid < KNNK) ml[tid] = knn_idx[(size_t)bn * KNNK + tid];
    if (tid < cnt) ml[KNNK + tid] = rev[(size_t)bn * REVCAP + tid];
    __syncthreads();
    int total = KNNK + cnt;
    if (tid < total) wl[tid] = 0.5f * dinv[b * NN + ml[tid]];
    __syncthreads();

    float dn = dinv[bn];
    float acc = 0.0f;
    for (int j = 0; j < total; j++)
        acc = fmaf(wl[j], fT[((size_t)b * NN + ml[j]) * CINC + tid], acc);
    float f0 = fT[(size_t)bn * CINC + tid];
    specB[(size_t)bn * CINC + tid] = (__bf16)(f0 - dn * acc);
}

// ---------------- GEMM1 (MFMA): g1 = gelu(bn(spec @ Wspec^T + b)) ----------------
__global__ __launch_bounds__(256) void gemm1_mfma(const __bf16* __restrict__ specB,
                                                  const __bf16* __restrict__ WspecB,
                                                  const float* __restrict__ bspec,
                                                  const float* __restrict__ gamma,
                                                  const float* __restrict__ beta,
                                                  const float* __restrict__ mean,
                                                  const float* __restrict__ var,
                                                  __bf16* __restrict__ g1B) {
    int b  = blockIdx.y;
    int n0 = blockIdx.x * 64;
    int w = threadIdx.x >> 6, lane = threadIdx.x & 63;
    int o0 = w * 64;                       // 4 waves tile o = 0..255
    int lr = lane & 15, lk = (lane >> 4) * 8;

    f32x4 acc[4][4] = {};
    const __bf16* As = specB + ((size_t)b * NN + n0 + lr) * CINC + lk;
    const __bf16* Bs = WspecB + (size_t)(o0 + lr) * CINC + lk;
#pragma unroll
    for (int kk = 0; kk < CINC; kk += 32) {
        bf16x8 a[4], bb[4];
#pragma unroll
        for (int m = 0; m < 4; m++)
            a[m] = *(const bf16x8*)(As + (size_t)(m * 16) * CINC + kk);
#pragma unroll
        for (int n = 0; n < 4; n++)
            bb[n] = *(const bf16x8*)(Bs + (size_t)(n * 16) * CINC + kk);
#pragma unroll
        for (int m = 0; m < 4; m++)
#pragma unroll
            for (int n = 0; n < 4; n++)
                acc[m][n] = __builtin_amdgcn_mfma_f32_16x16x32_bf16(a[m], bb[n], acc[m][n], 0, 0, 0);
    }

    int rb = (lane >> 4) * 4;
#pragma unroll
    for (int n = 0; n < 4; n++) {
        int o = o0 + n * 16 + lr;
        float sc = 1.0f / sqrtf(var[o] + 1e-5f);
        float ga = gamma[o], be = beta[o], mu = mean[o], bs = bspec[o];
#pragma unroll
        for (int m = 0; m < 4; m++) {
#pragma unroll
            for (int j = 0; j < 4; j++) {
                int nrow = n0 + m * 16 + rb + j;
                float y = acc[m][n][j] + bs;
                y = (y - mu) * sc;
                y = y * ga + be;
                float g = 0.5f * y * (1.0f + erff(y * 0.70710678118654752440f));
                g1B[((size_t)b * NN + nrow) * COU + o] = (__bf16)g;
            }
        }
    }
}

// ---------------- GEMM2 (MFMA): out[b,o,n] = Wc[o,:] @ g1[b,n,:] + bc[o] ----------------
__global__ __launch_bounds__(256) void gemm2_mfma(const __bf16* __restrict__ g1B,
                                                  const __bf16* __restrict__ WcB,
                                                  const float* __restrict__ bc,
                                                  float* __restrict__ out) {
    int b  = blockIdx.z;
    int n0 = blockIdx.x * 256;
    int o0 = blockIdx.y * 64;
    int w = threadIdx.x >> 6, lane = threadIdx.x & 63;
    int n0w = n0 + w * 64;                 // 4 waves tile n
    int lr = lane & 15, lk = (lane >> 4) * 8;

    f32x4 acc[4][4] = {};
    const __bf16* As = WcB + (size_t)(o0 + lr) * COU + lk;
    const __bf16* Bs = g1B + ((size_t)b * NN + n0w + lr) * COU + lk;
#pragma unroll
    for (int kk = 0; kk < COU; kk += 32) {
        bf16x8 a[4], bb[4];
#pragma unroll
        for (int m = 0; m < 4; m++)
            a[m] = *(const bf16x8*)(As + (size_t)(m * 16) * COU + kk);
#pragma unroll
        for (int n = 0; n < 4; n++)
            bb[n] = *(const bf16x8*)(Bs + (size_t)(n * 16) * COU + kk);
#pragma unroll
        for (int m = 0; m < 4; m++)
#pragma unroll
            for (int n = 0; n < 4; n++)
                acc[m][n] = __builtin_amdgcn_mfma_f32_16x16x32_bf16(a[m], bb[n], acc[m][n], 0, 0, 0);
    }

    int rb = (lane >> 4) * 4;
#pragma unroll
    for (int m = 0; m < 4; m++) {
#pragma unroll
        for (int j = 0; j < 4; j++) {
            int o = o0 + m * 16 + rb + j;
            float bias = bc[o];
#pragma unroll
            for (int n = 0; n < 4; n++) {
                int ncol = n0w + n * 16 + lr;
                out[((size_t)b * COU + o) * NN + ncol] = acc[m][n][j] + bias;
            }
        }
    }
}

extern "C" void kernel_launch(void* const* d_in, const int* in_sizes, int n_in,
                              void* d_out, int out_size, void* d_ws, size_t ws_size,
                              hipStream_t stream) {
    const float* xyz      = (const float*)d_in[0];
    const float* features = (const float*)d_in[1];
    const float* W_spec   = (const float*)d_in[2];
    const float* b_spec   = (const float*)d_in[3];
    const float* bn_gamma = (const float*)d_in[4];
    const float* bn_beta  = (const float*)d_in[5];
    const float* bn_mean  = (const float*)d_in[6];
    const float* bn_var   = (const float*)d_in[7];
    const float* W_low    = (const float*)d_in[8];
    const float* b_low    = (const float*)d_in[9];
    const float* W_high   = (const float*)d_in[10];
    const float* b_high   = (const float*)d_in[11];
    float* out = (float*)d_out;

    char* ws = (char*)d_ws;
    size_t off = 0;
    float*  fT    = (float*)(ws + off);  off += (size_t)BB * NN * CINC * 4;      // 8 MB
    __bf16* specB = (__bf16*)(ws + off); off += (size_t)BB * NN * CINC * 2;      // 4 MB
    __bf16* g1B   = (__bf16*)(ws + off); off += (size_t)BB * NN * COU  * 2;      // 8 MB
    int*    idx   = (int*)(ws + off);    off += (size_t)BB * NN * KNNK * 4;      // 1 MB
    int*    rcnt  = (int*)(ws + off);    off += (size_t)BB * NN * 4;             // 64 KB
    int*    rev   = (int*)(ws + off);    off += (size_t)BB * NN * REVCAP * 4;    // 4 MB
    float*  dinv  = (float*)(ws + off);  off += (size_t)BB * NN * 4;             // 64 KB
    __bf16* WspecB= (__bf16*)(ws + off); off += (size_t)COU * CINC * 2;          // 64 KB
    __bf16* WcB   = (__bf16*)(ws + off); off += (size_t)COU * COU * 2;           // 128 KB
    float*  bc    = (float*)(ws + off);  off += (size_t)COU * 4;                 // 1 KB

    hipMemsetAsync(rcnt, 0, (size_t)BB * NN * sizeof(int), stream);

    prep_kernel<<<dim3((COU * CINC + 255) / 256), dim3(256), 0, stream>>>(
        W_spec, W_low, W_high, b_low, b_high, WspecB, WcB, bc);
    transpose_kernel<<<dim3(NN / 32, CINC / 32, BB), dim3(32, 8), 0, stream>>>(features, fT);
    knn_fused_kernel<<<dim3(NN / 64, BB), dim3(512), 0, stream>>>(xyz, idx, rcnt, rev);
    dinv_kernel<<<dim3(BB * NN / 256), dim3(256), 0, stream>>>(rcnt, dinv);
    spec_kernel<<<dim3(BB * NN), dim3(128), 0, stream>>>(fT, idx, rcnt, rev, dinv, specB);
    gemm1_mfma<<<dim3(NN / 64, BB), dim3(256), 0, stream>>>(
        specB, WspecB, b_spec, bn_gamma, bn_beta, bn_mean, bn_var, g1B);
    gemm2_mfma<<<dim3(NN / 256, COU / 64, BB), dim3(256), 0, stream>>>(g1B, WcB, bc, out);
}

// Round 14
// 146.955 us; speedup vs baseline: 1.7562x; 1.3487x over previous
//
#include <hip/hip_runtime.h>
#include <hip/hip_bf16.h>
#include <math.h>

#define BB   8
#define NN   2048
#define BN   (BB * NN)
#define CINC 128
#define COU  256
#define KNNK 16
#define REVCAP 64
#define SEG   16
#define SEGC  (NN / SEG)   // 128 candidates per segment

typedef __bf16 bf16x8 __attribute__((ext_vector_type(8)));
typedef float  f32x4  __attribute__((ext_vector_type(4)));

// Single-instruction sorted-insert step: for ascending t_{j-1} <= t_j,
// new t_j = median(t_{j-1}, t_j, key). v_med3_u32 = 1 VOP3 op.
#define UMED3(dst, a, bb_, c) asm("v_med3_u32 %0, %1, %2, %3" : "=v"(dst) : "v"(a), "v"(bb_), "v"(c))

#define TOP_DECL \
    unsigned int t0=~0u,t1=~0u,t2=~0u,t3=~0u,t4=~0u,t5=~0u,t6=~0u,t7=~0u, \
                 t8=~0u,t9=~0u,t10=~0u,t11=~0u,t12=~0u,t13=~0u,t14=~0u,t15=~0u;

// Insert u into sorted multiset {t0..t15}, dropping the max. 15 med3 + 1 min.
// All med3s read pre-insert values (descending order) -> depth-1 dataflow.
#define TOP_INSERT(u) {                     \
    UMED3(t15, t14, t15, (u));              \
    UMED3(t14, t13, t14, (u));              \
    UMED3(t13, t12, t13, (u));              \
    UMED3(t12, t11, t12, (u));              \
    UMED3(t11, t10, t11, (u));              \
    UMED3(t10, t9,  t10, (u));              \
    UMED3(t9,  t8,  t9,  (u));              \
    UMED3(t8,  t7,  t8,  (u));              \
    UMED3(t7,  t6,  t7,  (u));              \
    UMED3(t6,  t5,  t6,  (u));              \
    UMED3(t5,  t4,  t5,  (u));              \
    UMED3(t4,  t3,  t4,  (u));              \
    UMED3(t3,  t2,  t3,  (u));              \
    UMED3(t2,  t1,  t2,  (u));              \
    UMED3(t1,  t0,  t1,  (u));              \
    t0 = ((u) < t0) ? (u) : t0;             \
}

// dist arithmetic: bit-identical to the verified R1-R13 formula.
static __device__ __forceinline__ unsigned int dist_du(float qx, float qy, float qz,
                                                       float qsq, float4 c) {
    float dot = fmaf(qz, c.z, fmaf(qy, c.y, __fmul_rn(qx, c.x)));
    float d = __fsub_rn(__fadd_rn(qsq, c.w), __fmul_rn(2.0f, dot));
    unsigned int du = __float_as_uint(d);
    du ^= (unsigned int)((int)du >> 31) | 0x80000000u;
    return du;
}

// ---------------- transpose features (B,C,N) -> fT (B,N,C) ----------------
__global__ __launch_bounds__(256) void transpose_kernel(const float* __restrict__ feat,
                                                        float* __restrict__ fT) {
    __shared__ float t[32][33];
    int b  = blockIdx.z;
    int n0 = blockIdx.x * 32, c0 = blockIdx.y * 32;
    int tx = threadIdx.x, ty = threadIdx.y;  // (32,8)
#pragma unroll
    for (int i = 0; i < 4; i++)
        t[ty + i * 8][tx] = feat[((size_t)b * CINC + c0 + ty + i * 8) * NN + n0 + tx];
    __syncthreads();
#pragma unroll
    for (int i = 0; i < 4; i++)
        fT[((size_t)b * NN + n0 + ty + i * 8) * CINC + c0 + tx] = t[tx][ty + i * 8];
}

// ---------------- prep: cast weights to bf16, concat W2 & bias ----------------
__global__ __launch_bounds__(256) void prep_kernel(const float* __restrict__ Wspec,
                                                   const float* __restrict__ Wlow,
                                                   const float* __restrict__ Whigh,
                                                   const float* __restrict__ blow,
                                                   const float* __restrict__ bhigh,
                                                   __bf16* __restrict__ WspecB,
                                                   __bf16* __restrict__ WcB,
                                                   float* __restrict__ bc) {
    int i = blockIdx.x * 256 + threadIdx.x;
    if (i < COU * CINC) WspecB[i] = (__bf16)Wspec[i];
    if (i < 128 * COU) {
        WcB[i] = (__bf16)Wlow[i];
        WcB[128 * COU + i] = (__bf16)Whigh[i];
    }
    if (i < 128) { bc[i] = blow[i]; bc[128 + i] = bhigh[i]; }
}

// ---------------- KNN fused v2: du-only partials + threshold + emission ----------------
// Block = 1024 threads = 16 waves, one block per 64-query group (grid 32x8).
// Wave w scans segment w (128 cands, lane = query):
//   Phase A: med3-u32 sorted top-16 of du -> pduL[16][16][64]        (du only)
//   Merge:   waves 0,1 half-merge 8 lists each -> hm; wave 0 -> T = 16th-smallest du
//   Emission: all waves rescan; du<T -> slot = atomicAdd(cntless), write knn_idx+rev
//             du==T -> tie list (per-query).  knn_idx slot order is irrelevant:
//             downstream uses the SET only (adjacency scatter + unordered sums).
//   Finalize: wave 0 picks (16-cntless) LOWEST-IDX ties (= lax.top_k tie-break);
//             >16-tie overflow falls back to ascending-idx rescan (exact, ~never).
// Selected set provably identical to the verified R8-R13 construction.
__global__ __launch_bounds__(1024, 4) void knn_fused_kernel(const float* __restrict__ xyz,
                                                            int* __restrict__ knn_idx,
                                                            int* __restrict__ revcnt,
                                                            int* __restrict__ rev) {
    __shared__ float4 cand[NN];                     // 32 KB
    __shared__ unsigned int pduL[KNNK][SEG][64];    // 64 KB
    __shared__ unsigned int hm[KNNK][2][64];        // 8 KB
    __shared__ unsigned int Tq[64];
    __shared__ int cntless[64];
    __shared__ int tiecnt[64];
    __shared__ unsigned short tieidx[64][16];       // 2 KB

    int b = blockIdx.y;
    int lane = threadIdx.x & 63;
    int w = threadIdx.x >> 6;               // wave id = segment (0..15)
    int q = blockIdx.x * 64 + lane;
    int bq = b * NN + q;

    const float* xb = xyz + (size_t)b * 3 * NN;
    for (int t = threadIdx.x; t < NN; t += 1024) {
        float x = xb[t], y = xb[NN + t], z = xb[2 * NN + t];
        float sq = __fadd_rn(__fadd_rn(__fmul_rn(x, x), __fmul_rn(y, y)), __fmul_rn(z, z));
        cand[t] = make_float4(x, y, z, sq);
    }
    if (threadIdx.x < 64) { cntless[lane] = 0; tiecnt[lane] = 0; }
    __syncthreads();

    float qx = xb[q], qy = xb[NN + q], qz = xb[2 * NN + q];
    float qsq = __fadd_rn(__fadd_rn(__fmul_rn(qx, qx), __fmul_rn(qy, qy)), __fmul_rn(qz, qz));

    {   // ---- phase A: per-wave sorted top-16 du over segment w ----
        int segbase = w * SEGC;
        TOP_DECL
        for (int i = 0; i < SEGC; i += 4) {
            float4 c0 = cand[segbase + i + 0];
            float4 c1 = cand[segbase + i + 1];
            float4 c2 = cand[segbase + i + 2];
            float4 c3 = cand[segbase + i + 3];
            unsigned int d0 = dist_du(qx, qy, qz, qsq, c0);
            unsigned int d1 = dist_du(qx, qy, qz, qsq, c1);
            unsigned int d2 = dist_du(qx, qy, qz, qsq, c2);
            unsigned int d3 = dist_du(qx, qy, qz, qsq, c3);
            TOP_INSERT(d0)
            TOP_INSERT(d1)
            TOP_INSERT(d2)
            TOP_INSERT(d3)
        }
        pduL[0][w][lane] = t0;   pduL[1][w][lane] = t1;
        pduL[2][w][lane] = t2;   pduL[3][w][lane] = t3;
        pduL[4][w][lane] = t4;   pduL[5][w][lane] = t5;
        pduL[6][w][lane] = t6;   pduL[7][w][lane] = t7;
        pduL[8][w][lane] = t8;   pduL[9][w][lane] = t9;
        pduL[10][w][lane] = t10; pduL[11][w][lane] = t11;
        pduL[12][w][lane] = t12; pduL[13][w][lane] = t13;
        pduL[14][w][lane] = t14; pduL[15][w][lane] = t15;
    }
    __syncthreads();

    if (w < 2) {   // ---- half-merge: wave w folds segments w*8 .. w*8+7 ----
        TOP_DECL
        int w20 = w * 8;
        for (int w2 = 0; w2 < 8; w2++) {
#pragma unroll
            for (int k = 0; k < KNNK; k++) {
                unsigned int u = pduL[k][w20 + w2][lane];
                TOP_INSERT(u)
            }
        }
        hm[0][w][lane] = t0;   hm[1][w][lane] = t1;
        hm[2][w][lane] = t2;   hm[3][w][lane] = t3;
        hm[4][w][lane] = t4;   hm[5][w][lane] = t5;
        hm[6][w][lane] = t6;   hm[7][w][lane] = t7;
        hm[8][w][lane] = t8;   hm[9][w][lane] = t9;
        hm[10][w][lane] = t10; hm[11][w][lane] = t11;
        hm[12][w][lane] = t12; hm[13][w][lane] = t13;
        hm[14][w][lane] = t14; hm[15][w][lane] = t15;
    }
    __syncthreads();

    if (w == 0) {  // ---- final: T = 16th smallest du of the 32 half-merged ----
        TOP_DECL
#pragma unroll
        for (int k = 0; k < KNNK; k++) {
            unsigned int u = hm[k][0][lane];
            TOP_INSERT(u)
        }
#pragma unroll
        for (int k = 0; k < KNNK; k++) {
            unsigned int u = hm[k][1][lane];
            TOP_INSERT(u)
        }
        Tq[lane] = t15;
    }
    __syncthreads();

    {   // ---- emission: all 16 waves rescan their segment ----
        unsigned int T = Tq[lane];
        int segbase = w * SEGC;
        for (int i = 0; i < SEGC; i++) {
            float4 c = cand[segbase + i];
            unsigned int du = dist_du(qx, qy, qz, qsq, c);
            if (du < T) {
                int slot = atomicAdd(&cntless[lane], 1);
                int gx = segbase + i;
                knn_idx[(size_t)bq * KNNK + slot] = gx;
                int pos = atomicAdd(&revcnt[b * NN + gx], 1);
                if (pos < REVCAP) rev[((size_t)(b * NN + gx)) * REVCAP + pos] = q;
            } else if (du == T) {
                int t = atomicAdd(&tiecnt[lane], 1);
                if (t < 16) tieidx[lane][t] = (unsigned short)(segbase + i);
            }
        }
    }
    __syncthreads();

    if (threadIdx.x < 64) {  // ---- finalize ties (wave 0, lane = query) ----
        unsigned int T = Tq[lane];
        int cl = cntless[lane];             // <= 15 by definition of T
        int need = KNNK - cl;
        int tc = tiecnt[lane];
        if (need > 0) {
            if (tc <= 16) {                 // all ties captured: pick lowest-idx ones
                for (int r = 0; r < need; r++) {
                    int best = 0x7fffffff, bj = 0;
                    for (int j = 0; j < tc; j++) {
                        int v = tieidx[lane][j];
                        if (v < best) { best = v; bj = j; }
                    }
                    tieidx[lane][bj] = 0xFFFF;
                    knn_idx[(size_t)bq * KNNK + cl + r] = best;
                    int pos = atomicAdd(&revcnt[b * NN + best], 1);
                    if (pos < REVCAP) rev[((size_t)(b * NN + best)) * REVCAP + pos] = q;
                }
            } else {                        // >16 ties: exact ascending-idx rescan
                int em = 0;
                for (int i = 0; i < NN && em < need; i++) {
                    unsigned int du = dist_du(qx, qy, qz, qsq, cand[i]);
                    if (du == T) {
                        knn_idx[(size_t)bq * KNNK + cl + em] = i;
                        int pos = atomicAdd(&revcnt[b * NN + i], 1);
                        if (pos < REVCAP) rev[((size_t)(b * NN + i)) * REVCAP + pos] = q;
                        em++;
                    }
                }
            }
        }
    }
}

// ---------------- dinv = rsqrt(D + 1e-6), D = 0.5*(K + indeg) ----------------
__global__ __launch_bounds__(256) void dinv_kernel(const int* __restrict__ revcnt,
                                                   float* __restrict__ dinv) {
    int i = blockIdx.x * 256 + threadIdx.x;
    if (i < BB * NN) {
        float D = 0.5f * (float)(KNNK + revcnt[i]);
        dinv[i] = 1.0f / sqrtf(D + 1e-6f);
    }
}

// ---------------- spec: f32 compute, bf16 output ----------------
__global__ __launch_bounds__(128) void spec_kernel(const float* __restrict__ fT,
                                                   const int* __restrict__ knn_idx,
                                                   const int* __restrict__ revcnt,
                                                   const int* __restrict__ rev,
                                                   const float* __restrict__ dinv,
                                                   __bf16* __restrict__ specB) {
    __shared__ int ml[KNNK + REVCAP];
    __shared__ float wl[KNNK + REVCAP];
    __shared__ int s_cnt;

    int bn = blockIdx.x;           // b*NN + n
    int b = bn >> 11;
    int tid = threadIdx.x;

    if (tid == 0) {
        int c = revcnt[bn];
        s_cnt = c < REVCAP ? c : REVCAP;
    }
    __syncthreads();
    int cnt = s_cnt;
    if (tid < KNNK) ml[tid] = knn_idx[(size_t)bn * KNNK + tid];
    if (tid < cnt) ml[KNNK + tid] = rev[(size_t)bn * REVCAP + tid];
    __syncthreads();
    int total = KNNK + cnt;
    if (tid < total) wl[tid] = 0.5f * dinv[b * NN + ml[tid]];
    __syncthreads();

    float dn = dinv[bn];
    float acc = 0.0f;
    for (int j = 0; j < total; j++)
        acc = fmaf(wl[j], fT[((size_t)b * NN + ml[j]) * CINC + tid], acc);
    float f0 = fT[(size_t)bn * CINC + tid];
    specB[(size_t)bn * CINC + tid] = (__bf16)(f0 - dn * acc);
}

// ---------------- GEMM1 (MFMA): g1 = gelu(bn(spec @ Wspec^T + b)) ----------------
__global__ __launch_bounds__(256) void gemm1_mfma(const __bf16* __restrict__ specB,
                                                  const __bf16* __restrict__ WspecB,
                                                  const float* __restrict__ bspec,
                                                  const float* __restrict__ gamma,
                                                  const float* __restrict__ beta,
                                                  const float* __restrict__ mean,
                                                  const float* __restrict__ var,
                                                  __bf16* __restrict__ g1B) {
    int b  = blockIdx.y;
    int n0 = blockIdx.x * 64;
    int w = threadIdx.x >> 6, lane = threadIdx.x & 63;
    int o0 = w * 64;                       // 4 waves tile o = 0..255
    int lr = lane & 15, lk = (lane >> 4) * 8;

    f32x4 acc[4][4] = {};
    const __bf16* As = specB + ((size_t)b * NN + n0 + lr) * CINC + lk;
    const __bf16* Bs = WspecB + (size_t)(o0 + lr) * CINC + lk;
#pragma unroll
    for (int kk = 0; kk < CINC; kk += 32) {
        bf16x8 a[4], bb[4];
#pragma unroll
        for (int m = 0; m < 4; m++)
            a[m] = *(const bf16x8*)(As + (size_t)(m * 16) * CINC + kk);
#pragma unroll
        for (int n = 0; n < 4; n++)
            bb[n] = *(const bf16x8*)(Bs + (size_t)(n * 16) * CINC + kk);
#pragma unroll
        for (int m = 0; m < 4; m++)
#pragma unroll
            for (int n = 0; n < 4; n++)
                acc[m][n] = __builtin_amdgcn_mfma_f32_16x16x32_bf16(a[m], bb[n], acc[m][n], 0, 0, 0);
    }

    int rb = (lane >> 4) * 4;
#pragma unroll
    for (int n = 0; n < 4; n++) {
        int o = o0 + n * 16 + lr;
        float sc = 1.0f / sqrtf(var[o] + 1e-5f);
        float ga = gamma[o], be = beta[o], mu = mean[o], bs = bspec[o];
#pragma unroll
        for (int m = 0; m < 4; m++) {
#pragma unroll
            for (int j = 0; j < 4; j++) {
                int nrow = n0 + m * 16 + rb + j;
                float y = acc[m][n][j] + bs;
                y = (y - mu) * sc;
                y = y * ga + be;
                float g = 0.5f * y * (1.0f + erff(y * 0.70710678118654752440f));
                g1B[((size_t)b * NN + nrow) * COU + o] = (__bf16)g;
            }
        }
    }
}

// ---------------- GEMM2 (MFMA): out[b,o,n] = Wc[o,:] @ g1[b,n,:] + bc[o] ----------------
__global__ __launch_bounds__(256) void gemm2_mfma(const __bf16* __restrict__ g1B,
                                                  const __bf16* __restrict__ WcB,
                                                  const float* __restrict__ bc,
                                                  float* __restrict__ out) {
    int b  = blockIdx.z;
    int n0 = blockIdx.x * 256;
    int o0 = blockIdx.y * 64;
    int w = threadIdx.x >> 6, lane = threadIdx.x & 63;
    int n0w = n0 + w * 64;                 // 4 waves tile n
    int lr = lane & 15, lk = (lane >> 4) * 8;

    f32x4 acc[4][4] = {};
    const __bf16* As = WcB + (size_t)(o0 + lr) * COU + lk;
    const __bf16* Bs = g1B + ((size_t)b * NN + n0w + lr) * COU + lk;
#pragma unroll
    for (int kk = 0; kk < COU; kk += 32) {
        bf16x8 a[4], bb[4];
#pragma unroll
        for (int m = 0; m < 4; m++)
            a[m] = *(const bf16x8*)(As + (size_t)(m * 16) * COU + kk);
#pragma unroll
        for (int n = 0; n < 4; n++)
            bb[n] = *(const bf16x8*)(Bs + (size_t)(n * 16) * COU + kk);
#pragma unroll
        for (int m = 0; m < 4; m++)
#pragma unroll
            for (int n = 0; n < 4; n++)
                acc[m][n] = __builtin_amdgcn_mfma_f32_16x16x32_bf16(a[m], bb[n], acc[m][n], 0, 0, 0);
    }

    int rb = (lane >> 4) * 4;
#pragma unroll
    for (int m = 0; m < 4; m++) {
#pragma unroll
        for (int j = 0; j < 4; j++) {
            int o = o0 + m * 16 + rb + j;
            float bias = bc[o];
#pragma unroll
            for (int n = 0; n < 4; n++) {
                int ncol = n0w + n * 16 + lr;
                out[((size_t)b * COU + o) * NN + ncol] = acc[m][n][j] + bias;
            }
        }
    }
}

extern "C" void kernel_launch(void* const* d_in, const int* in_sizes, int n_in,
                              void* d_out, int out_size, void* d_ws, size_t ws_size,
                              hipStream_t stream) {
    const float* xyz      = (const float*)d_in[0];
    const float* features = (const float*)d_in[1];
    const float* W_spec   = (const float*)d_in[2];
    const float* b_spec   = (const float*)d_in[3];
    const float* bn_gamma = (const float*)d_in[4];
    const float* bn_beta  = (const float*)d_in[5];
    const float* bn_mean  = (const float*)d_in[6];
    const float* bn_var   = (const float*)d_in[7];
    const float* W_low    = (const float*)d_in[8];
    const float* b_low    = (const float*)d_in[9];
    const float* W_high   = (const float*)d_in[10];
    const float* b_high   = (const float*)d_in[11];
    float* out = (float*)d_out;

    char* ws = (char*)d_ws;
    size_t off = 0;
    float*  fT    = (float*)(ws + off);  off += (size_t)BB * NN * CINC * 4;      // 8 MB
    __bf16* specB = (__bf16*)(ws + off); off += (size_t)BB * NN * CINC * 2;      // 4 MB
    __bf16* g1B   = (__bf16*)(ws + off); off += (size_t)BB * NN * COU  * 2;      // 8 MB
    int*    idx   = (int*)(ws + off);    off += (size_t)BB * NN * KNNK * 4;      // 1 MB
    int*    rcnt  = (int*)(ws + off);    off += (size_t)BB * NN * 4;             // 64 KB
    int*    rev   = (int*)(ws + off);    off += (size_t)BB * NN * REVCAP * 4;    // 4 MB
    float*  dinv  = (float*)(ws + off);  off += (size_t)BB * NN * 4;             // 64 KB
    __bf16* WspecB= (__bf16*)(ws + off); off += (size_t)COU * CINC * 2;          // 64 KB
    __bf16* WcB   = (__bf16*)(ws + off); off += (size_t)COU * COU * 2;           // 128 KB
    float*  bc    = (float*)(ws + off);  off += (size_t)COU * 4;                 // 1 KB

    hipMemsetAsync(rcnt, 0, (size_t)BB * NN * sizeof(int), stream);

    prep_kernel<<<dim3((COU * CINC + 255) / 256), dim3(256), 0, stream>>>(
        W_spec, W_low, W_high, b_low, b_high, WspecB, WcB, bc);
    transpose_kernel<<<dim3(NN / 32, CINC / 32, BB), dim3(32, 8), 0, stream>>>(features, fT);
    knn_fused_kernel<<<dim3(NN / 64, BB), dim3(1024), 0, stream>>>(xyz, idx, rcnt, rev);
    dinv_kernel<<<dim3(BB * NN / 256), dim3(256), 0, stream>>>(rcnt, dinv);
    spec_kernel<<<dim3(BB * NN), dim3(128), 0, stream>>>(fT, idx, rcnt, rev, dinv, specB);
    gemm1_mfma<<<dim3(NN / 64, BB), dim3(256), 0, stream>>>(
        specB, WspecB, b_spec, bn_gamma, bn_beta, bn_mean, bn_var, g1B);
    gemm2_mfma<<<dim3(NN / 256, COU / 64, BB), dim3(256), 0, stream>>>(g1B, WcB, bc, out);
}

// Round 15
// 118.905 us; speedup vs baseline: 2.1705x; 1.2359x over previous
//
#include <hip/hip_runtime.h>
#include <hip/hip_bf16.h>
#include <math.h>

#define BB   8
#define NN   2048
#define BN   (BB * NN)
#define CINC 128
#define COU  256
#define KNNK 16
#define REVCAP 64
#define SEG   16
#define SEGC  (NN / SEG)   // 128 candidates per segment

typedef __bf16 bf16x8 __attribute__((ext_vector_type(8)));
typedef float  f32x4  __attribute__((ext_vector_type(4)));

// Single-instruction sorted-insert step: for ascending t_{j-1} <= t_j,
// new t_j = median(t_{j-1}, t_j, key). v_med3_u32 = 1 VOP3 op.
#define UMED3(dst, a, bb_, c) asm("v_med3_u32 %0, %1, %2, %3" : "=v"(dst) : "v"(a), "v"(bb_), "v"(c))

#define TOP_DECL \
    unsigned int t0=~0u,t1=~0u,t2=~0u,t3=~0u,t4=~0u,t5=~0u,t6=~0u,t7=~0u, \
                 t8=~0u,t9=~0u,t10=~0u,t11=~0u,t12=~0u,t13=~0u,t14=~0u,t15=~0u;

// Insert u into sorted multiset {t0..t15}, dropping the max. 15 med3 + 1 min.
// All med3s read pre-insert values (descending order) -> depth-1 dataflow.
#define TOP_INSERT(u) {                     \
    UMED3(t15, t14, t15, (u));              \
    UMED3(t14, t13, t14, (u));              \
    UMED3(t13, t12, t13, (u));              \
    UMED3(t12, t11, t12, (u));              \
    UMED3(t11, t10, t11, (u));              \
    UMED3(t10, t9,  t10, (u));              \
    UMED3(t9,  t8,  t9,  (u));              \
    UMED3(t8,  t7,  t8,  (u));              \
    UMED3(t7,  t6,  t7,  (u));              \
    UMED3(t6,  t5,  t6,  (u));              \
    UMED3(t5,  t4,  t5,  (u));              \
    UMED3(t4,  t3,  t4,  (u));              \
    UMED3(t3,  t2,  t3,  (u));              \
    UMED3(t2,  t1,  t2,  (u));              \
    UMED3(t1,  t0,  t1,  (u));              \
    t0 = ((u) < t0) ? (u) : t0;             \
}

// dist arithmetic: bit-identical to the verified R1-R14 formula.
static __device__ __forceinline__ unsigned int dist_du(float qx, float qy, float qz,
                                                       float qsq, float4 c) {
    float dot = fmaf(qz, c.z, fmaf(qy, c.y, __fmul_rn(qx, c.x)));
    float d = __fsub_rn(__fadd_rn(qsq, c.w), __fmul_rn(2.0f, dot));
    unsigned int du = __float_as_uint(d);
    du ^= (unsigned int)((int)du >> 31) | 0x80000000u;
    return du;
}

// ---------------- transpose features (B,C,N) -> fT (B,N,C) ----------------
__global__ __launch_bounds__(256) void transpose_kernel(const float* __restrict__ feat,
                                                        float* __restrict__ fT) {
    __shared__ float t[32][33];
    int b  = blockIdx.z;
    int n0 = blockIdx.x * 32, c0 = blockIdx.y * 32;
    int tx = threadIdx.x, ty = threadIdx.y;  // (32,8)
#pragma unroll
    for (int i = 0; i < 4; i++)
        t[ty + i * 8][tx] = feat[((size_t)b * CINC + c0 + ty + i * 8) * NN + n0 + tx];
    __syncthreads();
#pragma unroll
    for (int i = 0; i < 4; i++)
        fT[((size_t)b * NN + n0 + ty + i * 8) * CINC + c0 + tx] = t[tx][ty + i * 8];
}

// ---------------- prep: cast weights to bf16, concat W2 & bias ----------------
__global__ __launch_bounds__(256) void prep_kernel(const float* __restrict__ Wspec,
                                                   const float* __restrict__ Wlow,
                                                   const float* __restrict__ Whigh,
                                                   const float* __restrict__ blow,
                                                   const float* __restrict__ bhigh,
                                                   __bf16* __restrict__ WspecB,
                                                   __bf16* __restrict__ WcB,
                                                   float* __restrict__ bc) {
    int i = blockIdx.x * 256 + threadIdx.x;
    if (i < COU * CINC) WspecB[i] = (__bf16)Wspec[i];
    if (i < 128 * COU) {
        WcB[i] = (__bf16)Wlow[i];
        WcB[128 * COU + i] = (__bf16)Whigh[i];
    }
    if (i < 128) { bc[i] = blow[i]; bc[128 + i] = bhigh[i]; }
}

// ---------------- KNN fused v3: LDS-only emission + batched global write-out ----------------
// Same verified selection as R14 (phase A du top-16, 2-level merge -> T, emission by
// threshold, lowest-idx tie-break). Change: emission writes only to LDS sel[16][64]
// (LDS atomic slots); one final phase has all 1024 threads do the global knn_idx /
// revcnt / rev traffic concurrently -> global atomic latency paid once, not per hit.
__global__ __launch_bounds__(1024, 4) void knn_fused_kernel(const float* __restrict__ xyz,
                                                            int* __restrict__ knn_idx,
                                                            int* __restrict__ revcnt,
                                                            int* __restrict__ rev) {
    __shared__ float4 cand[NN];                     // 32 KB
    __shared__ unsigned int pduL[KNNK][SEG][64];    // 64 KB
    __shared__ unsigned int hm[KNNK][2][64];        // 8 KB
    __shared__ unsigned int Tq[64];
    __shared__ int cntless[64];
    __shared__ int tiecnt[64];
    __shared__ unsigned short tieidx[16][64];       // 2 KB
    __shared__ unsigned short sel[KNNK][64];        // 2 KB

    int b = blockIdx.y;
    int lane = threadIdx.x & 63;
    int w = threadIdx.x >> 6;               // wave id = segment (0..15)
    int q = blockIdx.x * 64 + lane;
    int bq = b * NN + q;

    const float* xb = xyz + (size_t)b * 3 * NN;
    for (int t = threadIdx.x; t < NN; t += 1024) {
        float x = xb[t], y = xb[NN + t], z = xb[2 * NN + t];
        float sq = __fadd_rn(__fadd_rn(__fmul_rn(x, x), __fmul_rn(y, y)), __fmul_rn(z, z));
        cand[t] = make_float4(x, y, z, sq);
    }
    if (threadIdx.x < 64) { cntless[lane] = 0; tiecnt[lane] = 0; }
    __syncthreads();

    float qx = xb[q], qy = xb[NN + q], qz = xb[2 * NN + q];
    float qsq = __fadd_rn(__fadd_rn(__fmul_rn(qx, qx), __fmul_rn(qy, qy)), __fmul_rn(qz, qz));

    {   // ---- phase A: per-wave sorted top-16 du over segment w ----
        int segbase = w * SEGC;
        TOP_DECL
        for (int i = 0; i < SEGC; i += 4) {
            float4 c0 = cand[segbase + i + 0];
            float4 c1 = cand[segbase + i + 1];
            float4 c2 = cand[segbase + i + 2];
            float4 c3 = cand[segbase + i + 3];
            unsigned int d0 = dist_du(qx, qy, qz, qsq, c0);
            unsigned int d1 = dist_du(qx, qy, qz, qsq, c1);
            unsigned int d2 = dist_du(qx, qy, qz, qsq, c2);
            unsigned int d3 = dist_du(qx, qy, qz, qsq, c3);
            TOP_INSERT(d0)
            TOP_INSERT(d1)
            TOP_INSERT(d2)
            TOP_INSERT(d3)
        }
        pduL[0][w][lane] = t0;   pduL[1][w][lane] = t1;
        pduL[2][w][lane] = t2;   pduL[3][w][lane] = t3;
        pduL[4][w][lane] = t4;   pduL[5][w][lane] = t5;
        pduL[6][w][lane] = t6;   pduL[7][w][lane] = t7;
        pduL[8][w][lane] = t8;   pduL[9][w][lane] = t9;
        pduL[10][w][lane] = t10; pduL[11][w][lane] = t11;
        pduL[12][w][lane] = t12; pduL[13][w][lane] = t13;
        pduL[14][w][lane] = t14; pduL[15][w][lane] = t15;
    }
    __syncthreads();

    if (w < 2) {   // ---- half-merge: wave w folds segments w*8 .. w*8+7 ----
        TOP_DECL
        int w20 = w * 8;
        for (int w2 = 0; w2 < 8; w2++) {
#pragma unroll
            for (int k = 0; k < KNNK; k++) {
                unsigned int u = pduL[k][w20 + w2][lane];
                TOP_INSERT(u)
            }
        }
        hm[0][w][lane] = t0;   hm[1][w][lane] = t1;
        hm[2][w][lane] = t2;   hm[3][w][lane] = t3;
        hm[4][w][lane] = t4;   hm[5][w][lane] = t5;
        hm[6][w][lane] = t6;   hm[7][w][lane] = t7;
        hm[8][w][lane] = t8;   hm[9][w][lane] = t9;
        hm[10][w][lane] = t10; hm[11][w][lane] = t11;
        hm[12][w][lane] = t12; hm[13][w][lane] = t13;
        hm[14][w][lane] = t14; hm[15][w][lane] = t15;
    }
    __syncthreads();

    if (w == 0) {  // ---- final: T = 16th smallest du of the 32 half-merged ----
        TOP_DECL
#pragma unroll
        for (int k = 0; k < KNNK; k++) {
            unsigned int u = hm[k][0][lane];
            TOP_INSERT(u)
        }
#pragma unroll
        for (int k = 0; k < KNNK; k++) {
            unsigned int u = hm[k][1][lane];
            TOP_INSERT(u)
        }
        Tq[lane] = t15;
    }
    __syncthreads();

    {   // ---- emission: all 16 waves rescan their segment; LDS-only writes ----
        unsigned int T = Tq[lane];
        int segbase = w * SEGC;
        for (int i = 0; i < SEGC; i++) {
            float4 c = cand[segbase + i];
            unsigned int du = dist_du(qx, qy, qz, qsq, c);
            if (du < T) {
                int slot = atomicAdd(&cntless[lane], 1);
                sel[slot][lane] = (unsigned short)(segbase + i);
            } else if (du == T) {
                int t = atomicAdd(&tiecnt[lane], 1);
                if (t < 16) tieidx[t][lane] = (unsigned short)(segbase + i);
            }
        }
    }
    __syncthreads();

    if (threadIdx.x < 64) {  // ---- finalize ties into sel (wave 0, lane = query) ----
        unsigned int T = Tq[lane];
        int cl = cntless[lane];             // <= 15 by definition of T
        int need = KNNK - cl;
        int tc = tiecnt[lane];
        if (need > 0) {
            if (tc <= 16) {                 // all ties captured: pick lowest-idx ones
                for (int r = 0; r < need; r++) {
                    int best = 0x7fffffff, bj = 0;
                    for (int j = 0; j < tc; j++) {
                        int v = tieidx[j][lane];
                        if (v < best) { best = v; bj = j; }
                    }
                    tieidx[bj][lane] = 0xFFFF;
                    sel[cl + r][lane] = (unsigned short)best;
                }
            } else {                        // >16 ties: exact ascending-idx rescan
                int em = 0;
                for (int i = 0; i < NN && em < need; i++) {
                    unsigned int du = dist_du(qx, qy, qz, qsq, cand[i]);
                    if (du == T) { sel[cl + em][lane] = (unsigned short)i; em++; }
                }
            }
        }
    }
    __syncthreads();

    {   // ---- write-out: 1024 threads, entry w of query lane; all atomics parallel ----
        int x = (int)sel[w][lane];
        knn_idx[(size_t)bq * KNNK + w] = x;
        int pos = atomicAdd(&revcnt[b * NN + x], 1);
        if (pos < REVCAP) rev[((size_t)(b * NN + x)) * REVCAP + pos] = q;
    }
}

// ---------------- dinv = rsqrt(D + 1e-6), D = 0.5*(K + indeg) ----------------
__global__ __launch_bounds__(256) void dinv_kernel(const int* __restrict__ revcnt,
                                                   float* __restrict__ dinv) {
    int i = blockIdx.x * 256 + threadIdx.x;
    if (i < BB * NN) {
        float D = 0.5f * (float)(KNNK + revcnt[i]);
        dinv[i] = 1.0f / sqrtf(D + 1e-6f);
    }
}

// ---------------- spec: f32 compute, bf16 output ----------------
__global__ __launch_bounds__(128) void spec_kernel(const float* __restrict__ fT,
                                                   const int* __restrict__ knn_idx,
                                                   const int* __restrict__ revcnt,
                                                   const int* __restrict__ rev,
                                                   const float* __restrict__ dinv,
                                                   __bf16* __restrict__ specB) {
    __shared__ int ml[KNNK + REVCAP];
    __shared__ float wl[KNNK + REVCAP];
    __shared__ int s_cnt;

    int bn = blockIdx.x;           // b*NN + n
    int b = bn >> 11;
    int tid = threadIdx.x;

    if (tid == 0) {
        int c = revcnt[bn];
        s_cnt = c < REVCAP ? c : REVCAP;
    }
    __syncthreads();
    int cnt = s_cnt;
    if (tid < KNNK) ml[tid] = knn_idx[(size_t)bn * KNNK + tid];
    if (tid < cnt) ml[KNNK + tid] = rev[(size_t)bn * REVCAP + tid];
    __syncthreads();
    int total = KNNK + cnt;
    if (tid < total) wl[tid] = 0.5f * dinv[b * NN + ml[tid]];
    __syncthreads();

    float dn = dinv[bn];
    float acc = 0.0f;
    for (int j = 0; j < total; j++)
        acc = fmaf(wl[j], fT[((size_t)b * NN + ml[j]) * CINC + tid], acc);
    float f0 = fT[(size_t)bn * CINC + tid];
    specB[(size_t)bn * CINC + tid] = (__bf16)(f0 - dn * acc);
}

// ---------------- GEMM1 (MFMA): g1 = gelu(bn(spec @ Wspec^T + b)) ----------------
__global__ __launch_bounds__(256) void gemm1_mfma(const __bf16* __restrict__ specB,
                                                  const __bf16* __restrict__ WspecB,
                                                  const float* __restrict__ bspec,
                                                  const float* __restrict__ gamma,
                                                  const float* __restrict__ beta,
                                                  const float* __restrict__ mean,
                                                  const float* __restrict__ var,
                                                  __bf16* __restrict__ g1B) {
    int b  = blockIdx.y;
    int n0 = blockIdx.x * 64;
    int w = threadIdx.x >> 6, lane = threadIdx.x & 63;
    int o0 = w * 64;                       // 4 waves tile o = 0..255
    int lr = lane & 15, lk = (lane >> 4) * 8;

    f32x4 acc[4][4] = {};
    const __bf16* As = specB + ((size_t)b * NN + n0 + lr) * CINC + lk;
    const __bf16* Bs = WspecB + (size_t)(o0 + lr) * CINC + lk;
#pragma unroll
    for (int kk = 0; kk < CINC; kk += 32) {
        bf16x8 a[4], bb[4];
#pragma unroll
        for (int m = 0; m < 4; m++)
            a[m] = *(const bf16x8*)(As + (size_t)(m * 16) * CINC + kk);
#pragma unroll
        for (int n = 0; n < 4; n++)
            bb[n] = *(const bf16x8*)(Bs + (size_t)(n * 16) * CINC + kk);
#pragma unroll
        for (int m = 0; m < 4; m++)
#pragma unroll
            for (int n = 0; n < 4; n++)
                acc[m][n] = __builtin_amdgcn_mfma_f32_16x16x32_bf16(a[m], bb[n], acc[m][n], 0, 0, 0);
    }

    int rb = (lane >> 4) * 4;
#pragma unroll
    for (int n = 0; n < 4; n++) {
        int o = o0 + n * 16 + lr;
        float sc = 1.0f / sqrtf(var[o] + 1e-5f);
        float ga = gamma[o], be = beta[o], mu = mean[o], bs = bspec[o];
#pragma unroll
        for (int m = 0; m < 4; m++) {
#pragma unroll
            for (int j = 0; j < 4; j++) {
                int nrow = n0 + m * 16 + rb + j;
                float y = acc[m][n][j] + bs;
                y = (y - mu) * sc;
                y = y * ga + be;
                float g = 0.5f * y * (1.0f + erff(y * 0.70710678118654752440f));
                g1B[((size_t)b * NN + nrow) * COU + o] = (__bf16)g;
            }
        }
    }
}

// ---------------- GEMM2 (MFMA): out[b,o,n] = Wc[o,:] @ g1[b,n,:] + bc[o] ----------------
__global__ __launch_bounds__(256) void gemm2_mfma(const __bf16* __restrict__ g1B,
                                                  const __bf16* __restrict__ WcB,
                                                  const float* __restrict__ bc,
                                                  float* __restrict__ out) {
    int b  = blockIdx.z;
    int n0 = blockIdx.x * 256;
    int o0 = blockIdx.y * 64;
    int w = threadIdx.x >> 6, lane = threadIdx.x & 63;
    int n0w = n0 + w * 64;                 // 4 waves tile n
    int lr = lane & 15, lk = (lane >> 4) * 8;

    f32x4 acc[4][4] = {};
    const __bf16* As = WcB + (size_t)(o0 + lr) * COU + lk;
    const __bf16* Bs = g1B + ((size_t)b * NN + n0w + lr) * COU + lk;
#pragma unroll
    for (int kk = 0; kk < COU; kk += 32) {
        bf16x8 a[4], bb[4];
#pragma unroll
        for (int m = 0; m < 4; m++)
            a[m] = *(const bf16x8*)(As + (size_t)(m * 16) * COU + kk);
#pragma unroll
        for (int n = 0; n < 4; n++)
            bb[n] = *(const bf16x8*)(Bs + (size_t)(n * 16) * COU + kk);
#pragma unroll
        for (int m = 0; m < 4; m++)
#pragma unroll
            for (int n = 0; n < 4; n++)
                acc[m][n] = __builtin_amdgcn_mfma_f32_16x16x32_bf16(a[m], bb[n], acc[m][n], 0, 0, 0);
    }

    int rb = (lane >> 4) * 4;
#pragma unroll
    for (int m = 0; m < 4; m++) {
#pragma unroll
        for (int j = 0; j < 4; j++) {
            int o = o0 + m * 16 + rb + j;
            float bias = bc[o];
#pragma unroll
            for (int n = 0; n < 4; n++) {
                int ncol = n0w + n * 16 + lr;
                out[((size_t)b * COU + o) * NN + ncol] = acc[m][n][j] + bias;
            }
        }
    }
}

extern "C" void kernel_launch(void* const* d_in, const int* in_sizes, int n_in,
                              void* d_out, int out_size, void* d_ws, size_t ws_size,
                              hipStream_t stream) {
    const float* xyz      = (const float*)d_in[0];
    const float* features = (const float*)d_in[1];
    const float* W_spec   = (const float*)d_in[2];
    const float* b_spec   = (const float*)d_in[3];
    const float* bn_gamma = (const float*)d_in[4];
    const float* bn_beta  = (const float*)d_in[5];
    const float* bn_mean  = (const float*)d_in[6];
    const float* bn_var   = (const float*)d_in[7];
    const float* W_low    = (const float*)d_in[8];
    const float* b_low    = (const float*)d_in[9];
    const float* W_high   = (const float*)d_in[10];
    const float* b_high   = (const float*)d_in[11];
    float* out = (float*)d_out;

    char* ws = (char*)d_ws;
    size_t off = 0;
    float*  fT    = (float*)(ws + off);  off += (size_t)BB * NN * CINC * 4;      // 8 MB
    __bf16* specB = (__bf16*)(ws + off); off += (size_t)BB * NN * CINC * 2;      // 4 MB
    __bf16* g1B   = (__bf16*)(ws + off); off += (size_t)BB * NN * COU  * 2;      // 8 MB
    int*    idx   = (int*)(ws + off);    off += (size_t)BB * NN * KNNK * 4;      // 1 MB
    int*    rcnt  = (int*)(ws + off);    off += (size_t)BB * NN * 4;             // 64 KB
    int*    rev   = (int*)(ws + off);    off += (size_t)BB * NN * REVCAP * 4;    // 4 MB
    float*  dinv  = (float*)(ws + off);  off += (size_t)BB * NN * 4;             // 64 KB
    __bf16* WspecB= (__bf16*)(ws + off); off += (size_t)COU * CINC * 2;          // 64 KB
    __bf16* WcB   = (__bf16*)(ws + off); off += (size_t)COU * COU * 2;           // 128 KB
    float*  bc    = (float*)(ws + off);  off += (size_t)COU * 4;                 // 1 KB

    hipMemsetAsync(rcnt, 0, (size_t)BB * NN * sizeof(int), stream);

    prep_kernel<<<dim3((COU * CINC + 255) / 256), dim3(256), 0, stream>>>(
        W_spec, W_low, W_high, b_low, b_high, WspecB, WcB, bc);
    transpose_kernel<<<dim3(NN / 32, CINC / 32, BB), dim3(32, 8), 0, stream>>>(features, fT);
    knn_fused_kernel<<<dim3(NN / 64, BB), dim3(1024), 0, stream>>>(xyz, idx, rcnt, rev);
    dinv_kernel<<<dim3(BB * NN / 256), dim3(256), 0, stream>>>(rcnt, dinv);
    spec_kernel<<<dim3(BB * NN), dim3(128), 0, stream>>>(fT, idx, rcnt, rev, dinv, specB);
    gemm1_mfma<<<dim3(NN / 64, BB), dim3(256), 0, stream>>>(
        specB, WspecB, b_spec, bn_gamma, bn_beta, bn_mean, bn_var, g1B);
    gemm2_mfma<<<dim3(NN / 256, COU / 64, BB), dim3(256), 0, stream>>>(g1B, WcB, bc, out);
}

// Round 17
// 116.935 us; speedup vs baseline: 2.2070x; 1.0168x over previous
//
#include <hip/hip_runtime.h>
#include <hip/hip_bf16.h>
#include <math.h>

#define BB   8
#define NN   2048
#define BN   (BB * NN)
#define CINC 128
#define COU  256
#define KNNK 16
#define REVCAP 64
#define SEG   16
#define SEGC  (NN / SEG)   // 128 candidates per segment

typedef __bf16 bf16x8 __attribute__((ext_vector_type(8)));
typedef float  f32x4  __attribute__((ext_vector_type(4)));

// Single-instruction sorted-insert step: for ascending t_{j-1} <= t_j,
// new t_j = median(t_{j-1}, t_j, key). v_med3_u32 = 1 VOP3 op.
#define UMED3(dst, a, bb_, c) asm("v_med3_u32 %0, %1, %2, %3" : "=v"(dst) : "v"(a), "v"(bb_), "v"(c))

#define TOP_DECL \
    unsigned int t0=~0u,t1=~0u,t2=~0u,t3=~0u,t4=~0u,t5=~0u,t6=~0u,t7=~0u, \
                 t8=~0u,t9=~0u,t10=~0u,t11=~0u,t12=~0u,t13=~0u,t14=~0u,t15=~0u;

// Insert u into sorted multiset {t0..t15}, dropping the max. 15 med3 + 1 min.
// All med3s read pre-insert values (descending order) -> depth-1 dataflow.
#define TOP_INSERT(u) {                     \
    UMED3(t15, t14, t15, (u));              \
    UMED3(t14, t13, t14, (u));              \
    UMED3(t13, t12, t13, (u));              \
    UMED3(t12, t11, t12, (u));              \
    UMED3(t11, t10, t11, (u));              \
    UMED3(t10, t9,  t10, (u));              \
    UMED3(t9,  t8,  t9,  (u));              \
    UMED3(t8,  t7,  t8,  (u));              \
    UMED3(t7,  t6,  t7,  (u));              \
    UMED3(t6,  t5,  t6,  (u));              \
    UMED3(t5,  t4,  t5,  (u));              \
    UMED3(t4,  t3,  t4,  (u));              \
    UMED3(t3,  t2,  t3,  (u));              \
    UMED3(t2,  t1,  t2,  (u));              \
    UMED3(t1,  t0,  t1,  (u));              \
    t0 = ((u) < t0) ? (u) : t0;             \
}

// dist arithmetic: bit-identical to the verified R1-R15 formula.
static __device__ __forceinline__ unsigned int dist_du(float qx, float qy, float qz,
                                                       float qsq, float4 c) {
    float dot = fmaf(qz, c.z, fmaf(qy, c.y, __fmul_rn(qx, c.x)));
    float d = __fsub_rn(__fadd_rn(qsq, c.w), __fmul_rn(2.0f, dot));
    unsigned int du = __float_as_uint(d);
    du ^= (unsigned int)((int)du >> 31) | 0x80000000u;
    return du;
}

// ---------------- transpose features (B,C,N) -> fT (B,N,C) ----------------
__global__ __launch_bounds__(256) void transpose_kernel(const float* __restrict__ feat,
                                                        float* __restrict__ fT) {
    __shared__ float t[32][33];
    int b  = blockIdx.z;
    int n0 = blockIdx.x * 32, c0 = blockIdx.y * 32;
    int tx = threadIdx.x, ty = threadIdx.y;  // (32,8)
#pragma unroll
    for (int i = 0; i < 4; i++)
        t[ty + i * 8][tx] = feat[((size_t)b * CINC + c0 + ty + i * 8) * NN + n0 + tx];
    __syncthreads();
#pragma unroll
    for (int i = 0; i < 4; i++)
        fT[((size_t)b * NN + n0 + ty + i * 8) * CINC + c0 + tx] = t[tx][ty + i * 8];
}

// ---------------- prep: cast weights to bf16, concat W2 & bias ----------------
__global__ __launch_bounds__(256) void prep_kernel(const float* __restrict__ Wspec,
                                                   const float* __restrict__ Wlow,
                                                   const float* __restrict__ Whigh,
                                                   const float* __restrict__ blow,
                                                   const float* __restrict__ bhigh,
                                                   __bf16* __restrict__ WspecB,
                                                   __bf16* __restrict__ WcB,
                                                   float* __restrict__ bc) {
    int i = blockIdx.x * 256 + threadIdx.x;
    if (i < COU * CINC) WspecB[i] = (__bf16)Wspec[i];
    if (i < 128 * COU) {
        WcB[i] = (__bf16)Wlow[i];
        WcB[128 * COU + i] = (__bf16)Whigh[i];
    }
    if (i < 128) { bc[i] = blow[i]; bc[128 + i] = bhigh[i]; }
}

// ---------------- KNN fused v4: register tree-merge, 2 blocks/CU ----------------
// Same verified selection as R14/R15 (phase A du top-16 per wave-segment, T =
// global 16th-smallest du, threshold emission, lowest-idx tie-break, batched
// write-out). Change: pduL (64KB) removed; the 16 per-wave sorted lists are
// merged by a 4-stage binary tree (waves [s,2s) dump registers to a reused
// 32KB buffer, waves [0,s) fold = 16 sorted inserts; top-16 of union is
// order-invariant -> T identical). LDS 111.6 -> ~69 KB -> 2 blocks/CU.
__global__ __launch_bounds__(1024, 8) void knn_fused_kernel(const float* __restrict__ xyz,
                                                            int* __restrict__ knn_idx,
                                                            int* __restrict__ revcnt,
                                                            int* __restrict__ rev) {
    __shared__ float4 cand[NN];                     // 32 KB
    __shared__ unsigned int mbuf[8][KNNK][64];      // 32 KB (tree-merge staging)
    __shared__ unsigned int Tq[64];
    __shared__ int cntless[64];
    __shared__ int tiecnt[64];
    __shared__ unsigned short tieidx[16][64];       // 2 KB
    __shared__ unsigned short sel[KNNK][64];        // 2 KB

    int b = blockIdx.y;
    int lane = threadIdx.x & 63;
    int w = threadIdx.x >> 6;               // wave id = segment (0..15)
    int q = blockIdx.x * 64 + lane;
    int bq = b * NN + q;

    const float* xb = xyz + (size_t)b * 3 * NN;
    for (int t = threadIdx.x; t < NN; t += 1024) {
        float x = xb[t], y = xb[NN + t], z = xb[2 * NN + t];
        float sq = __fadd_rn(__fadd_rn(__fmul_rn(x, x), __fmul_rn(y, y)), __fmul_rn(z, z));
        cand[t] = make_float4(x, y, z, sq);
    }
    if (threadIdx.x < 64) { cntless[lane] = 0; tiecnt[lane] = 0; }
    __syncthreads();

    float qx = xb[q], qy = xb[NN + q], qz = xb[2 * NN + q];
    float qsq = __fadd_rn(__fadd_rn(__fmul_rn(qx, qx), __fmul_rn(qy, qy)), __fmul_rn(qz, qz));

    TOP_DECL
    {   // ---- phase A: per-wave sorted top-16 du over segment w (registers) ----
        int segbase = w * SEGC;
        for (int i = 0; i < SEGC; i += 4) {
            float4 c0 = cand[segbase + i + 0];
            float4 c1 = cand[segbase + i + 1];
            float4 c2 = cand[segbase + i + 2];
            float4 c3 = cand[segbase + i + 3];
            unsigned int d0 = dist_du(qx, qy, qz, qsq, c0);
            unsigned int d1 = dist_du(qx, qy, qz, qsq, c1);
            unsigned int d2 = dist_du(qx, qy, qz, qsq, c2);
            unsigned int d3 = dist_du(qx, qy, qz, qsq, c3);
            TOP_INSERT(d0)
            TOP_INSERT(d1)
            TOP_INSERT(d2)
            TOP_INSERT(d3)
        }
    }

    // ---- tree merge: 16 -> 8 -> 4 -> 2 -> 1 lists (T is order-invariant) ----
    for (int s = 8; s >= 1; s >>= 1) {
        if (w >= s && w < 2 * s) {
            int j = w - s;
            mbuf[j][0][lane] = t0;   mbuf[j][1][lane] = t1;
            mbuf[j][2][lane] = t2;   mbuf[j][3][lane] = t3;
            mbuf[j][4][lane] = t4;   mbuf[j][5][lane] = t5;
            mbuf[j][6][lane] = t6;   mbuf[j][7][lane] = t7;
            mbuf[j][8][lane] = t8;   mbuf[j][9][lane] = t9;
            mbuf[j][10][lane] = t10; mbuf[j][11][lane] = t11;
            mbuf[j][12][lane] = t12; mbuf[j][13][lane] = t13;
            mbuf[j][14][lane] = t14; mbuf[j][15][lane] = t15;
        }
        __syncthreads();
        if (w < s) {
#pragma unroll
            for (int k = 0; k < KNNK; k++) {
                unsigned int u = mbuf[w][k][lane];
                TOP_INSERT(u)
            }
        }
        __syncthreads();
    }
    if (w == 0) Tq[lane] = t15;
    __syncthreads();

    {   // ---- emission: all 16 waves rescan their segment; LDS-only writes ----
        unsigned int T = Tq[lane];
        int segbase = w * SEGC;
        for (int i = 0; i < SEGC; i++) {
            float4 c = cand[segbase + i];
            unsigned int du = dist_du(qx, qy, qz, qsq, c);
            if (du < T) {
                int slot = atomicAdd(&cntless[lane], 1);
                sel[slot][lane] = (unsigned short)(segbase + i);
            } else if (du == T) {
                int t = atomicAdd(&tiecnt[lane], 1);
                if (t < 16) tieidx[t][lane] = (unsigned short)(segbase + i);
            }
        }
    }
    __syncthreads();

    if (threadIdx.x < 64) {  // ---- finalize ties into sel (wave 0, lane = query) ----
        unsigned int T = Tq[lane];
        int cl = cntless[lane];             // <= 15 by definition of T
        int need = KNNK - cl;
        int tc = tiecnt[lane];
        if (need > 0) {
            if (tc <= 16) {                 // all ties captured: pick lowest-idx ones
                for (int r = 0; r < need; r++) {
                    int best = 0x7fffffff, bj = 0;
                    for (int j = 0; j < tc; j++) {
                        int v = tieidx[j][lane];
                        if (v < best) { best = v; bj = j; }
                    }
                    tieidx[bj][lane] = 0xFFFF;
                    sel[cl + r][lane] = (unsigned short)best;
                }
            } else {                        // >16 ties: exact ascending-idx rescan
                int em = 0;
                for (int i = 0; i < NN && em < need; i++) {
                    unsigned int du = dist_du(qx, qy, qz, qsq, cand[i]);
                    if (du == T) { sel[cl + em][lane] = (unsigned short)i; em++; }
                }
            }
        }
    }
    __syncthreads();

    {   // ---- write-out: 1024 threads, entry w of query lane; all atomics parallel ----
        int x = (int)sel[w][lane];
        knn_idx[(size_t)bq * KNNK + w] = x;
        int pos = atomicAdd(&revcnt[b * NN + x], 1);
        if (pos < REVCAP) rev[((size_t)(b * NN + x)) * REVCAP + pos] = q;
    }
}

// ---------------- dinv = rsqrt(D + 1e-6), D = 0.5*(K + indeg) ----------------
__global__ __launch_bounds__(256) void dinv_kernel(const int* __restrict__ revcnt,
                                                   float* __restrict__ dinv) {
    int i = blockIdx.x * 256 + threadIdx.x;
    if (i < BB * NN) {
        float D = 0.5f * (float)(KNNK + revcnt[i]);
        dinv[i] = 1.0f / sqrtf(D + 1e-6f);
    }
}

// ---------------- spec: f32 compute, bf16 output ----------------
__global__ __launch_bounds__(128) void spec_kernel(const float* __restrict__ fT,
                                                   const int* __restrict__ knn_idx,
                                                   const int* __restrict__ revcnt,
                                                   const int* __restrict__ rev,
                                                   const float* __restrict__ dinv,
                                                   __bf16* __restrict__ specB) {
    __shared__ int ml[KNNK + REVCAP];
    __shared__ float wl[KNNK + REVCAP];
    __shared__ int s_cnt;

    int bn = blockIdx.x;           // b*NN + n
    int b = bn >> 11;
    int tid = threadIdx.x;

    if (tid == 0) {
        int c = revcnt[bn];
        s_cnt = c < REVCAP ? c : REVCAP;
    }
    __syncthreads();
    int cnt = s_cnt;
    if (tid < KNNK) ml[tid] = knn_idx[(size_t)bn * KNNK + tid];
    if (tid < cnt) ml[KNNK + tid] = rev[(size_t)bn * REVCAP + tid];
    __syncthreads();
    int total = KNNK + cnt;
    if (tid < total) wl[tid] = 0.5f * dinv[b * NN + ml[tid]];
    __syncthreads();

    float dn = dinv[bn];
    float acc = 0.0f;
    for (int j = 0; j < total; j++)
        acc = fmaf(wl[j], fT[((size_t)b * NN + ml[j]) * CINC + tid], acc);
    float f0 = fT[(size_t)bn * CINC + tid];
    specB[(size_t)bn * CINC + tid] = (__bf16)(f0 - dn * acc);
}

// ---------------- GEMM1 (MFMA): g1 = gelu(bn(spec @ Wspec^T + b)) ----------------
__global__ __launch_bounds__(256) void gemm1_mfma(const __bf16* __restrict__ specB,
                                                  const __bf16* __restrict__ WspecB,
                                                  const float* __restrict__ bspec,
                                                  const float* __restrict__ gamma,
                                                  const float* __restrict__ beta,
                                                  const float* __restrict__ mean,
                                                  const float* __restrict__ var,
                                                  __bf16* __restrict__ g1B) {
    int b  = blockIdx.y;
    int n0 = blockIdx.x * 64;
    int w = threadIdx.x >> 6, lane = threadIdx.x & 63;
    int o0 = w * 64;                       // 4 waves tile o = 0..255
    int lr = lane & 15, lk = (lane >> 4) * 8;

    f32x4 acc[4][4] = {};
    const __bf16* As = specB + ((size_t)b * NN + n0 + lr) * CINC + lk;
    const __bf16* Bs = WspecB + (size_t)(o0 + lr) * CINC + lk;
#pragma unroll
    for (int kk = 0; kk < CINC; kk += 32) {
        bf16x8 a[4], bb[4];
#pragma unroll
        for (int m = 0; m < 4; m++)
            a[m] = *(const bf16x8*)(As + (size_t)(m * 16) * CINC + kk);
#pragma unroll
        for (int n = 0; n < 4; n++)
            bb[n] = *(const bf16x8*)(Bs + (size_t)(n * 16) * CINC + kk);
#pragma unroll
        for (int m = 0; m < 4; m++)
#pragma unroll
            for (int n = 0; n < 4; n++)
                acc[m][n] = __builtin_amdgcn_mfma_f32_16x16x32_bf16(a[m], bb[n], acc[m][n], 0, 0, 0);
    }

    int rb = (lane >> 4) * 4;
#pragma unroll
    for (int n = 0; n < 4; n++) {
        int o = o0 + n * 16 + lr;
        float sc = 1.0f / sqrtf(var[o] + 1e-5f);
        float ga = gamma[o], be = beta[o], mu = mean[o], bs = bspec[o];
#pragma unroll
        for (int m = 0; m < 4; m++) {
#pragma unroll
            for (int j = 0; j < 4; j++) {
                int nrow = n0 + m * 16 + rb + j;
                float y = acc[m][n][j] + bs;
                y = (y - mu) * sc;
                y = y * ga + be;
                float g = 0.5f * y * (1.0f + erff(y * 0.70710678118654752440f));
                g1B[((size_t)b * NN + nrow) * COU + o] = (__bf16)g;
            }
        }
    }
}

// ---------------- GEMM2 (MFMA): out[b,o,n] = Wc[o,:] @ g1[b,n,:] + bc[o] ----------------
__global__ __launch_bounds__(256) void gemm2_mfma(const __bf16* __restrict__ g1B,
                                                  const __bf16* __restrict__ WcB,
                                                  const float* __restrict__ bc,
                                                  float* __restrict__ out) {
    int b  = blockIdx.z;
    int n0 = blockIdx.x * 256;
    int o0 = blockIdx.y * 64;
    int w = threadIdx.x >> 6, lane = threadIdx.x & 63;
    int n0w = n0 + w * 64;                 // 4 waves tile n
    int lr = lane & 15, lk = (lane >> 4) * 8;

    f32x4 acc[4][4] = {};
    const __bf16* As = WcB + (size_t)(o0 + lr) * COU + lk;
    const __bf16* Bs = g1B + ((size_t)b * NN + n0w + lr) * COU + lk;
#pragma unroll
    for (int kk = 0; kk < COU; kk += 32) {
        bf16x8 a[4], bb[4];
#pragma unroll
        for (int m = 0; m < 4; m++)
            a[m] = *(const bf16x8*)(As + (size_t)(m * 16) * COU + kk);
#pragma unroll
        for (int n = 0; n < 4; n++)
            bb[n] = *(const bf16x8*)(Bs + (size_t)(n * 16) * COU + kk);
#pragma unroll
        for (int m = 0; m < 4; m++)
#pragma unroll
            for (int n = 0; n < 4; n++)
                acc[m][n] = __builtin_amdgcn_mfma_f32_16x16x32_bf16(a[m], bb[n], acc[m][n], 0, 0, 0);
    }

    int rb = (lane >> 4) * 4;
#pragma unroll
    for (int m = 0; m < 4; m++) {
#pragma unroll
        for (int j = 0; j < 4; j++) {
            int o = o0 + m * 16 + rb + j;
            float bias = bc[o];
#pragma unroll
            for (int n = 0; n < 4; n++) {
                int ncol = n0w + n * 16 + lr;
                out[((size_t)b * COU + o) * NN + ncol] = acc[m][n][j] + bias;
            }
        }
    }
}

extern "C" void kernel_launch(void* const* d_in, const int* in_sizes, int n_in,
                              void* d_out, int out_size, void* d_ws, size_t ws_size,
                              hipStream_t stream) {
    const float* xyz      = (const float*)d_in[0];
    const float* features = (const float*)d_in[1];
    const float* W_spec   = (const float*)d_in[2];
    const float* b_spec   = (const float*)d_in[3];
    const float* bn_gamma = (const float*)d_in[4];
    const float* bn_beta  = (const float*)d_in[5];
    const float* bn_mean  = (const float*)d_in[6];
    const float* bn_var   = (const float*)d_in[7];
    const float* W_low    = (const float*)d_in[8];
    const float* b_low    = (const float*)d_in[9];
    const float* W_high   = (const float*)d_in[10];
    const float* b_high   = (const float*)d_in[11];
    float* out = (float*)d_out;

    char* ws = (char*)d_ws;
    size_t off = 0;
    float*  fT    = (float*)(ws + off);  off += (size_t)BB * NN * CINC * 4;      // 8 MB
    __bf16* specB = (__bf16*)(ws + off); off += (size_t)BB * NN * CINC * 2;      // 4 MB
    __bf16* g1B   = (__bf16*)(ws + off); off += (size_t)BB * NN * COU  * 2;      // 8 MB
    int*    idx   = (int*)(ws + off);    off += (size_t)BB * NN * KNNK * 4;      // 1 MB
    int*    rcnt  = (int*)(ws + off);    off += (size_t)BB * NN * 4;             // 64 KB
    int*    rev   = (int*)(ws + off);    off += (size_t)BB * NN * REVCAP * 4;    // 4 MB
    float*  dinv  = (float*)(ws + off);  off += (size_t)BB * NN * 4;             // 64 KB
    __bf16* WspecB= (__bf16*)(ws + off); off += (size_t)COU * CINC * 2;          // 64 KB
    __bf16* WcB   = (__bf16*)(ws + off); off += (size_t)COU * COU * 2;           // 128 KB
    float*  bc    = (float*)(ws + off);  off += (size_t)COU * 4;                 // 1 KB

    hipMemsetAsync(rcnt, 0, (size_t)BB * NN * sizeof(int), stream);

    prep_kernel<<<dim3((COU * CINC + 255) / 256), dim3(256), 0, stream>>>(
        W_spec, W_low, W_high, b_low, b_high, WspecB, WcB, bc);
    transpose_kernel<<<dim3(NN / 32, CINC / 32, BB), dim3(32, 8), 0, stream>>>(features, fT);
    knn_fused_kernel<<<dim3(NN / 64, BB), dim3(1024), 0, stream>>>(xyz, idx, rcnt, rev);
    dinv_kernel<<<dim3(BB * NN / 256), dim3(256), 0, stream>>>(rcnt, dinv);
    spec_kernel<<<dim3(BB * NN), dim3(128), 0, stream>>>(fT, idx, rcnt, rev, dinv, specB);
    gemm1_mfma<<<dim3(NN / 64, BB), dim3(256), 0, stream>>>(
        specB, WspecB, b_spec, bn_gamma, bn_beta, bn_mean, bn_var, g1B);
    gemm2_mfma<<<dim3(NN / 256, COU / 64, BB), dim3(256), 0, stream>>>(g1B, WcB, bc, out);
}

// Round 19
// 106.691 us; speedup vs baseline: 2.4189x; 1.0960x over previous
//
#include <hip/hip_runtime.h>
#include <hip/hip_bf16.h>
#include <math.h>

#define BB   8
#define NN   2048
#define BN   (BB * NN)
#define CINC 128
#define COU  256
#define KNNK 16
#define REVCAP 64
#define QG   32            // queries per knn block
#define SEG  16            // wave-segments (128 cands each; lane-half scans 64)

typedef __bf16 bf16x8 __attribute__((ext_vector_type(8)));
typedef float  f32x4  __attribute__((ext_vector_type(4)));

// Single-instruction sorted-insert step: for ascending t_{j-1} <= t_j,
// new t_j = median(t_{j-1}, t_j, key). v_med3_u32 = 1 VOP3 op.
#define UMED3(dst, a, bb_, c) asm("v_med3_u32 %0, %1, %2, %3" : "=v"(dst) : "v"(a), "v"(bb_), "v"(c))

#define TOP_DECL \
    unsigned int t0=~0u,t1=~0u,t2=~0u,t3=~0u,t4=~0u,t5=~0u,t6=~0u,t7=~0u, \
                 t8=~0u,t9=~0u,t10=~0u,t11=~0u,t12=~0u,t13=~0u,t14=~0u,t15=~0u;

// Insert u into sorted multiset {t0..t15}, dropping the max. 15 med3 + 1 min.
#define TOP_INSERT(u) {                     \
    UMED3(t15, t14, t15, (u));              \
    UMED3(t14, t13, t14, (u));              \
    UMED3(t13, t12, t13, (u));              \
    UMED3(t12, t11, t12, (u));              \
    UMED3(t11, t10, t11, (u));              \
    UMED3(t10, t9,  t10, (u));              \
    UMED3(t9,  t8,  t9,  (u));              \
    UMED3(t8,  t7,  t8,  (u));              \
    UMED3(t7,  t6,  t7,  (u));              \
    UMED3(t6,  t5,  t6,  (u));              \
    UMED3(t5,  t4,  t5,  (u));              \
    UMED3(t4,  t3,  t4,  (u));              \
    UMED3(t3,  t2,  t3,  (u));              \
    UMED3(t2,  t1,  t2,  (u));              \
    UMED3(t1,  t0,  t1,  (u));              \
    t0 = ((u) < t0) ? (u) : t0;             \
}

// dist arithmetic: bit-identical to the verified R1-R17 formula.
static __device__ __forceinline__ unsigned int dist_du(float qx, float qy, float qz,
                                                       float qsq, float4 c) {
    float dot = fmaf(qz, c.z, fmaf(qy, c.y, __fmul_rn(qx, c.x)));
    float d = __fsub_rn(__fadd_rn(qsq, c.w), __fmul_rn(2.0f, dot));
    unsigned int du = __float_as_uint(d);
    du ^= (unsigned int)((int)du >> 31) | 0x80000000u;
    return du;
}

// ---------------- transpose features (B,C,N) -> fT (B,N,C) ----------------
__global__ __launch_bounds__(256) void transpose_kernel(const float* __restrict__ feat,
                                                        float* __restrict__ fT) {
    __shared__ float t[32][33];
    int b  = blockIdx.z;
    int n0 = blockIdx.x * 32, c0 = blockIdx.y * 32;
    int tx = threadIdx.x, ty = threadIdx.y;  // (32,8)
#pragma unroll
    for (int i = 0; i < 4; i++)
        t[ty + i * 8][tx] = feat[((size_t)b * CINC + c0 + ty + i * 8) * NN + n0 + tx];
    __syncthreads();
#pragma unroll
    for (int i = 0; i < 4; i++)
        fT[((size_t)b * NN + n0 + ty + i * 8) * CINC + c0 + tx] = t[tx][ty + i * 8];
}

// ---------------- prep: cast weights to bf16, concat W2 & bias ----------------
__global__ __launch_bounds__(256) void prep_kernel(const float* __restrict__ Wspec,
                                                   const float* __restrict__ Wlow,
                                                   const float* __restrict__ Whigh,
                                                   const float* __restrict__ blow,
                                                   const float* __restrict__ bhigh,
                                                   __bf16* __restrict__ WspecB,
                                                   __bf16* __restrict__ WcB,
                                                   float* __restrict__ bc) {
    int i = blockIdx.x * 256 + threadIdx.x;
    if (i < COU * CINC) WspecB[i] = (__bf16)Wspec[i];
    if (i < 128 * COU) {
        WcB[i] = (__bf16)Wlow[i];
        WcB[128 * COU + i] = (__bf16)Whigh[i];
    }
    if (i < 128) { bc[i] = blow[i]; bc[128 + i] = bhigh[i]; }
}

// ---------------- KNN fused v5: 32 queries/block -> grid 512 -> 2 blocks/CU ----------------
// Verified selection semantics (R14-R17): per-lane med3-u32 top-16 of du, merge to
// T = global 16th-smallest, threshold emission, lowest-idx tie-break (exact fallback).
// New decomposition: lane&31 = query, lane>>5 = candidate-half; each lane scans 64
// cands (half of wave-segment w). 16-shfl_xor(32) fold merges halves, then 4-stage
// tree (mbuf[8][16][32]). LDS ~51 KB; grid 512 -> 2 resident blocks/CU (32 waves).
__global__ __launch_bounds__(1024, 8) void knn_fused_kernel(const float* __restrict__ xyz,
                                                            int* __restrict__ knn_idx,
                                                            int* __restrict__ revcnt,
                                                            int* __restrict__ rev) {
    __shared__ float4 cand[NN];                     // 32 KB
    __shared__ unsigned int mbuf[8][KNNK][QG];      // 16 KB (tree-merge staging)
    __shared__ unsigned int Tq[QG];
    __shared__ int cntless[QG];
    __shared__ int tiecnt[QG];
    __shared__ unsigned short tieidx[16][QG];       // 1 KB
    __shared__ unsigned short sel[KNNK][QG];        // 1 KB

    int b = blockIdx.y;
    int lane = threadIdx.x & 63;
    int w = threadIdx.x >> 6;               // wave id = segment (0..15)
    int q32 = lane & 31;
    int qh = lane >> 5;                     // candidate half within segment
    int q = blockIdx.x * QG + q32;
    int bq = b * NN + q;

    const float* xb = xyz + (size_t)b * 3 * NN;
    for (int t = threadIdx.x; t < NN; t += 1024) {
        float x = xb[t], y = xb[NN + t], z = xb[2 * NN + t];
        float sq = __fadd_rn(__fadd_rn(__fmul_rn(x, x), __fmul_rn(y, y)), __fmul_rn(z, z));
        cand[t] = make_float4(x, y, z, sq);
    }
    if (threadIdx.x < QG) { cntless[threadIdx.x] = 0; tiecnt[threadIdx.x] = 0; }
    __syncthreads();

    float qx = xb[q], qy = xb[NN + q], qz = xb[2 * NN + q];
    float qsq = __fadd_rn(__fadd_rn(__fmul_rn(qx, qx), __fmul_rn(qy, qy)), __fmul_rn(qz, qz));

    int segbase = w * 128 + qh * 64;        // this lane's 64-candidate subrange

    TOP_DECL
    {   // ---- phase A: per-lane sorted top-16 du over its 64 candidates ----
        for (int i = 0; i < 64; i += 4) {
            float4 c0 = cand[segbase + i + 0];
            float4 c1 = cand[segbase + i + 1];
            float4 c2 = cand[segbase + i + 2];
            float4 c3 = cand[segbase + i + 3];
            unsigned int d0 = dist_du(qx, qy, qz, qsq, c0);
            unsigned int d1 = dist_du(qx, qy, qz, qsq, c1);
            unsigned int d2 = dist_du(qx, qy, qz, qsq, c2);
            unsigned int d3 = dist_du(qx, qy, qz, qsq, c3);
            TOP_INSERT(d0)
            TOP_INSERT(d1)
            TOP_INSERT(d2)
            TOP_INSERT(d3)
        }
    }

    {   // ---- intra-wave fold: merge lane-halves (both halves get the union top-16) ----
        unsigned int s0 = __shfl_xor(t0, 32),  s1 = __shfl_xor(t1, 32);
        unsigned int s2 = __shfl_xor(t2, 32),  s3 = __shfl_xor(t3, 32);
        unsigned int s4 = __shfl_xor(t4, 32),  s5 = __shfl_xor(t5, 32);
        unsigned int s6 = __shfl_xor(t6, 32),  s7 = __shfl_xor(t7, 32);
        unsigned int s8 = __shfl_xor(t8, 32),  s9 = __shfl_xor(t9, 32);
        unsigned int s10 = __shfl_xor(t10, 32), s11 = __shfl_xor(t11, 32);
        unsigned int s12 = __shfl_xor(t12, 32), s13 = __shfl_xor(t13, 32);
        unsigned int s14 = __shfl_xor(t14, 32), s15 = __shfl_xor(t15, 32);
        TOP_INSERT(s0)  TOP_INSERT(s1)  TOP_INSERT(s2)  TOP_INSERT(s3)
        TOP_INSERT(s4)  TOP_INSERT(s5)  TOP_INSERT(s6)  TOP_INSERT(s7)
        TOP_INSERT(s8)  TOP_INSERT(s9)  TOP_INSERT(s10) TOP_INSERT(s11)
        TOP_INSERT(s12) TOP_INSERT(s13) TOP_INSERT(s14) TOP_INSERT(s15)
    }

    // ---- tree merge: 16 -> 8 -> 4 -> 2 -> 1 wave-lists (T order-invariant) ----
    for (int s = 8; s >= 1; s >>= 1) {
        if (w >= s && w < 2 * s && lane < 32) {
            int j = w - s;
            mbuf[j][0][q32] = t0;   mbuf[j][1][q32] = t1;
            mbuf[j][2][q32] = t2;   mbuf[j][3][q32] = t3;
            mbuf[j][4][q32] = t4;   mbuf[j][5][q32] = t5;
            mbuf[j][6][q32] = t6;   mbuf[j][7][q32] = t7;
            mbuf[j][8][q32] = t8;   mbuf[j][9][q32] = t9;
            mbuf[j][10][q32] = t10; mbuf[j][11][q32] = t11;
            mbuf[j][12][q32] = t12; mbuf[j][13][q32] = t13;
            mbuf[j][14][q32] = t14; mbuf[j][15][q32] = t15;
        }
        __syncthreads();
        if (w < s) {
#pragma unroll
            for (int k = 0; k < KNNK; k++) {
                unsigned int u = mbuf[w][k][q32];
                TOP_INSERT(u)
            }
        }
        __syncthreads();
    }
    if (w == 0 && lane < 32) Tq[q32] = t15;
    __syncthreads();

    {   // ---- emission: each lane rescans its 64 cands; LDS-only writes ----
        unsigned int T = Tq[q32];
        for (int i = 0; i < 64; i++) {
            float4 c = cand[segbase + i];
            unsigned int du = dist_du(qx, qy, qz, qsq, c);
            if (du < T) {
                int slot = atomicAdd(&cntless[q32], 1);
                sel[slot][q32] = (unsigned short)(segbase + i);
            } else if (du == T) {
                int t = atomicAdd(&tiecnt[q32], 1);
                if (t < 16) tieidx[t][q32] = (unsigned short)(segbase + i);
            }
        }
    }
    __syncthreads();

    if (threadIdx.x < QG) {  // ---- finalize ties into sel (thread = query) ----
        unsigned int T = Tq[threadIdx.x];
        int cl = cntless[threadIdx.x];      // <= 15 by definition of T
        int need = KNNK - cl;
        int tc = tiecnt[threadIdx.x];
        if (need > 0) {
            if (tc <= 16) {                 // all ties captured: pick lowest-idx ones
                for (int r = 0; r < need; r++) {
                    int best = 0x7fffffff, bj = 0;
                    for (int j = 0; j < tc; j++) {
                        int v = tieidx[j][threadIdx.x];
                        if (v < best) { best = v; bj = j; }
                    }
                    tieidx[bj][threadIdx.x] = 0xFFFF;
                    sel[cl + r][threadIdx.x] = (unsigned short)best;
                }
            } else {                        // >16 ties: exact ascending-idx rescan
                int em = 0;
                for (int i = 0; i < NN && em < need; i++) {
                    unsigned int du = dist_du(qx, qy, qz, qsq, cand[i]);
                    if (du == T) { sel[cl + em][threadIdx.x] = (unsigned short)i; em++; }
                }
            }
        }
    }
    __syncthreads();

    if (lane < 32) {  // ---- write-out: entry w of query q32; 512 parallel atomics ----
        int x = (int)sel[w][q32];
        knn_idx[(size_t)bq * KNNK + w] = x;
        int pos = atomicAdd(&revcnt[b * NN + x], 1);
        if (pos < REVCAP) rev[((size_t)(b * NN + x)) * REVCAP + pos] = q;
    }
}

// ---------------- spec: f32 compute, bf16 output; dinv computed inline ----------------
__global__ __launch_bounds__(128) void spec_kernel(const float* __restrict__ fT,
                                                   const int* __restrict__ knn_idx,
                                                   const int* __restrict__ revcnt,
                                                   const int* __restrict__ rev,
                                                   __bf16* __restrict__ specB) {
    __shared__ int ml[KNNK + REVCAP];
    __shared__ float wl[KNNK + REVCAP];
    __shared__ int s_cnt;
    __shared__ float s_dn;

    int bn = blockIdx.x;           // b*NN + n
    int b = bn >> 11;
    int tid = threadIdx.x;

    if (tid == 0) {
        int c = revcnt[bn];
        s_cnt = c < REVCAP ? c : REVCAP;
        float D = 0.5f * (float)(KNNK + c);
        s_dn = 1.0f / sqrtf(D + 1e-6f);
    }
    __syncthreads();
    int cnt = s_cnt;
    if (tid < KNNK) ml[tid] = knn_idx[(size_t)bn * KNNK + tid];
    if (tid < cnt) ml[KNNK + tid] = rev[(size_t)bn * REVCAP + tid];
    __syncthreads();
    int total = KNNK + cnt;
    if (tid < total) {
        int m = ml[tid];
        float D = 0.5f * (float)(KNNK + revcnt[b * NN + m]);
        wl[tid] = 0.5f * (1.0f / sqrtf(D + 1e-6f));
    }
    __syncthreads();

    float dn = s_dn;
    float acc = 0.0f;
    for (int j = 0; j < total; j++)
        acc = fmaf(wl[j], fT[((size_t)b * NN + ml[j]) * CINC + tid], acc);
    float f0 = fT[(size_t)bn * CINC + tid];
    specB[(size_t)bn * CINC + tid] = (__bf16)(f0 - dn * acc);
}

// ---------------- fused GEMM1+GEMM2 via LDS g1 tile ----------------
// Phase 1 (= verified gemm1_mfma): g1 tile (64 n x 256 o) -> LDS (row pad +8).
// Phase 2 (= verified gemm2_mfma): out[b,o,n] = Wc @ g1^T from LDS, same
// fragment roles; only the B-operand source changed from global to LDS.
__global__ __launch_bounds__(256) void gemm12_fused(const __bf16* __restrict__ specB,
                                                    const __bf16* __restrict__ WspecB,
                                                    const float* __restrict__ bspec,
                                                    const float* __restrict__ gamma,
                                                    const float* __restrict__ beta,
                                                    const float* __restrict__ mean,
                                                    const float* __restrict__ var,
                                                    const __bf16* __restrict__ WcB,
                                                    const float* __restrict__ bc,
                                                    float* __restrict__ out) {
    __shared__ __bf16 g1s[64][COU + 8];    // 33 KB, pad -> 2-way-free LDS reads
    int b  = blockIdx.y;
    int n0 = blockIdx.x * 64;
    int w = threadIdx.x >> 6, lane = threadIdx.x & 63;
    int lr = lane & 15, lk = (lane >> 4) * 8;
    int rb = (lane >> 4) * 4;

    {   // ---- phase 1: spec @ Wspec^T + bias/BN/GELU -> g1s ----
        int o0 = w * 64;                   // 4 waves tile o = 0..255
        f32x4 acc[4][4] = {};
        const __bf16* As = specB + ((size_t)b * NN + n0 + lr) * CINC + lk;
        const __bf16* Bs = WspecB + (size_t)(o0 + lr) * CINC + lk;
#pragma unroll
        for (int kk = 0; kk < CINC; kk += 32) {
            bf16x8 a[4], bb[4];
#pragma unroll
            for (int m = 0; m < 4; m++)
                a[m] = *(const bf16x8*)(As + (size_t)(m * 16) * CINC + kk);
#pragma unroll
            for (int n = 0; n < 4; n++)
                bb[n] = *(const bf16x8*)(Bs + (size_t)(n * 16) * CINC + kk);
#pragma unroll
            for (int m = 0; m < 4; m++)
#pragma unroll
                for (int n = 0; n < 4; n++)
                    acc[m][n] = __builtin_amdgcn_mfma_f32_16x16x32_bf16(a[m], bb[n], acc[m][n], 0, 0, 0);
        }
#pragma unroll
        for (int n = 0; n < 4; n++) {
            int o = o0 + n * 16 + lr;
            float sc = 1.0f / sqrtf(var[o] + 1e-5f);
            float ga = gamma[o], be = beta[o], mu = mean[o], bs = bspec[o];
#pragma unroll
            for (int m = 0; m < 4; m++) {
#pragma unroll
                for (int j = 0; j < 4; j++) {
                    int nrow = m * 16 + rb + j;       // local n within tile
                    float y = acc[m][n][j] + bs;
                    y = (y - mu) * sc;
                    y = y * ga + be;
                    float g = 0.5f * y * (1.0f + erff(y * 0.70710678118654752440f));
                    g1s[nrow][o] = (__bf16)g;
                }
            }
        }
    }
    __syncthreads();

    {   // ---- phase 2: Wc @ g1^T + bias -> out ----
        int o0 = w * 64;                   // 4 waves tile o = 0..255
        f32x4 acc[4][4] = {};
        const __bf16* As = WcB + (size_t)(o0 + lr) * COU + lk;
#pragma unroll
        for (int kk = 0; kk < COU; kk += 32) {
            bf16x8 a[4], bb[4];
#pragma unroll
            for (int m = 0; m < 4; m++)
                a[m] = *(const bf16x8*)(As + (size_t)(m * 16) * COU + kk);
#pragma unroll
            for (int n = 0; n < 4; n++)
                bb[n] = *(const bf16x8*)(&g1s[n * 16 + lr][kk + lk]);
#pragma unroll
            for (int m = 0; m < 4; m++)
#pragma unroll
                for (int n = 0; n < 4; n++)
                    acc[m][n] = __builtin_amdgcn_mfma_f32_16x16x32_bf16(a[m], bb[n], acc[m][n], 0, 0, 0);
        }
#pragma unroll
        for (int m = 0; m < 4; m++) {
#pragma unroll
            for (int j = 0; j < 4; j++) {
                int o = o0 + m * 16 + rb + j;
                float bias = bc[o];
#pragma unroll
                for (int n = 0; n < 4; n++) {
                    int ncol = n0 + n * 16 + lr;
                    out[((size_t)b * COU + o) * NN + ncol] = acc[m][n][j] + bias;
                }
            }
        }
    }
}

extern "C" void kernel_launch(void* const* d_in, const int* in_sizes, int n_in,
                              void* d_out, int out_size, void* d_ws, size_t ws_size,
                              hipStream_t stream) {
    const float* xyz      = (const float*)d_in[0];
    const float* features = (const float*)d_in[1];
    const float* W_spec   = (const float*)d_in[2];
    const float* b_spec   = (const float*)d_in[3];
    const float* bn_gamma = (const float*)d_in[4];
    const float* bn_beta  = (const float*)d_in[5];
    const float* bn_mean  = (const float*)d_in[6];
    const float* bn_var   = (const float*)d_in[7];
    const float* W_low    = (const float*)d_in[8];
    const float* b_low    = (const float*)d_in[9];
    const float* W_high   = (const float*)d_in[10];
    const float* b_high   = (const float*)d_in[11];
    float* out = (float*)d_out;

    char* ws = (char*)d_ws;
    size_t off = 0;
    float*  fT    = (float*)(ws + off);  off += (size_t)BB * NN * CINC * 4;      // 8 MB
    __bf16* specB = (__bf16*)(ws + off); off += (size_t)BB * NN * CINC * 2;      // 4 MB
    int*    idx   = (int*)(ws + off);    off += (size_t)BB * NN * KNNK * 4;      // 1 MB
    int*    rcnt  = (int*)(ws + off);    off += (size_t)BB * NN * 4;             // 64 KB
    int*    rev   = (int*)(ws + off);    off += (size_t)BB * NN * REVCAP * 4;    // 4 MB
    __bf16* WspecB= (__bf16*)(ws + off); off += (size_t)COU * CINC * 2;          // 64 KB
    __bf16* WcB   = (__bf16*)(ws + off); off += (size_t)COU * COU * 2;           // 128 KB
    float*  bc    = (float*)(ws + off);  off += (size_t)COU * 4;                 // 1 KB

    hipMemsetAsync(rcnt, 0, (size_t)BB * NN * sizeof(int), stream);

    prep_kernel<<<dim3((COU * CINC + 255) / 256), dim3(256), 0, stream>>>(
        W_spec, W_low, W_high, b_low, b_high, WspecB, WcB, bc);
    transpose_kernel<<<dim3(NN / 32, CINC / 32, BB), dim3(32, 8), 0, stream>>>(features, fT);
    knn_fused_kernel<<<dim3(NN / QG, BB), dim3(1024), 0, stream>>>(xyz, idx, rcnt, rev);
    spec_kernel<<<dim3(BB * NN), dim3(128), 0, stream>>>(fT, idx, rcnt, rev, specB);
    gemm12_fused<<<dim3(NN / 64, BB), dim3(256), 0, stream>>>(
        specB, WspecB, b_spec, bn_gamma, bn_beta, bn_mean, bn_var, WcB, bc, out);
}

// Round 20
// 105.342 us; speedup vs baseline: 2.4499x; 1.0128x over previous
//
#include <hip/hip_runtime.h>
#include <hip/hip_bf16.h>
#include <math.h>

#define BB   8
#define NN   2048
#define BN   (BB * NN)
#define CINC 128
#define COU  256
#define KNNK 16
#define REVCAP 64
#define QG   32            // queries per knn block

typedef __bf16 bf16x8 __attribute__((ext_vector_type(8)));
typedef float  f32x4  __attribute__((ext_vector_type(4)));

#define UMED3(dst, a, bb_, c) asm("v_med3_u32 %0, %1, %2, %3" : "=v"(dst) : "v"(a), "v"(bb_), "v"(c))

#define TOP_DECL \
    unsigned int t0=~0u,t1=~0u,t2=~0u,t3=~0u,t4=~0u,t5=~0u,t6=~0u,t7=~0u, \
                 t8=~0u,t9=~0u,t10=~0u,t11=~0u,t12=~0u,t13=~0u,t14=~0u,t15=~0u;

// Insert u into sorted multiset {t0..t15}, dropping the max. 15 med3 + 1 min.
#define TOP_INSERT(u) {                     \
    UMED3(t15, t14, t15, (u));              \
    UMED3(t14, t13, t14, (u));              \
    UMED3(t13, t12, t13, (u));              \
    UMED3(t12, t11, t12, (u));              \
    UMED3(t11, t10, t11, (u));              \
    UMED3(t10, t9,  t10, (u));              \
    UMED3(t9,  t8,  t9,  (u));              \
    UMED3(t8,  t7,  t8,  (u));              \
    UMED3(t7,  t6,  t7,  (u));              \
    UMED3(t6,  t5,  t6,  (u));              \
    UMED3(t5,  t4,  t5,  (u));              \
    UMED3(t4,  t3,  t4,  (u));              \
    UMED3(t3,  t2,  t3,  (u));              \
    UMED3(t2,  t1,  t2,  (u));              \
    UMED3(t1,  t0,  t1,  (u));              \
    t0 = ((u) < t0) ? (u) : t0;             \
}

// dist arithmetic: bit-identical to the verified R1-R19 formula.
static __device__ __forceinline__ unsigned int dist_du(float qx, float qy, float qz,
                                                       float qsq, float4 c) {
    float dot = fmaf(qz, c.z, fmaf(qy, c.y, __fmul_rn(qx, c.x)));
    float d = __fsub_rn(__fadd_rn(qsq, c.w), __fmul_rn(2.0f, dot));
    unsigned int du = __float_as_uint(d);
    du ^= (unsigned int)((int)du >> 31) | 0x80000000u;
    return du;
}

// ---------------- setup: transpose (B,C,N)->fTB bf16 (B,N,C)  +  prep weights ----------------
// Blocks 0..2047: transpose tiles. Blocks 2048..2175: weight cast/concat.
__global__ __launch_bounds__(256) void setup_kernel(const float* __restrict__ feat,
                                                    __bf16* __restrict__ fTB,
                                                    const float* __restrict__ Wspec,
                                                    const float* __restrict__ Wlow,
                                                    const float* __restrict__ Whigh,
                                                    const float* __restrict__ blow,
                                                    const float* __restrict__ bhigh,
                                                    __bf16* __restrict__ WspecB,
                                                    __bf16* __restrict__ WcB,
                                                    float* __restrict__ bc) {
    __shared__ float t[32][33];
    int bid = blockIdx.x;
    int tx = threadIdx.x, ty = threadIdx.y;  // (32,8)
    if (bid < 2048) {
        int b  = bid >> 8;
        int r  = bid & 255;
        int n0 = (r & 63) * 32;
        int c0 = (r >> 6) * 32;
#pragma unroll
        for (int i = 0; i < 4; i++)
            t[ty + i * 8][tx] = feat[((size_t)b * CINC + c0 + ty + i * 8) * NN + n0 + tx];
        __syncthreads();
#pragma unroll
        for (int i = 0; i < 4; i++)
            fTB[((size_t)b * NN + n0 + ty + i * 8) * CINC + c0 + tx] = (__bf16)t[tx][ty + i * 8];
    } else {
        int i = (bid - 2048) * 256 + ty * 32 + tx;
        if (i < COU * CINC) WspecB[i] = (__bf16)Wspec[i];
        if (i < 128 * COU) {
            WcB[i] = (__bf16)Wlow[i];
            WcB[128 * COU + i] = (__bf16)Whigh[i];
        }
        if (i < 128) { bc[i] = blow[i]; bc[128 + i] = bhigh[i]; }
    }
}

// ---------------- KNN fused v5 (unchanged from verified R19) ----------------
__global__ __launch_bounds__(1024, 8) void knn_fused_kernel(const float* __restrict__ xyz,
                                                            int* __restrict__ knn_idx,
                                                            int* __restrict__ revcnt,
                                                            int* __restrict__ rev) {
    __shared__ float4 cand[NN];                     // 32 KB
    __shared__ unsigned int mbuf[8][KNNK][QG];      // 16 KB
    __shared__ unsigned int Tq[QG];
    __shared__ int cntless[QG];
    __shared__ int tiecnt[QG];
    __shared__ unsigned short tieidx[16][QG];
    __shared__ unsigned short sel[KNNK][QG];

    int b = blockIdx.y;
    int lane = threadIdx.x & 63;
    int w = threadIdx.x >> 6;
    int q32 = lane & 31;
    int qh = lane >> 5;
    int q = blockIdx.x * QG + q32;
    int bq = b * NN + q;

    const float* xb = xyz + (size_t)b * 3 * NN;
    for (int t = threadIdx.x; t < NN; t += 1024) {
        float x = xb[t], y = xb[NN + t], z = xb[2 * NN + t];
        float sq = __fadd_rn(__fadd_rn(__fmul_rn(x, x), __fmul_rn(y, y)), __fmul_rn(z, z));
        cand[t] = make_float4(x, y, z, sq);
    }
    if (threadIdx.x < QG) { cntless[threadIdx.x] = 0; tiecnt[threadIdx.x] = 0; }
    __syncthreads();

    float qx = xb[q], qy = xb[NN + q], qz = xb[2 * NN + q];
    float qsq = __fadd_rn(__fadd_rn(__fmul_rn(qx, qx), __fmul_rn(qy, qy)), __fmul_rn(qz, qz));

    int segbase = w * 128 + qh * 64;

    TOP_DECL
    for (int i = 0; i < 64; i += 4) {
        float4 c0 = cand[segbase + i + 0];
        float4 c1 = cand[segbase + i + 1];
        float4 c2 = cand[segbase + i + 2];
        float4 c3 = cand[segbase + i + 3];
        unsigned int d0 = dist_du(qx, qy, qz, qsq, c0);
        unsigned int d1 = dist_du(qx, qy, qz, qsq, c1);
        unsigned int d2 = dist_du(qx, qy, qz, qsq, c2);
        unsigned int d3 = dist_du(qx, qy, qz, qsq, c3);
        TOP_INSERT(d0)
        TOP_INSERT(d1)
        TOP_INSERT(d2)
        TOP_INSERT(d3)
    }

    {   // intra-wave fold: merge lane-halves
        unsigned int s0 = __shfl_xor(t0, 32),  s1 = __shfl_xor(t1, 32);
        unsigned int s2 = __shfl_xor(t2, 32),  s3 = __shfl_xor(t3, 32);
        unsigned int s4 = __shfl_xor(t4, 32),  s5 = __shfl_xor(t5, 32);
        unsigned int s6 = __shfl_xor(t6, 32),  s7 = __shfl_xor(t7, 32);
        unsigned int s8 = __shfl_xor(t8, 32),  s9 = __shfl_xor(t9, 32);
        unsigned int s10 = __shfl_xor(t10, 32), s11 = __shfl_xor(t11, 32);
        unsigned int s12 = __shfl_xor(t12, 32), s13 = __shfl_xor(t13, 32);
        unsigned int s14 = __shfl_xor(t14, 32), s15 = __shfl_xor(t15, 32);
        TOP_INSERT(s0)  TOP_INSERT(s1)  TOP_INSERT(s2)  TOP_INSERT(s3)
        TOP_INSERT(s4)  TOP_INSERT(s5)  TOP_INSERT(s6)  TOP_INSERT(s7)
        TOP_INSERT(s8)  TOP_INSERT(s9)  TOP_INSERT(s10) TOP_INSERT(s11)
        TOP_INSERT(s12) TOP_INSERT(s13) TOP_INSERT(s14) TOP_INSERT(s15)
    }

    for (int s = 8; s >= 1; s >>= 1) {
        if (w >= s && w < 2 * s && lane < 32) {
            int j = w - s;
            mbuf[j][0][q32] = t0;   mbuf[j][1][q32] = t1;
            mbuf[j][2][q32] = t2;   mbuf[j][3][q32] = t3;
            mbuf[j][4][q32] = t4;   mbuf[j][5][q32] = t5;
            mbuf[j][6][q32] = t6;   mbuf[j][7][q32] = t7;
            mbuf[j][8][q32] = t8;   mbuf[j][9][q32] = t9;
            mbuf[j][10][q32] = t10; mbuf[j][11][q32] = t11;
            mbuf[j][12][q32] = t12; mbuf[j][13][q32] = t13;
            mbuf[j][14][q32] = t14; mbuf[j][15][q32] = t15;
        }
        __syncthreads();
        if (w < s) {
#pragma unroll
            for (int k = 0; k < KNNK; k++) {
                unsigned int u = mbuf[w][k][q32];
                TOP_INSERT(u)
            }
        }
        __syncthreads();
    }
    if (w == 0 && lane < 32) Tq[q32] = t15;
    __syncthreads();

    {   // emission: LDS-only writes
        unsigned int T = Tq[q32];
        for (int i = 0; i < 64; i++) {
            float4 c = cand[segbase + i];
            unsigned int du = dist_du(qx, qy, qz, qsq, c);
            if (du < T) {
                int slot = atomicAdd(&cntless[q32], 1);
                sel[slot][q32] = (unsigned short)(segbase + i);
            } else if (du == T) {
                int t = atomicAdd(&tiecnt[q32], 1);
                if (t < 16) tieidx[t][q32] = (unsigned short)(segbase + i);
            }
        }
    }
    __syncthreads();

    if (threadIdx.x < QG) {  // finalize ties
        unsigned int T = Tq[threadIdx.x];
        int cl = cntless[threadIdx.x];
        int need = KNNK - cl;
        int tc = tiecnt[threadIdx.x];
        if (need > 0) {
            if (tc <= 16) {
                for (int r = 0; r < need; r++) {
                    int best = 0x7fffffff, bj = 0;
                    for (int j = 0; j < tc; j++) {
                        int v = tieidx[j][threadIdx.x];
                        if (v < best) { best = v; bj = j; }
                    }
                    tieidx[bj][threadIdx.x] = 0xFFFF;
                    sel[cl + r][threadIdx.x] = (unsigned short)best;
                }
            } else {
                int em = 0;
                for (int i = 0; i < NN && em < need; i++) {
                    unsigned int du = dist_du(qx, qy, qz, qsq, cand[i]);
                    if (du == T) { sel[cl + em][threadIdx.x] = (unsigned short)i; em++; }
                }
            }
        }
    }
    __syncthreads();

    if (lane < 32) {
        int x = (int)sel[w][q32];
        knn_idx[(size_t)bq * KNNK + w] = x;
        int pos = atomicAdd(&revcnt[b * NN + x], 1);
        if (pos < REVCAP) rev[((size_t)(b * NN + x)) * REVCAP + pos] = q;
    }
}

// ---------------- spec: bf16 gathers, 4-way ILP, bf16 output ----------------
__global__ __launch_bounds__(128) void spec_kernel(const __bf16* __restrict__ fTB,
                                                   const int* __restrict__ knn_idx,
                                                   const int* __restrict__ revcnt,
                                                   const int* __restrict__ rev,
                                                   __bf16* __restrict__ specB) {
    __shared__ int ml[KNNK + REVCAP];
    __shared__ float wl[KNNK + REVCAP];
    __shared__ int s_cnt;
    __shared__ float s_dn;

    int bn = blockIdx.x;           // b*NN + n
    int b = bn >> 11;
    int tid = threadIdx.x;

    if (tid == 0) {
        int c = revcnt[bn];
        s_cnt = c < REVCAP ? c : REVCAP;
        float D = 0.5f * (float)(KNNK + c);
        s_dn = 1.0f / sqrtf(D + 1e-6f);
    }
    __syncthreads();
    int cnt = s_cnt;
    if (tid < KNNK) ml[tid] = knn_idx[(size_t)bn * KNNK + tid];
    if (tid < cnt) ml[KNNK + tid] = rev[(size_t)bn * REVCAP + tid];
    __syncthreads();
    int total = KNNK + cnt;
    if (tid < total) {
        int m = ml[tid];
        float D = 0.5f * (float)(KNNK + revcnt[b * NN + m]);
        wl[tid] = 0.5f * (1.0f / sqrtf(D + 1e-6f));
    }
    __syncthreads();

    const __bf16* base = fTB + (size_t)b * NN * CINC + tid;
    float acc0 = 0.0f, acc1 = 0.0f, acc2 = 0.0f, acc3 = 0.0f;
    int j = 0;
    for (; j + 4 <= total; j += 4) {
        float f0v = (float)base[(size_t)ml[j + 0] * CINC];
        float f1v = (float)base[(size_t)ml[j + 1] * CINC];
        float f2v = (float)base[(size_t)ml[j + 2] * CINC];
        float f3v = (float)base[(size_t)ml[j + 3] * CINC];
        acc0 = fmaf(wl[j + 0], f0v, acc0);
        acc1 = fmaf(wl[j + 1], f1v, acc1);
        acc2 = fmaf(wl[j + 2], f2v, acc2);
        acc3 = fmaf(wl[j + 3], f3v, acc3);
    }
    for (; j < total; j++)
        acc0 = fmaf(wl[j], (float)base[(size_t)ml[j] * CINC], acc0);
    float acc = (acc0 + acc1) + (acc2 + acc3);

    float f0 = (float)base[(size_t)(bn & (NN - 1)) * CINC];
    specB[(size_t)bn * CINC + tid] = (__bf16)(f0 - s_dn * acc);
}

// ---------------- fused GEMM1+GEMM2 via LDS g1 tile (unchanged from R19) ----------------
__global__ __launch_bounds__(256) void gemm12_fused(const __bf16* __restrict__ specB,
                                                    const __bf16* __restrict__ WspecB,
                                                    const float* __restrict__ bspec,
                                                    const float* __restrict__ gamma,
                                                    const float* __restrict__ beta,
                                                    const float* __restrict__ mean,
                                                    const float* __restrict__ var,
                                                    const __bf16* __restrict__ WcB,
                                                    const float* __restrict__ bc,
                                                    float* __restrict__ out) {
    __shared__ __bf16 g1s[64][COU + 8];
    int b  = blockIdx.y;
    int n0 = blockIdx.x * 64;
    int w = threadIdx.x >> 6, lane = threadIdx.x & 63;
    int lr = lane & 15, lk = (lane >> 4) * 8;
    int rb = (lane >> 4) * 4;

    {   // phase 1: spec @ Wspec^T + bias/BN/GELU -> g1s
        int o0 = w * 64;
        f32x4 acc[4][4] = {};
        const __bf16* As = specB + ((size_t)b * NN + n0 + lr) * CINC + lk;
        const __bf16* Bs = WspecB + (size_t)(o0 + lr) * CINC + lk;
#pragma unroll
        for (int kk = 0; kk < CINC; kk += 32) {
            bf16x8 a[4], bb[4];
#pragma unroll
            for (int m = 0; m < 4; m++)
                a[m] = *(const bf16x8*)(As + (size_t)(m * 16) * CINC + kk);
#pragma unroll
            for (int n = 0; n < 4; n++)
                bb[n] = *(const bf16x8*)(Bs + (size_t)(n * 16) * CINC + kk);
#pragma unroll
            for (int m = 0; m < 4; m++)
#pragma unroll
                for (int n = 0; n < 4; n++)
                    acc[m][n] = __builtin_amdgcn_mfma_f32_16x16x32_bf16(a[m], bb[n], acc[m][n], 0, 0, 0);
        }
#pragma unroll
        for (int n = 0; n < 4; n++) {
            int o = o0 + n * 16 + lr;
            float sc = 1.0f / sqrtf(var[o] + 1e-5f);
            float ga = gamma[o], be = beta[o], mu = mean[o], bs = bspec[o];
#pragma unroll
            for (int m = 0; m < 4; m++) {
#pragma unroll
                for (int j = 0; j < 4; j++) {
                    int nrow = m * 16 + rb + j;
                    float y = acc[m][n][j] + bs;
                    y = (y - mu) * sc;
                    y = y * ga + be;
                    float g = 0.5f * y * (1.0f + erff(y * 0.70710678118654752440f));
                    g1s[nrow][o] = (__bf16)g;
                }
            }
        }
    }
    __syncthreads();

    {   // phase 2: Wc @ g1^T + bias -> out
        int o0 = w * 64;
        f32x4 acc[4][4] = {};
        const __bf16* As = WcB + (size_t)(o0 + lr) * COU + lk;
#pragma unroll
        for (int kk = 0; kk < COU; kk += 32) {
            bf16x8 a[4], bb[4];
#pragma unroll
            for (int m = 0; m < 4; m++)
                a[m] = *(const bf16x8*)(As + (size_t)(m * 16) * COU + kk);
#pragma unroll
            for (int n = 0; n < 4; n++)
                bb[n] = *(const bf16x8*)(&g1s[n * 16 + lr][kk + lk]);
#pragma unroll
            for (int m = 0; m < 4; m++)
#pragma unroll
                for (int n = 0; n < 4; n++)
                    acc[m][n] = __builtin_amdgcn_mfma_f32_16x16x32_bf16(a[m], bb[n], acc[m][n], 0, 0, 0);
        }
#pragma unroll
        for (int m = 0; m < 4; m++) {
#pragma unroll
            for (int j = 0; j < 4; j++) {
                int o = o0 + m * 16 + rb + j;
                float bias = bc[o];
#pragma unroll
                for (int n = 0; n < 4; n++) {
                    int ncol = n0 + n * 16 + lr;
                    out[((size_t)b * COU + o) * NN + ncol] = acc[m][n][j] + bias;
                }
            }
        }
    }
}

extern "C" void kernel_launch(void* const* d_in, const int* in_sizes, int n_in,
                              void* d_out, int out_size, void* d_ws, size_t ws_size,
                              hipStream_t stream) {
    const float* xyz      = (const float*)d_in[0];
    const float* features = (const float*)d_in[1];
    const float* W_spec   = (const float*)d_in[2];
    const float* b_spec   = (const float*)d_in[3];
    const float* bn_gamma = (const float*)d_in[4];
    const float* bn_beta  = (const float*)d_in[5];
    const float* bn_mean  = (const float*)d_in[6];
    const float* bn_var   = (const float*)d_in[7];
    const float* W_low    = (const float*)d_in[8];
    const float* b_low    = (const float*)d_in[9];
    const float* W_high   = (const float*)d_in[10];
    const float* b_high   = (const float*)d_in[11];
    float* out = (float*)d_out;

    char* ws = (char*)d_ws;
    size_t off = 0;
    __bf16* fTB   = (__bf16*)(ws + off); off += (size_t)BB * NN * CINC * 2;      // 4 MB
    __bf16* specB = (__bf16*)(ws + off); off += (size_t)BB * NN * CINC * 2;      // 4 MB
    int*    idx   = (int*)(ws + off);    off += (size_t)BB * NN * KNNK * 4;      // 1 MB
    int*    rcnt  = (int*)(ws + off);    off += (size_t)BB * NN * 4;             // 64 KB
    int*    rev   = (int*)(ws + off);    off += (size_t)BB * NN * REVCAP * 4;    // 4 MB
    __bf16* WspecB= (__bf16*)(ws + off); off += (size_t)COU * CINC * 2;          // 64 KB
    __bf16* WcB   = (__bf16*)(ws + off); off += (size_t)COU * COU * 2;           // 128 KB
    float*  bc    = (float*)(ws + off);  off += (size_t)COU * 4;                 // 1 KB

    hipMemsetAsync(rcnt, 0, (size_t)BB * NN * sizeof(int), stream);

    setup_kernel<<<dim3(2048 + 128), dim3(32, 8), 0, stream>>>(
        features, fTB, W_spec, W_low, W_high, b_low, b_high, WspecB, WcB, bc);
    knn_fused_kernel<<<dim3(NN / QG, BB), dim3(1024), 0, stream>>>(xyz, idx, rcnt, rev);
    spec_kernel<<<dim3(BB * NN), dim3(128), 0, stream>>>(fTB, idx, rcnt, rev, specB);
    gemm12_fused<<<dim3(NN / 64, BB), dim3(256), 0, stream>>>(
        specB, WspecB, b_spec, bn_gamma, bn_beta, bn_mean, bn_var, WcB, bc, out);
}

// Round 22
// 97.100 us; speedup vs baseline: 2.6579x; 1.0849x over previous
//
#include <hip/hip_runtime.h>
#include <hip/hip_bf16.h>
#include <math.h>

#define BB   8
#define NN   2048
#define BN   (BB * NN)
#define CINC 128
#define COU  256
#define KNNK 16
#define REVCAP 64
#define QG   32            // queries per knn block

typedef __bf16 bf16x8 __attribute__((ext_vector_type(8)));
typedef float  f32x4  __attribute__((ext_vector_type(4)));

#define UMED3(dst, a, bb_, c) asm("v_med3_u32 %0, %1, %2, %3" : "=v"(dst) : "v"(a), "v"(bb_), "v"(c))

// 16 sorted regs t0<=..<=t15 (t8..t15 only used from the fold onward).
#define TOP_DECL \
    unsigned int t0=~0u,t1=~0u,t2=~0u,t3=~0u,t4=~0u,t5=~0u,t6=~0u,t7=~0u, \
                 t8=~0u,t9=~0u,t10=~0u,t11=~0u,t12=~0u,t13=~0u,t14=~0u,t15=~0u;

// 16-deep insert (merge/fallback): 15 med3 + 1 min.
#define TOP_INSERT(u) {                     \
    UMED3(t15, t14, t15, (u));              \
    UMED3(t14, t13, t14, (u));              \
    UMED3(t13, t12, t13, (u));              \
    UMED3(t12, t11, t12, (u));              \
    UMED3(t11, t10, t11, (u));              \
    UMED3(t10, t9,  t10, (u));              \
    UMED3(t9,  t8,  t9,  (u));              \
    UMED3(t8,  t7,  t8,  (u));              \
    UMED3(t7,  t6,  t7,  (u));              \
    UMED3(t6,  t5,  t6,  (u));              \
    UMED3(t5,  t4,  t5,  (u));              \
    UMED3(t4,  t3,  t4,  (u));              \
    UMED3(t3,  t2,  t3,  (u));              \
    UMED3(t2,  t1,  t2,  (u));              \
    UMED3(t1,  t0,  t1,  (u));              \
    t0 = ((u) < t0) ? (u) : t0;             \
}

// 8-deep insert (hot scan): 7 med3 + 1 min. Per-lane lists only feed the
// T computation; exactness is guaranteed by the cl>=16 detect + fallback.
#define TOP8_INSERT(u) {                    \
    UMED3(t7,  t6,  t7,  (u));              \
    UMED3(t6,  t5,  t6,  (u));              \
    UMED3(t5,  t4,  t5,  (u));              \
    UMED3(t4,  t3,  t4,  (u));              \
    UMED3(t3,  t2,  t3,  (u));              \
    UMED3(t2,  t1,  t2,  (u));              \
    UMED3(t1,  t0,  t1,  (u));              \
    t0 = ((u) < t0) ? (u) : t0;             \
}

// dist arithmetic: bit-identical to the verified R1-R20 formula.
static __device__ __forceinline__ unsigned int dist_du(float qx, float qy, float qz,
                                                       float qsq, float4 c) {
    float dot = fmaf(qz, c.z, fmaf(qy, c.y, __fmul_rn(qx, c.x)));
    float d = __fsub_rn(__fadd_rn(qsq, c.w), __fmul_rn(2.0f, dot));
    unsigned int du = __float_as_uint(d);
    du ^= (unsigned int)((int)du >> 31) | 0x80000000u;
    return du;
}

// ---------------- setup: transpose (B,C,N)->fTB bf16 (B,N,C)  +  prep weights ----------------
__global__ __launch_bounds__(256) void setup_kernel(const float* __restrict__ feat,
                                                    __bf16* __restrict__ fTB,
                                                    const float* __restrict__ Wspec,
                                                    const float* __restrict__ Wlow,
                                                    const float* __restrict__ Whigh,
                                                    const float* __restrict__ blow,
                                                    const float* __restrict__ bhigh,
                                                    __bf16* __restrict__ WspecB,
                                                    __bf16* __restrict__ WcB,
                                                    float* __restrict__ bc) {
    __shared__ float t[32][33];
    int bid = blockIdx.x;
    int tx = threadIdx.x, ty = threadIdx.y;  // (32,8)
    if (bid < 2048) {
        int b  = bid >> 8;
        int r  = bid & 255;
        int n0 = (r & 63) * 32;
        int c0 = (r >> 6) * 32;
#pragma unroll
        for (int i = 0; i < 4; i++)
            t[ty + i * 8][tx] = feat[((size_t)b * CINC + c0 + ty + i * 8) * NN + n0 + tx];
        __syncthreads();
#pragma unroll
        for (int i = 0; i < 4; i++)
            fTB[((size_t)b * NN + n0 + ty + i * 8) * CINC + c0 + tx] = (__bf16)t[tx][ty + i * 8];
    } else {
        int i = (bid - 2048) * 256 + ty * 32 + tx;
        if (i < COU * CINC) WspecB[i] = (__bf16)Wspec[i];
        if (i < 128 * COU) {
            WcB[i] = (__bf16)Wlow[i];
            WcB[128 * COU + i] = (__bf16)Whigh[i];
        }
        if (i < 128) { bc[i] = blow[i]; bc[128 + i] = bhigh[i]; }
    }
}

// ---------------- KNN fused v6: per-lane top-8 scan + exact detect/fallback ----------------
// T_est = 16th smallest of union of per-lane top-8s >= T_true, equal unless one
// lane holds >=9 of the true top-16 (~1e-8/query). Emission counts cntless =
// #{du < T_est}: cl >= 16 <=> T_est wrong -> exact serial fallback (lax.top_k
// semantics). Otherwise identical selection to the verified R14-R20 path.
__global__ __launch_bounds__(1024, 8) void knn_fused_kernel(const float* __restrict__ xyz,
                                                            int* __restrict__ knn_idx,
                                                            int* __restrict__ revcnt,
                                                            int* __restrict__ rev) {
    __shared__ float4 cand[NN];                     // 32 KB
    __shared__ unsigned int mbuf[8][KNNK][QG];      // 16 KB
    __shared__ unsigned int Tq[QG];
    __shared__ int cntless[QG];
    __shared__ int tiecnt[QG];
    __shared__ unsigned short tieidx[16][QG];
    __shared__ unsigned short sel[KNNK][QG];

    int b = blockIdx.y;
    int lane = threadIdx.x & 63;
    int w = threadIdx.x >> 6;
    int q32 = lane & 31;
    int qh = lane >> 5;
    int q = blockIdx.x * QG + q32;
    int bq = b * NN + q;

    const float* xb = xyz + (size_t)b * 3 * NN;
    for (int t = threadIdx.x; t < NN; t += 1024) {
        float x = xb[t], y = xb[NN + t], z = xb[2 * NN + t];
        float sq = __fadd_rn(__fadd_rn(__fmul_rn(x, x), __fmul_rn(y, y)), __fmul_rn(z, z));
        cand[t] = make_float4(x, y, z, sq);
    }
    if (threadIdx.x < QG) { cntless[threadIdx.x] = 0; tiecnt[threadIdx.x] = 0; }
    __syncthreads();

    float qx = xb[q], qy = xb[NN + q], qz = xb[2 * NN + q];
    float qsq = __fadd_rn(__fadd_rn(__fmul_rn(qx, qx), __fmul_rn(qy, qy)), __fmul_rn(qz, qz));

    int segbase = w * 128 + qh * 64;

    TOP_DECL
    for (int i = 0; i < 64; i += 4) {   // phase A: 8-deep scan (hot loop)
        float4 c0 = cand[segbase + i + 0];
        float4 c1 = cand[segbase + i + 1];
        float4 c2 = cand[segbase + i + 2];
        float4 c3 = cand[segbase + i + 3];
        unsigned int d0 = dist_du(qx, qy, qz, qsq, c0);
        unsigned int d1 = dist_du(qx, qy, qz, qsq, c1);
        unsigned int d2 = dist_du(qx, qy, qz, qsq, c2);
        unsigned int d3 = dist_du(qx, qy, qz, qsq, c3);
        TOP8_INSERT(d0)
        TOP8_INSERT(d1)
        TOP8_INSERT(d2)
        TOP8_INSERT(d3)
    }

    {   // intra-wave fold: partner's 8-list into this lane's 16-list (t8..t15 = inf)
        unsigned int s0 = __shfl_xor(t0, 32), s1 = __shfl_xor(t1, 32);
        unsigned int s2 = __shfl_xor(t2, 32), s3 = __shfl_xor(t3, 32);
        unsigned int s4 = __shfl_xor(t4, 32), s5 = __shfl_xor(t5, 32);
        unsigned int s6 = __shfl_xor(t6, 32), s7 = __shfl_xor(t7, 32);
        TOP_INSERT(s0) TOP_INSERT(s1) TOP_INSERT(s2) TOP_INSERT(s3)
        TOP_INSERT(s4) TOP_INSERT(s5) TOP_INSERT(s6) TOP_INSERT(s7)
    }

    for (int s = 8; s >= 1; s >>= 1) {  // tree merge (16-wide, unchanged)
        if (w >= s && w < 2 * s && lane < 32) {
            int j = w - s;
            mbuf[j][0][q32] = t0;   mbuf[j][1][q32] = t1;
            mbuf[j][2][q32] = t2;   mbuf[j][3][q32] = t3;
            mbuf[j][4][q32] = t4;   mbuf[j][5][q32] = t5;
            mbuf[j][6][q32] = t6;   mbuf[j][7][q32] = t7;
            mbuf[j][8][q32] = t8;   mbuf[j][9][q32] = t9;
            mbuf[j][10][q32] = t10; mbuf[j][11][q32] = t11;
            mbuf[j][12][q32] = t12; mbuf[j][13][q32] = t13;
            mbuf[j][14][q32] = t14; mbuf[j][15][q32] = t15;
        }
        __syncthreads();
        if (w < s) {
#pragma unroll
            for (int k = 0; k < KNNK; k++) {
                unsigned int u = mbuf[w][k][q32];
                TOP_INSERT(u)
            }
        }
        __syncthreads();
    }
    if (w == 0 && lane < 32) Tq[q32] = t15;
    __syncthreads();

    {   // emission: LDS-only writes, slot guarded (T_est may be wrong -> cl>=16)
        unsigned int T = Tq[q32];
        for (int i = 0; i < 64; i++) {
            float4 c = cand[segbase + i];
            unsigned int du = dist_du(qx, qy, qz, qsq, c);
            if (du < T) {
                int slot = atomicAdd(&cntless[q32], 1);
                if (slot < 16) sel[slot][q32] = (unsigned short)(segbase + i);
            } else if (du == T) {
                int t = atomicAdd(&tiecnt[q32], 1);
                if (t < 16) tieidx[t][q32] = (unsigned short)(segbase + i);
            }
        }
    }
    __syncthreads();

    if (threadIdx.x < QG) {  // finalize (thread = query)
        int cl = cntless[threadIdx.x];
        if (cl >= 16) {
            // exact fallback (~1e-8/query): full 16-deep scan -> true T, then
            // ascending emit du<T, then ascending ties. Pure lax.top_k.
            TOP_DECL                          // shadows outer regs (dead here)
            for (int i = 0; i < NN; i++) {
                unsigned int du = dist_du(qx, qy, qz, qsq, cand[i]);
                TOP_INSERT(du)
            }
            unsigned int Tt = t15;
            int fp = 0;
            for (int i = 0; i < NN && fp < KNNK; i++) {
                unsigned int du = dist_du(qx, qy, qz, qsq, cand[i]);
                if (du < Tt) sel[fp++][threadIdx.x] = (unsigned short)i;
            }
            for (int i = 0; i < NN && fp < KNNK; i++) {
                unsigned int du = dist_du(qx, qy, qz, qsq, cand[i]);
                if (du == Tt) sel[fp++][threadIdx.x] = (unsigned short)i;
            }
        } else {
            unsigned int T = Tq[threadIdx.x];
            int need = KNNK - cl;
            int tc = tiecnt[threadIdx.x];
            if (need > 0) {
                if (tc <= 16) {
                    for (int r = 0; r < need; r++) {
                        int best = 0x7fffffff, bj = 0;
                        for (int j = 0; j < tc; j++) {
                            int v = tieidx[j][threadIdx.x];
                            if (v < best) { best = v; bj = j; }
                        }
                        tieidx[bj][threadIdx.x] = 0xFFFF;
                        sel[cl + r][threadIdx.x] = (unsigned short)best;
                    }
                } else {
                    int em = 0;
                    for (int i = 0; i < NN && em < need; i++) {
                        unsigned int du = dist_du(qx, qy, qz, qsq, cand[i]);
                        if (du == T) { sel[cl + em][threadIdx.x] = (unsigned short)i; em++; }
                    }
                }
            }
        }
    }
    __syncthreads();

    if (lane < 32) {  // write-out: entry w of query q32
        int x = (int)sel[w][q32];
        knn_idx[(size_t)bq * KNNK + w] = x;
        int pos = atomicAdd(&revcnt[b * NN + x], 1);
        if (pos < REVCAP) rev[((size_t)(b * NN + x)) * REVCAP + pos] = q;
    }
}

// ---------------- spec: bf16 gathers, 4-way ILP, bf16 output (unchanged R20) ----------------
__global__ __launch_bounds__(128) void spec_kernel(const __bf16* __restrict__ fTB,
                                                   const int* __restrict__ knn_idx,
                                                   const int* __restrict__ revcnt,
                                                   const int* __restrict__ rev,
                                                   __bf16* __restrict__ specB) {
    __shared__ int ml[KNNK + REVCAP];
    __shared__ float wl[KNNK + REVCAP];
    __shared__ int s_cnt;
    __shared__ float s_dn;

    int bn = blockIdx.x;           // b*NN + n
    int b = bn >> 11;
    int tid = threadIdx.x;

    if (tid == 0) {
        int c = revcnt[bn];
        s_cnt = c < REVCAP ? c : REVCAP;
        float D = 0.5f * (float)(KNNK + c);
        s_dn = 1.0f / sqrtf(D + 1e-6f);
    }
    __syncthreads();
    int cnt = s_cnt;
    if (tid < KNNK) ml[tid] = knn_idx[(size_t)bn * KNNK + tid];
    if (tid < cnt) ml[KNNK + tid] = rev[(size_t)bn * REVCAP + tid];
    __syncthreads();
    int total = KNNK + cnt;
    if (tid < total) {
        int m = ml[tid];
        float D = 0.5f * (float)(KNNK + revcnt[b * NN + m]);
        wl[tid] = 0.5f * (1.0f / sqrtf(D + 1e-6f));
    }
    __syncthreads();

    const __bf16* base = fTB + (size_t)b * NN * CINC + tid;
    float acc0 = 0.0f, acc1 = 0.0f, acc2 = 0.0f, acc3 = 0.0f;
    int j = 0;
    for (; j + 4 <= total; j += 4) {
        float f0v = (float)base[(size_t)ml[j + 0] * CINC];
        float f1v = (float)base[(size_t)ml[j + 1] * CINC];
        float f2v = (float)base[(size_t)ml[j + 2] * CINC];
        float f3v = (float)base[(size_t)ml[j + 3] * CINC];
        acc0 = fmaf(wl[j + 0], f0v, acc0);
        acc1 = fmaf(wl[j + 1], f1v, acc1);
        acc2 = fmaf(wl[j + 2], f2v, acc2);
        acc3 = fmaf(wl[j + 3], f3v, acc3);
    }
    for (; j < total; j++)
        acc0 = fmaf(wl[j], (float)base[(size_t)ml[j] * CINC], acc0);
    float acc = (acc0 + acc1) + (acc2 + acc3);

    float f0 = (float)base[(size_t)(bn & (NN - 1)) * CINC];
    specB[(size_t)bn * CINC + tid] = (__bf16)(f0 - s_dn * acc);
}

// ---------------- fused GEMM1+GEMM2 via LDS g1 tile (unchanged R20) ----------------
__global__ __launch_bounds__(256) void gemm12_fused(const __bf16* __restrict__ specB,
                                                    const __bf16* __restrict__ WspecB,
                                                    const float* __restrict__ bspec,
                                                    const float* __restrict__ gamma,
                                                    const float* __restrict__ beta,
                                                    const float* __restrict__ mean,
                                                    const float* __restrict__ var,
                                                    const __bf16* __restrict__ WcB,
                                                    const float* __restrict__ bc,
                                                    float* __restrict__ out) {
    __shared__ __bf16 g1s[64][COU + 8];
    int b  = blockIdx.y;
    int n0 = blockIdx.x * 64;
    int w = threadIdx.x >> 6, lane = threadIdx.x & 63;
    int lr = lane & 15, lk = (lane >> 4) * 8;
    int rb = (lane >> 4) * 4;

    {   // phase 1: spec @ Wspec^T + bias/BN/GELU -> g1s
        int o0 = w * 64;
        f32x4 acc[4][4] = {};
        const __bf16* As = specB + ((size_t)b * NN + n0 + lr) * CINC + lk;
        const __bf16* Bs = WspecB + (size_t)(o0 + lr) * CINC + lk;
#pragma unroll
        for (int kk = 0; kk < CINC; kk += 32) {
            bf16x8 a[4], bb[4];
#pragma unroll
            for (int m = 0; m < 4; m++)
                a[m] = *(const bf16x8*)(As + (size_t)(m * 16) * CINC + kk);
#pragma unroll
            for (int n = 0; n < 4; n++)
                bb[n] = *(const bf16x8*)(Bs + (size_t)(n * 16) * CINC + kk);
#pragma unroll
            for (int m = 0; m < 4; m++)
#pragma unroll
                for (int n = 0; n < 4; n++)
                    acc[m][n] = __builtin_amdgcn_mfma_f32_16x16x32_bf16(a[m], bb[n], acc[m][n], 0, 0, 0);
        }
#pragma unroll
        for (int n = 0; n < 4; n++) {
            int o = o0 + n * 16 + lr;
            float sc = 1.0f / sqrtf(var[o] + 1e-5f);
            float ga = gamma[o], be = beta[o], mu = mean[o], bs = bspec[o];
#pragma unroll
            for (int m = 0; m < 4; m++) {
#pragma unroll
                for (int j = 0; j < 4; j++) {
                    int nrow = m * 16 + rb + j;
                    float y = acc[m][n][j] + bs;
                    y = (y - mu) * sc;
                    y = y * ga + be;
                    float g = 0.5f * y * (1.0f + erff(y * 0.70710678118654752440f));
                    g1s[nrow][o] = (__bf16)g;
                }
            }
        }
    }
    __syncthreads();

    {   // phase 2: Wc @ g1^T + bias -> out
        int o0 = w * 64;
        f32x4 acc[4][4] = {};
        const __bf16* As = WcB + (size_t)(o0 + lr) * COU + lk;
#pragma unroll
        for (int kk = 0; kk < COU; kk += 32) {
            bf16x8 a[4], bb[4];
#pragma unroll
            for (int m = 0; m < 4; m++)
                a[m] = *(const bf16x8*)(As + (size_t)(m * 16) * COU + kk);
#pragma unroll
            for (int n = 0; n < 4; n++)
                bb[n] = *(const bf16x8*)(&g1s[n * 16 + lr][kk + lk]);
#pragma unroll
            for (int m = 0; m < 4; m++)
#pragma unroll
                for (int n = 0; n < 4; n++)
                    acc[m][n] = __builtin_amdgcn_mfma_f32_16x16x32_bf16(a[m], bb[n], acc[m][n], 0, 0, 0);
        }
#pragma unroll
        for (int m = 0; m < 4; m++) {
#pragma unroll
            for (int j = 0; j < 4; j++) {
                int o = o0 + m * 16 + rb + j;
                float bias = bc[o];
#pragma unroll
                for (int n = 0; n < 4; n++) {
                    int ncol = n0 + n * 16 + lr;
                    out[((size_t)b * COU + o) * NN + ncol] = acc[m][n][j] + bias;
                }
            }
        }
    }
}

extern "C" void kernel_launch(void* const* d_in, const int* in_sizes, int n_in,
                              void* d_out, int out_size, void* d_ws, size_t ws_size,
                              hipStream_t stream) {
    const float* xyz      = (const float*)d_in[0];
    const float* features = (const float*)d_in[1];
    const float* W_spec   = (const float*)d_in[2];
    const float* b_spec   = (const float*)d_in[3];
    const float* bn_gamma = (const float*)d_in[4];
    const float* bn_beta  = (const float*)d_in[5];
    const float* bn_mean  = (const float*)d_in[6];
    const float* bn_var   = (const float*)d_in[7];
    const float* W_low    = (const float*)d_in[8];
    const float* b_low    = (const float*)d_in[9];
    const float* W_high   = (const float*)d_in[10];
    const float* b_high   = (const float*)d_in[11];
    float* out = (float*)d_out;

    char* ws = (char*)d_ws;
    size_t off = 0;
    __bf16* fTB   = (__bf16*)(ws + off); off += (size_t)BB * NN * CINC * 2;      // 4 MB
    __bf16* specB = (__bf16*)(ws + off); off += (size_t)BB * NN * CINC * 2;      // 4 MB
    int*    idx   = (int*)(ws + off);    off += (size_t)BB * NN * KNNK * 4;      // 1 MB
    int*    rcnt  = (int*)(ws + off);    off += (size_t)BB * NN * 4;             // 64 KB
    int*    rev   = (int*)(ws + off);    off += (size_t)BB * NN * REVCAP * 4;    // 4 MB
    __bf16* WspecB= (__bf16*)(ws + off); off += (size_t)COU * CINC * 2;          // 64 KB
    __bf16* WcB   = (__bf16*)(ws + off); off += (size_t)COU * COU * 2;           // 128 KB
    float*  bc    = (float*)(ws + off);  off += (size_t)COU * 4;                 // 1 KB

    hipMemsetAsync(rcnt, 0, (size_t)BB * NN * sizeof(int), stream);

    setup_kernel<<<dim3(2048 + 128), dim3(32, 8), 0, stream>>>(
        features, fTB, W_spec, W_low, W_high, b_low, b_high, WspecB, WcB, bc);
    knn_fused_kernel<<<dim3(NN / QG, BB), dim3(1024), 0, stream>>>(xyz, idx, rcnt, rev);
    spec_kernel<<<dim3(BB * NN), dim3(128), 0, stream>>>(fTB, idx, rcnt, rev, specB);
    gemm12_fused<<<dim3(NN / 64, BB), dim3(256), 0, stream>>>(
        specB, WspecB, b_spec, bn_gamma, bn_beta, bn_mean, bn_var, WcB, bc, out);
}

// Round 23
// 92.197 us; speedup vs baseline: 2.7992x; 1.0532x over previous
//
#include <hip/hip_runtime.h>
#include <hip/hip_bf16.h>
#include <math.h>

#define BB   8
#define NN   2048
#define BN   (BB * NN)
#define CINC 128
#define COU  256
#define KNNK 16
#define REVCAP 64
#define QG   32            // queries per knn block

typedef __bf16 bf16x8 __attribute__((ext_vector_type(8)));
typedef float  f32x4  __attribute__((ext_vector_type(4)));

#define UMED3(dst, a, bb_, c) asm("v_med3_u32 %0, %1, %2, %3" : "=v"(dst) : "v"(a), "v"(bb_), "v"(c))

// 16 sorted regs t0<=..<=t15 (t8..t15 only used from the fold onward).
#define TOP_DECL \
    unsigned int t0=~0u,t1=~0u,t2=~0u,t3=~0u,t4=~0u,t5=~0u,t6=~0u,t7=~0u, \
                 t8=~0u,t9=~0u,t10=~0u,t11=~0u,t12=~0u,t13=~0u,t14=~0u,t15=~0u;

// 16-deep insert (merge/fallback): 15 med3 + 1 min.
#define TOP_INSERT(u) {                     \
    UMED3(t15, t14, t15, (u));              \
    UMED3(t14, t13, t14, (u));              \
    UMED3(t13, t12, t13, (u));              \
    UMED3(t12, t11, t12, (u));              \
    UMED3(t11, t10, t11, (u));              \
    UMED3(t10, t9,  t10, (u));              \
    UMED3(t9,  t8,  t9,  (u));              \
    UMED3(t8,  t7,  t8,  (u));              \
    UMED3(t7,  t6,  t7,  (u));              \
    UMED3(t6,  t5,  t6,  (u));              \
    UMED3(t5,  t4,  t5,  (u));              \
    UMED3(t4,  t3,  t4,  (u));              \
    UMED3(t3,  t2,  t3,  (u));              \
    UMED3(t2,  t1,  t2,  (u));              \
    UMED3(t1,  t0,  t1,  (u));              \
    t0 = ((u) < t0) ? (u) : t0;             \
}

// 8-deep insert (hot scan): 7 med3 + 1 min. Per-lane lists only feed the
// T computation; exactness is guaranteed by the cl>=16 detect + fallback.
#define TOP8_INSERT(u) {                    \
    UMED3(t7,  t6,  t7,  (u));              \
    UMED3(t6,  t5,  t6,  (u));              \
    UMED3(t5,  t4,  t5,  (u));              \
    UMED3(t4,  t3,  t4,  (u));              \
    UMED3(t3,  t2,  t3,  (u));              \
    UMED3(t2,  t1,  t2,  (u));              \
    UMED3(t1,  t0,  t1,  (u));              \
    t0 = ((u) < t0) ? (u) : t0;             \
}

// dist arithmetic: bit-identical to the verified R1-R22 formula.
static __device__ __forceinline__ unsigned int dist_du(float qx, float qy, float qz,
                                                       float qsq, float4 c) {
    float dot = fmaf(qz, c.z, fmaf(qy, c.y, __fmul_rn(qx, c.x)));
    float d = __fsub_rn(__fadd_rn(qsq, c.w), __fmul_rn(2.0f, dot));
    unsigned int du = __float_as_uint(d);
    du ^= (unsigned int)((int)du >> 31) | 0x80000000u;
    return du;
}

// ---------------- setup: transpose + prep weights + zero rcnt (replaces memset) ----------------
__global__ __launch_bounds__(256) void setup_kernel(const float* __restrict__ feat,
                                                    __bf16* __restrict__ fTB,
                                                    const float* __restrict__ Wspec,
                                                    const float* __restrict__ Wlow,
                                                    const float* __restrict__ Whigh,
                                                    const float* __restrict__ blow,
                                                    const float* __restrict__ bhigh,
                                                    __bf16* __restrict__ WspecB,
                                                    __bf16* __restrict__ WcB,
                                                    float* __restrict__ bc,
                                                    int* __restrict__ rcnt) {
    __shared__ float t[32][33];
    int bid = blockIdx.x;
    int tx = threadIdx.x, ty = threadIdx.y;  // (32,8)
    if (bid < 2048) {
        int b  = bid >> 8;
        int r  = bid & 255;
        int n0 = (r & 63) * 32;
        int c0 = (r >> 6) * 32;
#pragma unroll
        for (int i = 0; i < 4; i++)
            t[ty + i * 8][tx] = feat[((size_t)b * CINC + c0 + ty + i * 8) * NN + n0 + tx];
        __syncthreads();
#pragma unroll
        for (int i = 0; i < 4; i++)
            fTB[((size_t)b * NN + n0 + ty + i * 8) * CINC + c0 + tx] = (__bf16)t[tx][ty + i * 8];
    } else {
        int r = bid - 2048;                  // 0..127
        int i = r * 256 + ty * 32 + tx;
        if (i < COU * CINC) WspecB[i] = (__bf16)Wspec[i];
        if (i < 128 * COU) {
            WcB[i] = (__bf16)Wlow[i];
            WcB[128 * COU + i] = (__bf16)Whigh[i];
        }
        if (i < 128) { bc[i] = blow[i]; bc[128 + i] = bhigh[i]; }
        // zero rcnt: 128 blocks x 128 ints = 16384 ints (BB*NN)
        rcnt[r * 128 + (ty * 32 + tx) % 128] = 0;   // each of 256 threads hits 128 slots twice (idempotent)
    }
}

// ---------------- KNN fused v6 (unchanged from verified R22) ----------------
__global__ __launch_bounds__(1024, 8) void knn_fused_kernel(const float* __restrict__ xyz,
                                                            int* __restrict__ knn_idx,
                                                            int* __restrict__ revcnt,
                                                            int* __restrict__ rev) {
    __shared__ float4 cand[NN];                     // 32 KB
    __shared__ unsigned int mbuf[8][KNNK][QG];      // 16 KB
    __shared__ unsigned int Tq[QG];
    __shared__ int cntless[QG];
    __shared__ int tiecnt[QG];
    __shared__ unsigned short tieidx[16][QG];
    __shared__ unsigned short sel[KNNK][QG];

    int b = blockIdx.y;
    int lane = threadIdx.x & 63;
    int w = threadIdx.x >> 6;
    int q32 = lane & 31;
    int qh = lane >> 5;
    int q = blockIdx.x * QG + q32;
    int bq = b * NN + q;

    const float* xb = xyz + (size_t)b * 3 * NN;
    for (int t = threadIdx.x; t < NN; t += 1024) {
        float x = xb[t], y = xb[NN + t], z = xb[2 * NN + t];
        float sq = __fadd_rn(__fadd_rn(__fmul_rn(x, x), __fmul_rn(y, y)), __fmul_rn(z, z));
        cand[t] = make_float4(x, y, z, sq);
    }
    if (threadIdx.x < QG) { cntless[threadIdx.x] = 0; tiecnt[threadIdx.x] = 0; }
    __syncthreads();

    float qx = xb[q], qy = xb[NN + q], qz = xb[2 * NN + q];
    float qsq = __fadd_rn(__fadd_rn(__fmul_rn(qx, qx), __fmul_rn(qy, qy)), __fmul_rn(qz, qz));

    int segbase = w * 128 + qh * 64;

    TOP_DECL
    for (int i = 0; i < 64; i += 4) {   // phase A: 8-deep scan (hot loop)
        float4 c0 = cand[segbase + i + 0];
        float4 c1 = cand[segbase + i + 1];
        float4 c2 = cand[segbase + i + 2];
        float4 c3 = cand[segbase + i + 3];
        unsigned int d0 = dist_du(qx, qy, qz, qsq, c0);
        unsigned int d1 = dist_du(qx, qy, qz, qsq, c1);
        unsigned int d2 = dist_du(qx, qy, qz, qsq, c2);
        unsigned int d3 = dist_du(qx, qy, qz, qsq, c3);
        TOP8_INSERT(d0)
        TOP8_INSERT(d1)
        TOP8_INSERT(d2)
        TOP8_INSERT(d3)
    }

    {   // intra-wave fold: partner's 8-list into this lane's 16-list (t8..t15 = inf)
        unsigned int s0 = __shfl_xor(t0, 32), s1 = __shfl_xor(t1, 32);
        unsigned int s2 = __shfl_xor(t2, 32), s3 = __shfl_xor(t3, 32);
        unsigned int s4 = __shfl_xor(t4, 32), s5 = __shfl_xor(t5, 32);
        unsigned int s6 = __shfl_xor(t6, 32), s7 = __shfl_xor(t7, 32);
        TOP_INSERT(s0) TOP_INSERT(s1) TOP_INSERT(s2) TOP_INSERT(s3)
        TOP_INSERT(s4) TOP_INSERT(s5) TOP_INSERT(s6) TOP_INSERT(s7)
    }

    for (int s = 8; s >= 1; s >>= 1) {  // tree merge (16-wide, unchanged)
        if (w >= s && w < 2 * s && lane < 32) {
            int j = w - s;
            mbuf[j][0][q32] = t0;   mbuf[j][1][q32] = t1;
            mbuf[j][2][q32] = t2;   mbuf[j][3][q32] = t3;
            mbuf[j][4][q32] = t4;   mbuf[j][5][q32] = t5;
            mbuf[j][6][q32] = t6;   mbuf[j][7][q32] = t7;
            mbuf[j][8][q32] = t8;   mbuf[j][9][q32] = t9;
            mbuf[j][10][q32] = t10; mbuf[j][11][q32] = t11;
            mbuf[j][12][q32] = t12; mbuf[j][13][q32] = t13;
            mbuf[j][14][q32] = t14; mbuf[j][15][q32] = t15;
        }
        __syncthreads();
        if (w < s) {
#pragma unroll
            for (int k = 0; k < KNNK; k++) {
                unsigned int u = mbuf[w][k][q32];
                TOP_INSERT(u)
            }
        }
        __syncthreads();
    }
    if (w == 0 && lane < 32) Tq[q32] = t15;
    __syncthreads();

    {   // emission: LDS-only writes, slot guarded (T_est may be wrong -> cl>=16)
        unsigned int T = Tq[q32];
        for (int i = 0; i < 64; i++) {
            float4 c = cand[segbase + i];
            unsigned int du = dist_du(qx, qy, qz, qsq, c);
            if (du < T) {
                int slot = atomicAdd(&cntless[q32], 1);
                if (slot < 16) sel[slot][q32] = (unsigned short)(segbase + i);
            } else if (du == T) {
                int t = atomicAdd(&tiecnt[q32], 1);
                if (t < 16) tieidx[t][q32] = (unsigned short)(segbase + i);
            }
        }
    }
    __syncthreads();

    if (threadIdx.x < QG) {  // finalize (thread = query)
        int cl = cntless[threadIdx.x];
        if (cl >= 16) {
            // exact fallback (~1e-8/query): full 16-deep scan -> true T, then
            // ascending emit du<T, then ascending ties. Pure lax.top_k.
            TOP_DECL                          // shadows outer regs (dead here)
            for (int i = 0; i < NN; i++) {
                unsigned int du = dist_du(qx, qy, qz, qsq, cand[i]);
                TOP_INSERT(du)
            }
            unsigned int Tt = t15;
            int fp = 0;
            for (int i = 0; i < NN && fp < KNNK; i++) {
                unsigned int du = dist_du(qx, qy, qz, qsq, cand[i]);
                if (du < Tt) sel[fp++][threadIdx.x] = (unsigned short)i;
            }
            for (int i = 0; i < NN && fp < KNNK; i++) {
                unsigned int du = dist_du(qx, qy, qz, qsq, cand[i]);
                if (du == Tt) sel[fp++][threadIdx.x] = (unsigned short)i;
            }
        } else {
            unsigned int T = Tq[threadIdx.x];
            int need = KNNK - cl;
            int tc = tiecnt[threadIdx.x];
            if (need > 0) {
                if (tc <= 16) {
                    for (int r = 0; r < need; r++) {
                        int best = 0x7fffffff, bj = 0;
                        for (int j = 0; j < tc; j++) {
                            int v = tieidx[j][threadIdx.x];
                            if (v < best) { best = v; bj = j; }
                        }
                        tieidx[bj][threadIdx.x] = 0xFFFF;
                        sel[cl + r][threadIdx.x] = (unsigned short)best;
                    }
                } else {
                    int em = 0;
                    for (int i = 0; i < NN && em < need; i++) {
                        unsigned int du = dist_du(qx, qy, qz, qsq, cand[i]);
                        if (du == T) { sel[cl + em][threadIdx.x] = (unsigned short)i; em++; }
                    }
                }
            }
        }
    }
    __syncthreads();

    if (lane < 32) {  // write-out: entry w of query q32
        int x = (int)sel[w][q32];
        knn_idx[(size_t)bq * KNNK + w] = x;
        int pos = atomicAdd(&revcnt[b * NN + x], 1);
        if (pos < REVCAP) rev[((size_t)(b * NN + x)) * REVCAP + pos] = q;
    }
}

// ---------------- spec: bf16 gathers, 4-way ILP, bf16 output (unchanged R22) ----------------
__global__ __launch_bounds__(128) void spec_kernel(const __bf16* __restrict__ fTB,
                                                   const int* __restrict__ knn_idx,
                                                   const int* __restrict__ revcnt,
                                                   const int* __restrict__ rev,
                                                   __bf16* __restrict__ specB) {
    __shared__ int ml[KNNK + REVCAP];
    __shared__ float wl[KNNK + REVCAP];
    __shared__ int s_cnt;
    __shared__ float s_dn;

    int bn = blockIdx.x;           // b*NN + n
    int b = bn >> 11;
    int tid = threadIdx.x;

    if (tid == 0) {
        int c = revcnt[bn];
        s_cnt = c < REVCAP ? c : REVCAP;
        float D = 0.5f * (float)(KNNK + c);
        s_dn = 1.0f / sqrtf(D + 1e-6f);
    }
    __syncthreads();
    int cnt = s_cnt;
    if (tid < KNNK) ml[tid] = knn_idx[(size_t)bn * KNNK + tid];
    if (tid < cnt) ml[KNNK + tid] = rev[(size_t)bn * REVCAP + tid];
    __syncthreads();
    int total = KNNK + cnt;
    if (tid < total) {
        int m = ml[tid];
        float D = 0.5f * (float)(KNNK + revcnt[b * NN + m]);
        wl[tid] = 0.5f * (1.0f / sqrtf(D + 1e-6f));
    }
    __syncthreads();

    const __bf16* base = fTB + (size_t)b * NN * CINC + tid;
    float acc0 = 0.0f, acc1 = 0.0f, acc2 = 0.0f, acc3 = 0.0f;
    int j = 0;
    for (; j + 4 <= total; j += 4) {
        float f0v = (float)base[(size_t)ml[j + 0] * CINC];
        float f1v = (float)base[(size_t)ml[j + 1] * CINC];
        float f2v = (float)base[(size_t)ml[j + 2] * CINC];
        float f3v = (float)base[(size_t)ml[j + 3] * CINC];
        acc0 = fmaf(wl[j + 0], f0v, acc0);
        acc1 = fmaf(wl[j + 1], f1v, acc1);
        acc2 = fmaf(wl[j + 2], f2v, acc2);
        acc3 = fmaf(wl[j + 3], f3v, acc3);
    }
    for (; j < total; j++)
        acc0 = fmaf(wl[j], (float)base[(size_t)ml[j] * CINC], acc0);
    float acc = (acc0 + acc1) + (acc2 + acc3);

    float f0 = (float)base[(size_t)(bn & (NN - 1)) * CINC];
    specB[(size_t)bn * CINC + tid] = (__bf16)(f0 - s_dn * acc);
}

// ---------------- fused GEMM1+GEMM2 via LDS g1 tile (unchanged R22) ----------------
__global__ __launch_bounds__(256) void gemm12_fused(const __bf16* __restrict__ specB,
                                                    const __bf16* __restrict__ WspecB,
                                                    const float* __restrict__ bspec,
                                                    const float* __restrict__ gamma,
                                                    const float* __restrict__ beta,
                                                    const float* __restrict__ mean,
                                                    const float* __restrict__ var,
                                                    const __bf16* __restrict__ WcB,
                                                    const float* __restrict__ bc,
                                                    float* __restrict__ out) {
    __shared__ __bf16 g1s[64][COU + 8];
    int b  = blockIdx.y;
    int n0 = blockIdx.x * 64;
    int w = threadIdx.x >> 6, lane = threadIdx.x & 63;
    int lr = lane & 15, lk = (lane >> 4) * 8;
    int rb = (lane >> 4) * 4;

    {   // phase 1: spec @ Wspec^T + bias/BN/GELU -> g1s
        int o0 = w * 64;
        f32x4 acc[4][4] = {};
        const __bf16* As = specB + ((size_t)b * NN + n0 + lr) * CINC + lk;
        const __bf16* Bs = WspecB + (size_t)(o0 + lr) * CINC + lk;
#pragma unroll
        for (int kk = 0; kk < CINC; kk += 32) {
            bf16x8 a[4], bb[4];
#pragma unroll
            for (int m = 0; m < 4; m++)
                a[m] = *(const bf16x8*)(As + (size_t)(m * 16) * CINC + kk);
#pragma unroll
            for (int n = 0; n < 4; n++)
                bb[n] = *(const bf16x8*)(Bs + (size_t)(n * 16) * CINC + kk);
#pragma unroll
            for (int m = 0; m < 4; m++)
#pragma unroll
                for (int n = 0; n < 4; n++)
                    acc[m][n] = __builtin_amdgcn_mfma_f32_16x16x32_bf16(a[m], bb[n], acc[m][n], 0, 0, 0);
        }
#pragma unroll
        for (int n = 0; n < 4; n++) {
            int o = o0 + n * 16 + lr;
            float sc = 1.0f / sqrtf(var[o] + 1e-5f);
            float ga = gamma[o], be = beta[o], mu = mean[o], bs = bspec[o];
#pragma unroll
            for (int m = 0; m < 4; m++) {
#pragma unroll
                for (int j = 0; j < 4; j++) {
                    int nrow = m * 16 + rb + j;
                    float y = acc[m][n][j] + bs;
                    y = (y - mu) * sc;
                    y = y * ga + be;
                    float g = 0.5f * y * (1.0f + erff(y * 0.70710678118654752440f));
                    g1s[nrow][o] = (__bf16)g;
                }
            }
        }
    }
    __syncthreads();

    {   // phase 2: Wc @ g1^T + bias -> out
        int o0 = w * 64;
        f32x4 acc[4][4] = {};
        const __bf16* As = WcB + (size_t)(o0 + lr) * COU + lk;
#pragma unroll
        for (int kk = 0; kk < COU; kk += 32) {
            bf16x8 a[4], bb[4];
#pragma unroll
            for (int m = 0; m < 4; m++)
                a[m] = *(const bf16x8*)(As + (size_t)(m * 16) * COU + kk);
#pragma unroll
            for (int n = 0; n < 4; n++)
                bb[n] = *(const bf16x8*)(&g1s[n * 16 + lr][kk + lk]);
#pragma unroll
            for (int m = 0; m < 4; m++)
#pragma unroll
                for (int n = 0; n < 4; n++)
                    acc[m][n] = __builtin_amdgcn_mfma_f32_16x16x32_bf16(a[m], bb[n], acc[m][n], 0, 0, 0);
        }
#pragma unroll
        for (int m = 0; m < 4; m++) {
#pragma unroll
            for (int j = 0; j < 4; j++) {
                int o = o0 + m * 16 + rb + j;
                float bias = bc[o];
#pragma unroll
                for (int n = 0; n < 4; n++) {
                    int ncol = n0 + n * 16 + lr;
                    out[((size_t)b * COU + o) * NN + ncol] = acc[m][n][j] + bias;
                }
            }
        }
    }
}

extern "C" void kernel_launch(void* const* d_in, const int* in_sizes, int n_in,
                              void* d_out, int out_size, void* d_ws, size_t ws_size,
                              hipStream_t stream) {
    const float* xyz      = (const float*)d_in[0];
    const float* features = (const float*)d_in[1];
    const float* W_spec   = (const float*)d_in[2];
    const float* b_spec   = (const float*)d_in[3];
    const float* bn_gamma = (const float*)d_in[4];
    const float* bn_beta  = (const float*)d_in[5];
    const float* bn_mean  = (const float*)d_in[6];
    const float* bn_var   = (const float*)d_in[7];
    const float* W_low    = (const float*)d_in[8];
    const float* b_low    = (const float*)d_in[9];
    const float* W_high   = (const float*)d_in[10];
    const float* b_high   = (const float*)d_in[11];
    float* out = (float*)d_out;

    char* ws = (char*)d_ws;
    size_t off = 0;
    __bf16* fTB   = (__bf16*)(ws + off); off += (size_t)BB * NN * CINC * 2;      // 4 MB
    __bf16* specB = (__bf16*)(ws + off); off += (size_t)BB * NN * CINC * 2;      // 4 MB
    int*    idx   = (int*)(ws + off);    off += (size_t)BB * NN * KNNK * 4;      // 1 MB
    int*    rcnt  = (int*)(ws + off);    off += (size_t)BB * NN * 4;             // 64 KB
    int*    rev   = (int*)(ws + off);    off += (size_t)BB * NN * REVCAP * 4;    // 4 MB
    __bf16* WspecB= (__bf16*)(ws + off); off += (size_t)COU * CINC * 2;          // 64 KB
    __bf16* WcB   = (__bf16*)(ws + off); off += (size_t)COU * COU * 2;           // 128 KB
    float*  bc    = (float*)(ws + off);  off += (size_t)COU * 4;                 // 1 KB

    setup_kernel<<<dim3(2048 + 128), dim3(32, 8), 0, stream>>>(
        features, fTB, W_spec, W_low, W_high, b_low, b_high, WspecB, WcB, bc, rcnt);
    knn_fused_kernel<<<dim3(NN / QG, BB), dim3(1024), 0, stream>>>(xyz, idx, rcnt, rev);
    spec_kernel<<<dim3(BB * NN), dim3(128), 0, stream>>>(fTB, idx, rcnt, rev, specB);
    gemm12_fused<<<dim3(NN / 64, BB), dim3(256), 0, stream>>>(
        specB, WspecB, b_spec, bn_gamma, bn_beta, bn_mean, bn_var, WcB, bc, out);
}